// Round 2
// baseline (308.093 us; speedup 1.0000x reference)
//
#include <hip/hip_runtime.h>
#include <math.h>

constexpr int cE = 8;
constexpr int cH = 1024;
constexpr int cF = 2816;
constexpr int cR = 256;
constexpr int cT = 2048;
constexpr int ROWS = cT * 2;   // total routed (token, expert) rows = T*K
constexpr int LDA = 40;        // padded LDS row stride (BK=32 reg-staged kernels)

using short8  = __attribute__((ext_vector_type(8))) short;
using float4v = __attribute__((ext_vector_type(4))) float;
#define MFMA16 __builtin_amdgcn_mfma_f32_16x16x32_bf16

__device__ __forceinline__ unsigned short f2bf(float f) {
  union { float f; unsigned u; } v; v.f = f;
  unsigned r = v.u + 0x7fffu + ((v.u >> 16) & 1u);   // RNE
  return (unsigned short)(r >> 16);
}
__device__ __forceinline__ float bf2f(unsigned short s) {
  union { unsigned u; float f; } v; v.u = (unsigned)s << 16; return v.f;
}

// pack 8 fp32 -> 8 bf16, single 16B store
__device__ __forceinline__ void store_bf8(unsigned short* dst, float4 a, float4 b) {
  union { unsigned short u[8]; uint4 v; } t;
  t.u[0] = f2bf(a.x); t.u[1] = f2bf(a.y); t.u[2] = f2bf(a.z); t.u[3] = f2bf(a.w);
  t.u[4] = f2bf(b.x); t.u[5] = f2bf(b.y); t.u[6] = f2bf(b.z); t.u[7] = f2bf(b.w);
  *reinterpret_cast<uint4*>(dst) = t.v;
}

// async global->LDS, 16 B per lane. LDS dest = wave-uniform base + lane*16,
// global source address is per-lane (gather-capable).
__device__ __forceinline__ void gld16(const unsigned short* g, unsigned short* l) {
  __builtin_amdgcn_global_load_lds(
      (const __attribute__((address_space(1))) void*)g,
      (__attribute__((address_space(3))) void*)l, 16, 0, 0);
}

// ---------------------------------------------------------------------------
// LAUNCH 1: all 6 transposes (fp32->bf16) + gating + x->bf16, one launch.
//  [0,64)        Cg  256x256 x1
//  [64,128)      Cu  256x256 x1
//  [128,2176)    Vd  256x1024 x8
//  [2176,7808)   Vg  256x2816 x8
//  [7808,13440)  Vu  256x2816 x8
//  [13440,19072) Ud  2816x256 x8
//  [19072,19584) gating (512 blocks x 4 tokens)
// ---------------------------------------------------------------------------
constexpr int TCONV_BLOCKS = 19072;
constexpr int PREP1_BLOCKS = TCONV_BLOCKS + cT / 4;

__device__ __forceinline__ void tconv_tile(
    const float* __restrict__ in, unsigned short* __restrict__ out,
    int P, int Q, int e, int bx, int by, int tid, float (*tile)[33])
{
  const long es = (long)P * Q;
  in += e * es; out += e * es;
  const int c0 = bx * 32, r0 = by * 32;
  const int r = tid >> 3, c4 = (tid & 7) * 4;
  float4 v = *reinterpret_cast<const float4*>(in + (long)(r0 + r) * Q + c0 + c4);
  tile[r][c4 + 0] = v.x; tile[r][c4 + 1] = v.y;
  tile[r][c4 + 2] = v.z; tile[r][c4 + 3] = v.w;
  __syncthreads();
  const int cc = tid >> 3, rr4 = (tid & 7) * 4;
  ushort4 o;
  o.x = f2bf(tile[rr4 + 0][cc]);
  o.y = f2bf(tile[rr4 + 1][cc]);
  o.z = f2bf(tile[rr4 + 2][cc]);
  o.w = f2bf(tile[rr4 + 3][cc]);
  *reinterpret_cast<ushort4*>(out + (long)(c0 + cc) * P + r0 + rr4) = o;
}

__global__ __launch_bounds__(256) void k_prep1(
    const float* __restrict__ Cg, unsigned short* __restrict__ CgT,
    const float* __restrict__ Cu, unsigned short* __restrict__ CuT,
    const float* __restrict__ Vd, unsigned short* __restrict__ VdT,
    const float* __restrict__ Vg, unsigned short* __restrict__ vgT,
    const float* __restrict__ Vu, unsigned short* __restrict__ vuT,
    const float* __restrict__ Ud, unsigned short* __restrict__ udT,
    const float* __restrict__ x, const float* __restrict__ gw,
    unsigned short* __restrict__ xb, int* __restrict__ et,
    float* __restrict__ wt)
{
  __shared__ float tile[32][33];
  int b = blockIdx.x;
  const int tid = threadIdx.x;
  if (b < TCONV_BLOCKS) {
    const float* in; unsigned short* out; int P, Q;
    if (b < 64)         { in = Cg; out = CgT; P = 256;  Q = 256;  }
    else if (b < 128)   { b -= 64;    in = Cu; out = CuT; P = 256;  Q = 256;  }
    else if (b < 2176)  { b -= 128;   in = Vd; out = VdT; P = 256;  Q = 1024; }
    else if (b < 7808)  { b -= 2176;  in = Vg; out = vgT; P = 256;  Q = 2816; }
    else if (b < 13440) { b -= 7808;  in = Vu; out = vuT; P = 256;  Q = 2816; }
    else                { b -= 13440; in = Ud; out = udT; P = 2816; Q = 256;  }
    const int tpe = (P / 32) * (Q / 32);
    const int e = b / tpe, rem = b % tpe;
    const int bx = rem % (Q / 32), by = rem / (Q / 32);
    tconv_tile(in, out, P, Q, e, bx, by, tid, tile);
    return;
  }
  // ---- gating path ----
  const int wid = tid >> 6, lane = tid & 63;
  const int t = (b - TCONV_BLOCKS) * 4 + wid;
  const float* xr = x + (long)t * cH + lane * 16;
  float4 v0 = *reinterpret_cast<const float4*>(xr);
  float4 v1 = *reinterpret_cast<const float4*>(xr + 4);
  float4 v2 = *reinterpret_cast<const float4*>(xr + 8);
  float4 v3 = *reinterpret_cast<const float4*>(xr + 12);
  store_bf8(xb + (long)t * cH + lane * 16, v0, v1);
  store_bf8(xb + (long)t * cH + lane * 16 + 8, v2, v3);
  float xv[16];
  *reinterpret_cast<float4*>(&xv[0])  = v0;
  *reinterpret_cast<float4*>(&xv[4])  = v1;
  *reinterpret_cast<float4*>(&xv[8])  = v2;
  *reinterpret_cast<float4*>(&xv[12]) = v3;
  const float* g = gw + (long)lane * 16 * cE;
  float l[cE];
#pragma unroll
  for (int e = 0; e < cE; ++e) l[e] = 0.f;
#pragma unroll
  for (int i = 0; i < 16; ++i) {
    float4 ga = *reinterpret_cast<const float4*>(g + i * cE);
    float4 gb = *reinterpret_cast<const float4*>(g + i * cE + 4);
    float xi = xv[i];
    l[0] += xi * ga.x; l[1] += xi * ga.y; l[2] += xi * ga.z; l[3] += xi * ga.w;
    l[4] += xi * gb.x; l[5] += xi * gb.y; l[6] += xi * gb.z; l[7] += xi * gb.w;
  }
#pragma unroll
  for (int m = 1; m < 64; m <<= 1)
#pragma unroll
    for (int e = 0; e < cE; ++e)
      l[e] += __shfl_xor(l[e], m, 64);
  if (lane == 0) {
    int i0 = 0; float m0 = l[0];
#pragma unroll
    for (int e = 1; e < cE; ++e) if (l[e] > m0) { m0 = l[e]; i0 = e; }
    int i1 = -1; float m1 = -1e30f;
#pragma unroll
    for (int e = 0; e < cE; ++e) if (e != i0 && l[e] > m1) { m1 = l[e]; i1 = e; }
    float w0 = 1.f / (1.f + expf(m1 - m0));
    et[t * 2 + 0] = i0;  et[t * 2 + 1] = i1;
    wt[t * 2 + 0] = w0;  wt[t * 2 + 1] = 1.f - w0;
  }
}

// ---------------------------------------------------------------------------
// MFMA fold body: D[m][n] = sum_k A[m][k] * B[n][k],  K = 256 fixed.
// tile 128x64, BK=32, register prefetch.
// ---------------------------------------------------------------------------
__device__ __forceinline__ void foldm_body(
    const unsigned short* __restrict__ A, const float* __restrict__ B,
    unsigned short* __restrict__ D, int ldd, int m0, int n0, int tid,
    unsigned short* As, unsigned short* Bs)
{
  const int sr = tid >> 2, sk = (tid & 3) * 8;
  const unsigned short* a0 = A + (long)(m0 + sr) * 256 + sk;
  const unsigned short* a1 = a0 + (long)64 * 256;
  const float* br = B + (long)(n0 + sr) * 256 + sk;
  uint4 rA0, rA1; float4 rB0, rB1;
  auto load_slice = [&](int k0) {
    rA0 = *reinterpret_cast<const uint4*>(a0 + k0);
    rA1 = *reinterpret_cast<const uint4*>(a1 + k0);
    rB0 = *reinterpret_cast<const float4*>(br + k0);
    rB1 = *reinterpret_cast<const float4*>(br + k0 + 4);
  };
  load_slice(0);
  const int wid = tid >> 6, lane = tid & 63;
  const int wm = (wid >> 1) * 64, wn = (wid & 1) * 32;
  const int fr = lane & 15, fq = lane >> 4;
  float4v zf = {0.f, 0.f, 0.f, 0.f};
  float4v acc[4][2];
#pragma unroll
  for (int i = 0; i < 4; ++i) { acc[i][0] = zf; acc[i][1] = zf; }
  for (int k0 = 0; k0 < 256; k0 += 32) {
    *reinterpret_cast<uint4*>(&As[sr * LDA + sk]) = rA0;
    *reinterpret_cast<uint4*>(&As[(sr + 64) * LDA + sk]) = rA1;
    store_bf8(&Bs[sr * LDA + sk], rB0, rB1);
    if (k0 + 32 < 256) load_slice(k0 + 32);
    __syncthreads();
    short8 af[4], bf[2];
#pragma unroll
    for (int mi = 0; mi < 4; ++mi)
      af[mi] = *reinterpret_cast<const short8*>(&As[(wm + mi * 16 + fr) * LDA + fq * 8]);
#pragma unroll
    for (int nj = 0; nj < 2; ++nj)
      bf[nj] = *reinterpret_cast<const short8*>(&Bs[(wn + nj * 16 + fr) * LDA + fq * 8]);
#pragma unroll
    for (int mi = 0; mi < 4; ++mi)
#pragma unroll
      for (int nj = 0; nj < 2; ++nj)
        acc[mi][nj] = MFMA16(af[mi], bf[nj], acc[mi][nj], 0, 0, 0);
    __syncthreads();
  }
#pragma unroll
  for (int mi = 0; mi < 4; ++mi)
#pragma unroll
    for (int r = 0; r < 4; ++r) {
      int m = m0 + wm + mi * 16 + fq * 4 + r;
#pragma unroll
      for (int nj = 0; nj < 2; ++nj)
        D[(long)m * ldd + n0 + wn + nj * 16 + fr] = f2bf(acc[mi][nj][r]);
    }
}

// ---------------------------------------------------------------------------
// LAUNCH 2: foldm2 (b1t, 512 blocks) + foldm vd2t (256 blocks) + lists (1).
// folds depend on tconv (launch 1); lists depends on gating (launch 1).
// ---------------------------------------------------------------------------
constexpr int PREP2_BLOCKS = 512 + 256 + 1;
__global__ __launch_bounds__(256, 2) void k_prep2(
    const unsigned short* __restrict__ CgT, const unsigned short* __restrict__ CuT,
    const float* __restrict__ Ug, const float* __restrict__ Uu,
    unsigned short* __restrict__ b1t,
    const unsigned short* __restrict__ VdT, const float* __restrict__ Cd,
    unsigned short* __restrict__ vd2t,
    const int* __restrict__ et, int* __restrict__ rowmap,
    int* __restrict__ tok, int* __restrict__ cnt, int* __restrict__ off)
{
  __shared__ __align__(16) unsigned short As[128 * LDA], Bs[64 * LDA];
  __shared__ int sc_[cE], sp_[cE], so_[cE];
  const int b = blockIdx.x;
  const int tid = threadIdx.x;
  if (b < 512) {
    // merged gate+up b1t fold: z = sel<<3 | e; grid was (16, 2, 16)
    const int bx = b & 15, by = (b >> 4) & 1, z = b >> 5;
    const int sel = z >> 3, e = z & 7;
    const unsigned short* A = sel ? CuT : CgT;
    const float* B = (sel ? Uu : Ug) + (long)e * cH * cR;
    unsigned short* Dp = b1t + (long)e * 512 * 1024 + (long)sel * 256 * 1024;
    foldm_body(A, B, Dp, cH, by * 128, bx * 64, tid, As, Bs);
  } else if (b < 768) {
    // vd2t fold: grid was (4, 8, 8)
    const int b2 = b - 512;
    const int bx = b2 & 3, by = (b2 >> 2) & 7, e = b2 >> 5;
    foldm_body(VdT + (long)e * cH * cR, Cd, vd2t + (long)e * cH * 256, cR,
               by * 128, bx * 64, tid, As, Bs);
  } else {
    // ---- lists path (single block) ----
    if (tid < cE) { sc_[tid] = 0; sp_[tid] = 0; }
    __syncthreads();
    for (int i = tid; i < ROWS; i += 256) atomicAdd(&sc_[et[i]], 1);
    __syncthreads();
    if (tid == 0) {
      int s = 0;
      for (int e = 0; e < cE; ++e) { so_[e] = s; s += sc_[e]; }
    }
    __syncthreads();
    for (int i = tid; i < ROWS; i += 256) {
      int e = et[i];
      int slot = atomicAdd(&sp_[e], 1);
      int cr = so_[e] + slot;
      rowmap[i] = cr;
      tok[cr] = i >> 1;
    }
    if (tid < cE) { cnt[tid] = sc_[tid]; off[tid] = so_[tid]; }
  }
}

// ---------------------------------------------------------------------------
// COMPACT t1 GEMM: t1[o+row] = xb[tok[o+row]] @ b1t[e]^T   (K=1024, N=512)
// tile 128x64, BK=64, gather via per-lane global_load_lds source addresses.
// grid = (512/64, cT/128, E), early-return past cnt[e].
// ---------------------------------------------------------------------------
__global__ __launch_bounds__(256, 2) void k_t1c(
    const unsigned short* __restrict__ xb, const unsigned short* __restrict__ b1t,
    unsigned short* __restrict__ t1, const int* __restrict__ tok,
    const int* __restrict__ cnt, const int* __restrict__ off)
{
  __shared__ __align__(16) unsigned short As[128 * 64], Bs[64 * 64];
  const int e = blockIdx.z, c = cnt[e], o = off[e];
  const int m0 = blockIdx.y * 128;
  if (m0 >= c) return;
  const int n0 = blockIdx.x * 64;
  const int tid = threadIdx.x;
  const int wid = tid >> 6, lane = tid & 63;
  const int sr8 = lane >> 3, sc = (lane & 7) * 8;
  const unsigned short* gA[4];
#pragma unroll
  for (int j = 0; j < 4; ++j) {
    int row = min(m0 + wid * 32 + j * 8 + sr8, c - 1);
    gA[j] = xb + (long)tok[o + row] * cH + sc;
  }
  const unsigned short* gB = b1t + (long)e * 512 * 1024 +
      (long)(n0 + wid * 16 + sr8) * 1024 + sc;
  unsigned short* lA = As + wid * 32 * 64;   // wave-uniform dest
  unsigned short* lB = Bs + wid * 16 * 64;
  const int wm = (wid >> 1) * 64, wn = (wid & 1) * 32;
  const int fr = lane & 15, fq = lane >> 4;
  float4v zf = {0.f, 0.f, 0.f, 0.f};
  float4v acc[4][2];
#pragma unroll
  for (int i = 0; i < 4; ++i) { acc[i][0] = zf; acc[i][1] = zf; }
  for (int k0 = 0; k0 < cH; k0 += 64) {
#pragma unroll
    for (int j = 0; j < 4; ++j) gld16(gA[j] + k0, lA + j * 8 * 64);
    gld16(gB + k0, lB);
    gld16(gB + (long)8 * 1024 + k0, lB + 8 * 64);
    __syncthreads();
#pragma unroll
    for (int ks = 0; ks < 2; ++ks) {
      short8 af[4], bf[2];
#pragma unroll
      for (int mi = 0; mi < 4; ++mi)
        af[mi] = *reinterpret_cast<const short8*>(
            &As[(wm + mi * 16 + fr) * 64 + ks * 32 + fq * 8]);
#pragma unroll
      for (int nj = 0; nj < 2; ++nj)
        bf[nj] = *reinterpret_cast<const short8*>(
            &Bs[(wn + nj * 16 + fr) * 64 + ks * 32 + fq * 8]);
#pragma unroll
      for (int mi = 0; mi < 4; ++mi)
#pragma unroll
        for (int nj = 0; nj < 2; ++nj)
          acc[mi][nj] = MFMA16(af[mi], bf[nj], acc[mi][nj], 0, 0, 0);
    }
    __syncthreads();
  }
#pragma unroll
  for (int mi = 0; mi < 4; ++mi)
#pragma unroll
    for (int r = 0; r < 4; ++r) {
      int row = m0 + wm + mi * 16 + fq * 4 + r;
      if (row < c) {
#pragma unroll
        for (int nj = 0; nj < 2; ++nj)
          t1[(long)(o + row) * 512 + n0 + wn + nj * 16 + fr] = f2bf(acc[mi][nj][r]);
      }
    }
}

// ---------------------------------------------------------------------------
// dual GEMM: a = silu(t1g @ vgT^T) * (t1u @ vuT^T)  [rows x F], K=256
// async staging, unpadded LDS, BK=32, clamped staging rows. grid=(44,16,E)
// ---------------------------------------------------------------------------
__global__ __launch_bounds__(256, 2) void k_act(
    const unsigned short* __restrict__ t1,
    const unsigned short* __restrict__ vgT, const unsigned short* __restrict__ vuT,
    unsigned short* __restrict__ a, const int* __restrict__ cnt,
    const int* __restrict__ off)
{
  __shared__ __align__(16) unsigned short Ag[128 * 32], Au[128 * 32];
  __shared__ __align__(16) unsigned short Bg[64 * 32],  Bu[64 * 32];
  const int e = blockIdx.z, c = cnt[e], o = off[e];
  const int m0 = blockIdx.y * 128;
  if (m0 >= c) return;
  const int n0 = blockIdx.x * 64;
  const int tid = threadIdx.x;
  const int wid = tid >> 6, lane = tid & 63;
  const int sr16 = lane >> 2, sc = (lane & 3) * 8;
  const int ra0 = o + min(m0 + wid * 32 + sr16, c - 1);
  const int ra1 = o + min(m0 + wid * 32 + 16 + sr16, c - 1);
  const unsigned short* gAg0 = t1 + (long)ra0 * 512 + sc;
  const unsigned short* gAg1 = t1 + (long)ra1 * 512 + sc;
  const unsigned short* gBg = vgT + (long)e * cF * 256 + (long)(n0 + wid * 16 + sr16) * 256 + sc;
  const unsigned short* gBu = vuT + (long)e * cF * 256 + (long)(n0 + wid * 16 + sr16) * 256 + sc;
  unsigned short* lAg = Ag + wid * 32 * 32;
  unsigned short* lAu = Au + wid * 32 * 32;
  unsigned short* lBg = Bg + wid * 16 * 32;
  unsigned short* lBu = Bu + wid * 16 * 32;
  const int wm = (wid >> 1) * 64, wn = (wid & 1) * 32;
  const int fr = lane & 15, fq = lane >> 4;
  float4v zf = {0.f, 0.f, 0.f, 0.f};
  float4v accg[4][2], accu[4][2];
#pragma unroll
  for (int i = 0; i < 4; ++i) { accg[i][0] = zf; accg[i][1] = zf; accu[i][0] = zf; accu[i][1] = zf; }
  for (int k0 = 0; k0 < 256; k0 += 32) {
    gld16(gAg0 + k0, lAg);
    gld16(gAg1 + k0, lAg + 16 * 32);
    gld16(gAg0 + 256 + k0, lAu);
    gld16(gAg1 + 256 + k0, lAu + 16 * 32);
    gld16(gBg + k0, lBg);
    gld16(gBu + k0, lBu);
    __syncthreads();
    short8 ag[4], au[4], bg[2], bu[2];
#pragma unroll
    for (int mi = 0; mi < 4; ++mi) {
      ag[mi] = *reinterpret_cast<const short8*>(&Ag[(wm + mi * 16 + fr) * 32 + fq * 8]);
      au[mi] = *reinterpret_cast<const short8*>(&Au[(wm + mi * 16 + fr) * 32 + fq * 8]);
    }
#pragma unroll
    for (int nj = 0; nj < 2; ++nj) {
      bg[nj] = *reinterpret_cast<const short8*>(&Bg[(wn + nj * 16 + fr) * 32 + fq * 8]);
      bu[nj] = *reinterpret_cast<const short8*>(&Bu[(wn + nj * 16 + fr) * 32 + fq * 8]);
    }
#pragma unroll
    for (int mi = 0; mi < 4; ++mi)
#pragma unroll
      for (int nj = 0; nj < 2; ++nj) {
        accg[mi][nj] = MFMA16(ag[mi], bg[nj], accg[mi][nj], 0, 0, 0);
        accu[mi][nj] = MFMA16(au[mi], bu[nj], accu[mi][nj], 0, 0, 0);
      }
    __syncthreads();
  }
#pragma unroll
  for (int mi = 0; mi < 4; ++mi)
#pragma unroll
    for (int r = 0; r < 4; ++r) {
      int row = m0 + wm + mi * 16 + fq * 4 + r;
      if (row < c) {
#pragma unroll
        for (int nj = 0; nj < 2; ++nj) {
          float g = accg[mi][nj][r];
          float u = accu[mi][nj][r];
          float s = g / (1.f + expf(-g)) * u;
          a[(long)(o + row) * cF + n0 + wn + nj * 16 + fr] = f2bf(s);
        }
      }
    }
}

// ---------------------------------------------------------------------------
// t3b = a @ udT^T, FULL K=2816 (no split-K), bf16 stores. [ROWS][256].
// async staging, unpadded LDS [64][64], BK=64, clamped rows, 44 iters.
// grid = (4, 32, E). Replaces the old split-K t3p + k_red pair.
// ---------------------------------------------------------------------------
__global__ __launch_bounds__(256, 2) void k_t3(
    const unsigned short* __restrict__ a, const unsigned short* __restrict__ udT,
    unsigned short* __restrict__ t3b, const int* __restrict__ cnt,
    const int* __restrict__ off)
{
  __shared__ __align__(16) unsigned short As[64 * 64], Bs[64 * 64];
  const int e = blockIdx.z, c = cnt[e], o = off[e];
  const int m0 = blockIdx.y * 64;
  if (m0 >= c) return;
  const int n0 = blockIdx.x * 64;
  const int tid = threadIdx.x;
  const int wid = tid >> 6, lane = tid & 63;
  const int sr8 = lane >> 3, sc = (lane & 7) * 8;
  const int ra0 = o + min(m0 + wid * 16 + sr8, c - 1);
  const int ra1 = o + min(m0 + wid * 16 + 8 + sr8, c - 1);
  const unsigned short* gA0 = a + (long)ra0 * cF + sc;
  const unsigned short* gA1 = a + (long)ra1 * cF + sc;
  const unsigned short* gB  = udT + (long)e * 256 * cF + (long)(n0 + wid * 16 + sr8) * cF + sc;
  unsigned short* lA = As + wid * 16 * 64;
  unsigned short* lB = Bs + wid * 16 * 64;
  const int wm = (wid >> 1) * 32, wn = (wid & 1) * 32;
  const int fr = lane & 15, fq = lane >> 4;
  float4v zf = {0.f, 0.f, 0.f, 0.f};
  float4v acc[2][2] = {{zf, zf}, {zf, zf}};
  for (int k0 = 0; k0 < cF; k0 += 64) {
    gld16(gA0 + k0, lA);
    gld16(gA1 + k0, lA + 8 * 64);
    gld16(gB + k0, lB);
    gld16(gB + (long)8 * cF + k0, lB + 8 * 64);
    __syncthreads();
#pragma unroll
    for (int ks = 0; ks < 2; ++ks) {
      short8 af[2], bf[2];
#pragma unroll
      for (int mi = 0; mi < 2; ++mi)
        af[mi] = *reinterpret_cast<const short8*>(
            &As[(wm + mi * 16 + fr) * 64 + ks * 32 + fq * 8]);
#pragma unroll
      for (int nj = 0; nj < 2; ++nj)
        bf[nj] = *reinterpret_cast<const short8*>(
            &Bs[(wn + nj * 16 + fr) * 64 + ks * 32 + fq * 8]);
#pragma unroll
      for (int mi = 0; mi < 2; ++mi)
#pragma unroll
        for (int nj = 0; nj < 2; ++nj)
          acc[mi][nj] = MFMA16(af[mi], bf[nj], acc[mi][nj], 0, 0, 0);
    }
    __syncthreads();
  }
#pragma unroll
  for (int mi = 0; mi < 2; ++mi)
#pragma unroll
    for (int r = 0; r < 4; ++r) {
      int row = m0 + wm + mi * 16 + fq * 4 + r;
      if (row < c) {
        unsigned short* dst = t3b + (long)(o + row) * 256 + n0 + wn;
#pragma unroll
        for (int nj = 0; nj < 2; ++nj)
          dst[nj * 16 + fr] = f2bf(acc[mi][nj][r]);
      }
    }
}

// ---------------------------------------------------------------------------
// y = t3b @ vd2t^T   [rows x 1024] bf16, plain stores. K = 256.
// async staging, unpadded LDS, BK=32. grid = (16, 16, E)
// ---------------------------------------------------------------------------
__global__ __launch_bounds__(256, 2) void k_y(
    const unsigned short* __restrict__ t3b, const unsigned short* __restrict__ vd2t,
    unsigned short* __restrict__ y, const int* __restrict__ cnt,
    const int* __restrict__ off)
{
  __shared__ __align__(16) unsigned short As[128 * 32], Bs[64 * 32];
  const int e = blockIdx.z, c = cnt[e], o = off[e];
  const int m0 = blockIdx.y * 128;
  if (m0 >= c) return;
  const int n0 = blockIdx.x * 64;
  const int tid = threadIdx.x;
  const int wid = tid >> 6, lane = tid & 63;
  const int sr16 = lane >> 2, sc = (lane & 3) * 8;
  const int ra0 = o + min(m0 + wid * 32 + sr16, c - 1);
  const int ra1 = o + min(m0 + wid * 32 + 16 + sr16, c - 1);
  const unsigned short* gA0 = t3b + (long)ra0 * 256 + sc;
  const unsigned short* gA1 = t3b + (long)ra1 * 256 + sc;
  const unsigned short* gB  = vd2t + (long)e * cH * 256 + (long)(n0 + wid * 16 + sr16) * 256 + sc;
  unsigned short* lA = As + wid * 32 * 32;
  unsigned short* lB = Bs + wid * 16 * 32;
  const int wm = (wid >> 1) * 64, wn = (wid & 1) * 32;
  const int fr = lane & 15, fq = lane >> 4;
  float4v zf = {0.f, 0.f, 0.f, 0.f};
  float4v acc[4][2];
#pragma unroll
  for (int i = 0; i < 4; ++i) { acc[i][0] = zf; acc[i][1] = zf; }
  for (int k0 = 0; k0 < 256; k0 += 32) {
    gld16(gA0 + k0, lA);
    gld16(gA1 + k0, lA + 16 * 32);
    gld16(gB + k0, lB);
    __syncthreads();
    short8 af[4], bf[2];
#pragma unroll
    for (int mi = 0; mi < 4; ++mi)
      af[mi] = *reinterpret_cast<const short8*>(&As[(wm + mi * 16 + fr) * 32 + fq * 8]);
#pragma unroll
    for (int nj = 0; nj < 2; ++nj)
      bf[nj] = *reinterpret_cast<const short8*>(&Bs[(wn + nj * 16 + fr) * 32 + fq * 8]);
#pragma unroll
    for (int mi = 0; mi < 4; ++mi)
#pragma unroll
      for (int nj = 0; nj < 2; ++nj)
        acc[mi][nj] = MFMA16(af[mi], bf[nj], acc[mi][nj], 0, 0, 0);
    __syncthreads();
  }
#pragma unroll
  for (int mi = 0; mi < 4; ++mi)
#pragma unroll
    for (int r = 0; r < 4; ++r) {
      int row = m0 + wm + mi * 16 + fq * 4 + r;
      if (row < c) {
#pragma unroll
        for (int nj = 0; nj < 2; ++nj)
          y[(long)(o + row) * cH + n0 + wn + nj * 16 + fr] = f2bf(acc[mi][nj][r]);
      }
    }
}

// ---------------------------------------------------------------------------
// out[t] = w0 * y[rowmap[2t]] + w1 * y[rowmap[2t+1]]   (pure write, no zero)
// ---------------------------------------------------------------------------
__global__ __launch_bounds__(256) void k_combine(
    const unsigned short* __restrict__ y, const float* __restrict__ wt,
    const int* __restrict__ rowmap, float* __restrict__ out)
{
  const int tid = threadIdx.x;
  const int t = blockIdx.x * 2 + (tid >> 7);
  const int h = (tid & 127) * 8;
  const int r0 = rowmap[2 * t], r1 = rowmap[2 * t + 1];
  const float w0 = wt[2 * t], w1 = wt[2 * t + 1];
  union { uint4 v; unsigned short s[8]; } ua, ub;
  ua.v = *reinterpret_cast<const uint4*>(y + (long)r0 * cH + h);
  ub.v = *reinterpret_cast<const uint4*>(y + (long)r1 * cH + h);
  float o[8];
#pragma unroll
  for (int i = 0; i < 8; ++i)
    o[i] = w0 * bf2f(ua.s[i]) + w1 * bf2f(ub.s[i]);
  float* dst = out + (long)t * cH + h;
  *reinterpret_cast<float4*>(dst)     = make_float4(o[0], o[1], o[2], o[3]);
  *reinterpret_cast<float4*>(dst + 4) = make_float4(o[4], o[5], o[6], o[7]);
}

// ---------------------------------------------------------------------------
extern "C" void kernel_launch(void* const* d_in, const int* in_sizes, int n_in,
                              void* d_out, int out_size, void* d_ws, size_t ws_size,
                              hipStream_t stream)
{
  const float* x  = (const float*)d_in[0];
  const float* gw = (const float*)d_in[1];
  const float* Ug = (const float*)d_in[2];
  const float* Cg = (const float*)d_in[3];
  const float* Vg = (const float*)d_in[4];
  const float* Uu = (const float*)d_in[5];
  const float* Cu = (const float*)d_in[6];
  const float* Vu = (const float*)d_in[7];
  const float* Ud = (const float*)d_in[8];
  const float* Cd = (const float*)d_in[9];
  const float* Vd = (const float*)d_in[10];
  float* out = (float*)d_out;

  // workspace layout (~79 MiB peak, with aliasing)
  char* w = (char*)d_ws;
  // region 0: vgT (phase-1); t3b (2 MiB bf16) aliases it in phase 2
  unsigned short* vgT = (unsigned short*)w;
  unsigned short* t3b = (unsigned short*)w;
  w += (long)cE * cF * 256 * 2;                                               // 11.53
  unsigned short* b1t = (unsigned short*)w;  w += (long)cE * 512 * 1024 * 2;  // 8.39
  unsigned short* vd2t = (unsigned short*)w; w += (long)cE * cH * 256 * 2;    // 4.19
  // vuT phase-1; yb (8.39) aliases it in phase 2
  unsigned short* vuT = (unsigned short*)w;
  unsigned short* yb  = (unsigned short*)w;  w += (long)cE * cF * 256 * 2;    // 11.53
  unsigned short* udT = (unsigned short*)w;  w += (long)cE * 256 * cF * 2;    // 11.53
  // VdT consumed by prep2 fold; xb (bf16 x, 4.19 MB) written by prep1 must
  // NOT alias it anymore (both live during launch 1-2) -> keep separate.
  unsigned short* VdT = (unsigned short*)w;  w += (long)cE * cH * 256 * 2;    // 4.19
  unsigned short* xb  = (unsigned short*)w;  w += (long)cT * cH * 2;          // 4.19
  unsigned short* CgT = (unsigned short*)w;  w += (long)cR * cR * 2;          // 0.13
  unsigned short* CuT = (unsigned short*)w;  w += (long)cR * cR * 2;          // 0.13
  unsigned short* t1  = (unsigned short*)w;  w += (long)ROWS * 512 * 2;       // 4.19
  unsigned short* ab  = (unsigned short*)w;  w += (long)ROWS * cF * 2;        // 23.07
  float* wt   = (float*)w; w += ROWS * 4;
  int* et     = (int*)w; w += ROWS * 4;
  int* rowmap = (int*)w; w += ROWS * 4;
  int* tok    = (int*)w; w += ROWS * 4;
  int* cnt = (int*)w; w += cE * 4;
  int* off = (int*)w; w += cE * 4;

  // L1: all transposes + gating + x->bf16
  k_prep1<<<dim3(PREP1_BLOCKS), dim3(256), 0, stream>>>(
      Cg, CgT, Cu, CuT, Vd, VdT, Vg, vgT, Vu, vuT, Ud, udT, x, gw, xb, et, wt);
  // L2: b1t fold + vd2t fold + routing lists
  k_prep2<<<dim3(PREP2_BLOCKS), dim3(256), 0, stream>>>(
      CgT, CuT, Ug, Uu, b1t, VdT, Cd, vd2t, et, rowmap, tok, cnt, off);
  // L3: compact t1 GEMM (gathered A rows, per-expert B)
  k_t1c<<<dim3(8, cT / 128, cE), dim3(256), 0, stream>>>(xb, b1t, t1, tok, cnt, off);
  // L4: a = silu(t1g @ Vg) * (t1u @ Vu)
  k_act<<<dim3(cF / 64, cT / 128, cE), dim3(256), 0, stream>>>(t1, vgT, vuT, ab, cnt, off);
  // L5: t3b = a @ Ud (full-K, bf16 out; aliases dead vgT)
  k_t3<<<dim3(4, cT / 64, cE), dim3(256), 0, stream>>>(ab, udT, t3b, cnt, off);
  // L6: y = t3b @ Vd2 (aliases dead vuT)
  k_y<<<dim3(cH / 64, cT / 128, cE), dim3(256), 0, stream>>>(t3b, vd2t, yb, cnt, off);
  // L7: out = w0*y[r0] + w1*y[r1]
  k_combine<<<dim3(cT / 2), dim3(256), 0, stream>>>(yb, wt, rowmap, out);
}

// Round 3
// 304.776 us; speedup vs baseline: 1.0109x; 1.0109x over previous
//
#include <hip/hip_runtime.h>
#include <math.h>

constexpr int cE = 8;
constexpr int cH = 1024;
constexpr int cF = 2816;
constexpr int cR = 256;
constexpr int cT = 2048;
constexpr int ROWS = cT * 2;   // total routed (token, expert) rows = T*K
constexpr int LDA = 40;        // padded LDS row stride (BK=32 reg-staged kernels)

using short8  = __attribute__((ext_vector_type(8))) short;
using float4v = __attribute__((ext_vector_type(4))) float;
#define MFMA16 __builtin_amdgcn_mfma_f32_16x16x32_bf16

__device__ __forceinline__ unsigned short f2bf(float f) {
  union { float f; unsigned u; } v; v.f = f;
  unsigned r = v.u + 0x7fffu + ((v.u >> 16) & 1u);   // RNE
  return (unsigned short)(r >> 16);
}
__device__ __forceinline__ float bf2f(unsigned short s) {
  union { unsigned u; float f; } v; v.u = (unsigned)s << 16; return v.f;
}

// pack 8 fp32 -> 8 bf16, single 16B store
__device__ __forceinline__ void store_bf8(unsigned short* dst, float4 a, float4 b) {
  union { unsigned short u[8]; uint4 v; } t;
  t.u[0] = f2bf(a.x); t.u[1] = f2bf(a.y); t.u[2] = f2bf(a.z); t.u[3] = f2bf(a.w);
  t.u[4] = f2bf(b.x); t.u[5] = f2bf(b.y); t.u[6] = f2bf(b.z); t.u[7] = f2bf(b.w);
  *reinterpret_cast<uint4*>(dst) = t.v;
}

// async global->LDS, 16 B per lane. LDS dest = wave-uniform base + lane*16,
// global source address is per-lane (gather-capable).
__device__ __forceinline__ void gld16(const unsigned short* g, unsigned short* l) {
  __builtin_amdgcn_global_load_lds(
      (const __attribute__((address_space(1))) void*)g,
      (__attribute__((address_space(3))) void*)l, 16, 0, 0);
}

// ---------------------------------------------------------------------------
// 64x64 transpose tile (fp32 -> bf16): in [P][Q] per batch -> out [Q][P].
// 4x the work per block of the old 32x32 version: latency-bound fix.
// ---------------------------------------------------------------------------
__device__ __forceinline__ void tconv_tile64(
    const float* __restrict__ in, unsigned short* __restrict__ out,
    int P, int Q, int e, int bx, int by, int tid, float (*tile)[65])
{
  const long es = (long)P * Q;
  in += e * es; out += e * es;
  const int c0 = bx * 64, r0 = by * 64;
  const int r = tid >> 4, c4 = (tid & 15) * 4;
#pragma unroll
  for (int p = 0; p < 4; ++p) {
    float4 v = *reinterpret_cast<const float4*>(
        in + (long)(r0 + p * 16 + r) * Q + c0 + c4);
    tile[p * 16 + r][c4 + 0] = v.x; tile[p * 16 + r][c4 + 1] = v.y;
    tile[p * 16 + r][c4 + 2] = v.z; tile[p * 16 + r][c4 + 3] = v.w;
  }
  __syncthreads();
  const int cc = tid >> 4, rr4 = (tid & 15) * 4;
#pragma unroll
  for (int p = 0; p < 4; ++p) {
    ushort4 o;
    o.x = f2bf(tile[rr4 + 0][p * 16 + cc]);
    o.y = f2bf(tile[rr4 + 1][p * 16 + cc]);
    o.z = f2bf(tile[rr4 + 2][p * 16 + cc]);
    o.w = f2bf(tile[rr4 + 3][p * 16 + cc]);
    *reinterpret_cast<ushort4*>(out + (long)(c0 + p * 16 + cc) * P + r0 + rr4) = o;
  }
}

// ---------------------------------------------------------------------------
// LAUNCH 1: all 6 transposes (64x64 tiles) + gating + x->bf16, one launch.
//  [0,16)      Cg 256x256      [16,32)     Cu 256x256
//  [32,544)    Vd 256x1024x8   [544,1952)  Vg 256x2816x8
//  [1952,3360) Vu 256x2816x8   [3360,4768) Ud 2816x256x8
//  [4768,5280) gating (512 blocks x 4 tokens)
// ---------------------------------------------------------------------------
constexpr int TCONV_BLOCKS = 4768;
constexpr int PREP1_BLOCKS = TCONV_BLOCKS + cT / 4;

__global__ __launch_bounds__(256) void k_prep1(
    const float* __restrict__ Cg, unsigned short* __restrict__ CgT,
    const float* __restrict__ Cu, unsigned short* __restrict__ CuT,
    const float* __restrict__ Vd, unsigned short* __restrict__ VdT,
    const float* __restrict__ Vg, unsigned short* __restrict__ vgT,
    const float* __restrict__ Vu, unsigned short* __restrict__ vuT,
    const float* __restrict__ Ud, unsigned short* __restrict__ udT,
    const float* __restrict__ x, const float* __restrict__ gw,
    unsigned short* __restrict__ xb, int* __restrict__ et,
    float* __restrict__ wt)
{
  __shared__ float tile[64][65];
  int b = blockIdx.x;
  const int tid = threadIdx.x;
  if (b < TCONV_BLOCKS) {
    const float* in; unsigned short* out; int P, Q;
    if (b < 16)         { in = Cg; out = CgT; P = 256;  Q = 256;  }
    else if (b < 32)    { b -= 16;    in = Cu; out = CuT; P = 256;  Q = 256;  }
    else if (b < 544)   { b -= 32;    in = Vd; out = VdT; P = 256;  Q = 1024; }
    else if (b < 1952)  { b -= 544;   in = Vg; out = vgT; P = 256;  Q = 2816; }
    else if (b < 3360)  { b -= 1952;  in = Vu; out = vuT; P = 256;  Q = 2816; }
    else                { b -= 3360;  in = Ud; out = udT; P = 2816; Q = 256;  }
    const int tpe = (P / 64) * (Q / 64);
    const int e = b / tpe, rem = b % tpe;
    const int bx = rem % (Q / 64), by = rem / (Q / 64);
    tconv_tile64(in, out, P, Q, e, bx, by, tid, tile);
    return;
  }
  // ---- gating path ----
  const int wid = tid >> 6, lane = tid & 63;
  const int t = (b - TCONV_BLOCKS) * 4 + wid;
  const float* xr = x + (long)t * cH + lane * 16;
  float4 v0 = *reinterpret_cast<const float4*>(xr);
  float4 v1 = *reinterpret_cast<const float4*>(xr + 4);
  float4 v2 = *reinterpret_cast<const float4*>(xr + 8);
  float4 v3 = *reinterpret_cast<const float4*>(xr + 12);
  store_bf8(xb + (long)t * cH + lane * 16, v0, v1);
  store_bf8(xb + (long)t * cH + lane * 16 + 8, v2, v3);
  float xv[16];
  *reinterpret_cast<float4*>(&xv[0])  = v0;
  *reinterpret_cast<float4*>(&xv[4])  = v1;
  *reinterpret_cast<float4*>(&xv[8])  = v2;
  *reinterpret_cast<float4*>(&xv[12]) = v3;
  const float* g = gw + (long)lane * 16 * cE;
  float l[cE];
#pragma unroll
  for (int e = 0; e < cE; ++e) l[e] = 0.f;
#pragma unroll
  for (int i = 0; i < 16; ++i) {
    float4 ga = *reinterpret_cast<const float4*>(g + i * cE);
    float4 gb = *reinterpret_cast<const float4*>(g + i * cE + 4);
    float xi = xv[i];
    l[0] += xi * ga.x; l[1] += xi * ga.y; l[2] += xi * ga.z; l[3] += xi * ga.w;
    l[4] += xi * gb.x; l[5] += xi * gb.y; l[6] += xi * gb.z; l[7] += xi * gb.w;
  }
#pragma unroll
  for (int m = 1; m < 64; m <<= 1)
#pragma unroll
    for (int e = 0; e < cE; ++e)
      l[e] += __shfl_xor(l[e], m, 64);
  if (lane == 0) {
    int i0 = 0; float m0 = l[0];
#pragma unroll
    for (int e = 1; e < cE; ++e) if (l[e] > m0) { m0 = l[e]; i0 = e; }
    int i1 = -1; float m1 = -1e30f;
#pragma unroll
    for (int e = 0; e < cE; ++e) if (e != i0 && l[e] > m1) { m1 = l[e]; i1 = e; }
    float w0 = 1.f / (1.f + expf(m1 - m0));
    et[t * 2 + 0] = i0;  et[t * 2 + 1] = i1;
    wt[t * 2 + 0] = w0;  wt[t * 2 + 1] = 1.f - w0;
  }
}

// ---------------------------------------------------------------------------
// MFMA fold body: D[m][n] = sum_k A[m][k] * B[n][k],  K = 256 fixed.
// tile 128x64, BK=32, register prefetch.
// ---------------------------------------------------------------------------
__device__ __forceinline__ void foldm_body(
    const unsigned short* __restrict__ A, const float* __restrict__ B,
    unsigned short* __restrict__ D, int ldd, int m0, int n0, int tid,
    unsigned short* As, unsigned short* Bs)
{
  const int sr = tid >> 2, sk = (tid & 3) * 8;
  const unsigned short* a0 = A + (long)(m0 + sr) * 256 + sk;
  const unsigned short* a1 = a0 + (long)64 * 256;
  const float* br = B + (long)(n0 + sr) * 256 + sk;
  uint4 rA0, rA1; float4 rB0, rB1;
  auto load_slice = [&](int k0) {
    rA0 = *reinterpret_cast<const uint4*>(a0 + k0);
    rA1 = *reinterpret_cast<const uint4*>(a1 + k0);
    rB0 = *reinterpret_cast<const float4*>(br + k0);
    rB1 = *reinterpret_cast<const float4*>(br + k0 + 4);
  };
  load_slice(0);
  const int wid = tid >> 6, lane = tid & 63;
  const int wm = (wid >> 1) * 64, wn = (wid & 1) * 32;
  const int fr = lane & 15, fq = lane >> 4;
  float4v zf = {0.f, 0.f, 0.f, 0.f};
  float4v acc[4][2];
#pragma unroll
  for (int i = 0; i < 4; ++i) { acc[i][0] = zf; acc[i][1] = zf; }
  for (int k0 = 0; k0 < 256; k0 += 32) {
    *reinterpret_cast<uint4*>(&As[sr * LDA + sk]) = rA0;
    *reinterpret_cast<uint4*>(&As[(sr + 64) * LDA + sk]) = rA1;
    store_bf8(&Bs[sr * LDA + sk], rB0, rB1);
    if (k0 + 32 < 256) load_slice(k0 + 32);
    __syncthreads();
    short8 af[4], bf[2];
#pragma unroll
    for (int mi = 0; mi < 4; ++mi)
      af[mi] = *reinterpret_cast<const short8*>(&As[(wm + mi * 16 + fr) * LDA + fq * 8]);
#pragma unroll
    for (int nj = 0; nj < 2; ++nj)
      bf[nj] = *reinterpret_cast<const short8*>(&Bs[(wn + nj * 16 + fr) * LDA + fq * 8]);
#pragma unroll
    for (int mi = 0; mi < 4; ++mi)
#pragma unroll
      for (int nj = 0; nj < 2; ++nj)
        acc[mi][nj] = MFMA16(af[mi], bf[nj], acc[mi][nj], 0, 0, 0);
    __syncthreads();
  }
#pragma unroll
  for (int mi = 0; mi < 4; ++mi)
#pragma unroll
    for (int r = 0; r < 4; ++r) {
      int m = m0 + wm + mi * 16 + fq * 4 + r;
#pragma unroll
      for (int nj = 0; nj < 2; ++nj)
        D[(long)m * ldd + n0 + wn + nj * 16 + fr] = f2bf(acc[mi][nj][r]);
    }
}

// ---------------------------------------------------------------------------
// LAUNCH 2: foldm2 (b1t, 512 blocks) + foldm vd2t (256 blocks) + lists (1).
// ---------------------------------------------------------------------------
constexpr int PREP2_BLOCKS = 512 + 256 + 1;
__global__ __launch_bounds__(256, 2) void k_prep2(
    const unsigned short* __restrict__ CgT, const unsigned short* __restrict__ CuT,
    const float* __restrict__ Ug, const float* __restrict__ Uu,
    unsigned short* __restrict__ b1t,
    const unsigned short* __restrict__ VdT, const float* __restrict__ Cd,
    unsigned short* __restrict__ vd2t,
    const int* __restrict__ et, int* __restrict__ rowmap,
    int* __restrict__ tok, int* __restrict__ cnt, int* __restrict__ off)
{
  __shared__ __align__(16) unsigned short As[128 * LDA], Bs[64 * LDA];
  __shared__ int sc_[cE], sp_[cE], so_[cE];
  const int b = blockIdx.x;
  const int tid = threadIdx.x;
  if (b < 512) {
    // merged gate+up b1t fold: z = sel<<3 | e; grid was (16, 2, 16)
    const int bx = b & 15, by = (b >> 4) & 1, z = b >> 5;
    const int sel = z >> 3, e = z & 7;
    const unsigned short* A = sel ? CuT : CgT;
    const float* B = (sel ? Uu : Ug) + (long)e * cH * cR;
    unsigned short* Dp = b1t + (long)e * 512 * 1024 + (long)sel * 256 * 1024;
    foldm_body(A, B, Dp, cH, by * 128, bx * 64, tid, As, Bs);
  } else if (b < 768) {
    // vd2t fold: grid was (4, 8, 8)
    const int b2 = b - 512;
    const int bx = b2 & 3, by = (b2 >> 2) & 7, e = b2 >> 5;
    foldm_body(VdT + (long)e * cH * cR, Cd, vd2t + (long)e * cH * 256, cR,
               by * 128, bx * 64, tid, As, Bs);
  } else {
    // ---- lists path (single block) ----
    if (tid < cE) { sc_[tid] = 0; sp_[tid] = 0; }
    __syncthreads();
    for (int i = tid; i < ROWS; i += 256) atomicAdd(&sc_[et[i]], 1);
    __syncthreads();
    if (tid == 0) {
      int s = 0;
      for (int e = 0; e < cE; ++e) { so_[e] = s; s += sc_[e]; }
    }
    __syncthreads();
    for (int i = tid; i < ROWS; i += 256) {
      int e = et[i];
      int slot = atomicAdd(&sp_[e], 1);
      int cr = so_[e] + slot;
      rowmap[i] = cr;
      tok[cr] = i >> 1;
    }
    if (tid < cE) { cnt[tid] = sc_[tid]; off[tid] = so_[tid]; }
  }
}

// ---------------------------------------------------------------------------
// COMPACT t1 GEMM: t1[o+row] = xb[tok[o+row]] @ b1t[e]^T   (K=1024, N=512)
// tile 128x64, BK=64, gather via per-lane global_load_lds source addresses.
// grid = (512/64, cT/128, E), early-return past cnt[e].
// ---------------------------------------------------------------------------
__global__ __launch_bounds__(256, 2) void k_t1c(
    const unsigned short* __restrict__ xb, const unsigned short* __restrict__ b1t,
    unsigned short* __restrict__ t1, const int* __restrict__ tok,
    const int* __restrict__ cnt, const int* __restrict__ off)
{
  __shared__ __align__(16) unsigned short As[128 * 64], Bs[64 * 64];
  const int e = blockIdx.z, c = cnt[e], o = off[e];
  const int m0 = blockIdx.y * 128;
  if (m0 >= c) return;
  const int n0 = blockIdx.x * 64;
  const int tid = threadIdx.x;
  const int wid = tid >> 6, lane = tid & 63;
  const int sr8 = lane >> 3, sc = (lane & 7) * 8;
  const unsigned short* gA[4];
#pragma unroll
  for (int j = 0; j < 4; ++j) {
    int row = min(m0 + wid * 32 + j * 8 + sr8, c - 1);
    gA[j] = xb + (long)tok[o + row] * cH + sc;
  }
  const unsigned short* gB = b1t + (long)e * 512 * 1024 +
      (long)(n0 + wid * 16 + sr8) * 1024 + sc;
  unsigned short* lA = As + wid * 32 * 64;   // wave-uniform dest
  unsigned short* lB = Bs + wid * 16 * 64;
  const int wm = (wid >> 1) * 64, wn = (wid & 1) * 32;
  const int fr = lane & 15, fq = lane >> 4;
  float4v zf = {0.f, 0.f, 0.f, 0.f};
  float4v acc[4][2];
#pragma unroll
  for (int i = 0; i < 4; ++i) { acc[i][0] = zf; acc[i][1] = zf; }
  for (int k0 = 0; k0 < cH; k0 += 64) {
#pragma unroll
    for (int j = 0; j < 4; ++j) gld16(gA[j] + k0, lA + j * 8 * 64);
    gld16(gB + k0, lB);
    gld16(gB + (long)8 * 1024 + k0, lB + 8 * 64);
    __syncthreads();
#pragma unroll
    for (int ks = 0; ks < 2; ++ks) {
      short8 af[4], bf[2];
#pragma unroll
      for (int mi = 0; mi < 4; ++mi)
        af[mi] = *reinterpret_cast<const short8*>(
            &As[(wm + mi * 16 + fr) * 64 + ks * 32 + fq * 8]);
#pragma unroll
      for (int nj = 0; nj < 2; ++nj)
        bf[nj] = *reinterpret_cast<const short8*>(
            &Bs[(wn + nj * 16 + fr) * 64 + ks * 32 + fq * 8]);
#pragma unroll
      for (int mi = 0; mi < 4; ++mi)
#pragma unroll
        for (int nj = 0; nj < 2; ++nj)
          acc[mi][nj] = MFMA16(af[mi], bf[nj], acc[mi][nj], 0, 0, 0);
    }
    __syncthreads();
  }
#pragma unroll
  for (int mi = 0; mi < 4; ++mi)
#pragma unroll
    for (int r = 0; r < 4; ++r) {
      int row = m0 + wm + mi * 16 + fq * 4 + r;
      if (row < c) {
#pragma unroll
        for (int nj = 0; nj < 2; ++nj)
          t1[(long)(o + row) * 512 + n0 + wn + nj * 16 + fr] = f2bf(acc[mi][nj][r]);
      }
    }
}

// ---------------------------------------------------------------------------
// dual GEMM: a = silu(t1g @ vgT^T) * (t1u @ vuT^T)  [rows x F], K=256
// async staging, unpadded LDS, BK=64 (half the barriers of BK=32).
// grid = (44, 16, E)
// ---------------------------------------------------------------------------
__global__ __launch_bounds__(256, 2) void k_act(
    const unsigned short* __restrict__ t1,
    const unsigned short* __restrict__ vgT, const unsigned short* __restrict__ vuT,
    unsigned short* __restrict__ a, const int* __restrict__ cnt,
    const int* __restrict__ off)
{
  __shared__ __align__(16) unsigned short Ag[128 * 64], Au[128 * 64];
  __shared__ __align__(16) unsigned short Bg[64 * 64],  Bu[64 * 64];
  const int e = blockIdx.z, c = cnt[e], o = off[e];
  const int m0 = blockIdx.y * 128;
  if (m0 >= c) return;
  const int n0 = blockIdx.x * 64;
  const int tid = threadIdx.x;
  const int wid = tid >> 6, lane = tid & 63;
  const int sr8 = lane >> 3, sc8 = (lane & 7) * 8;
  // A: per wave 32 rows (4 groups of 8); row length 512 (g [0,256), u [256,512))
  const unsigned short* gA[4];
#pragma unroll
  for (int j = 0; j < 4; ++j) {
    int row = o + min(m0 + wid * 32 + j * 8 + sr8, c - 1);
    gA[j] = t1 + (long)row * 512 + sc8;
  }
  const unsigned short* gBg = vgT + (long)e * cF * 256 +
      (long)(n0 + wid * 16 + sr8) * 256 + sc8;
  const unsigned short* gBu = vuT + (long)e * cF * 256 +
      (long)(n0 + wid * 16 + sr8) * 256 + sc8;
  unsigned short* lAg = Ag + wid * 32 * 64;
  unsigned short* lAu = Au + wid * 32 * 64;
  unsigned short* lBg = Bg + wid * 16 * 64;
  unsigned short* lBu = Bu + wid * 16 * 64;
  const int wm = (wid >> 1) * 64, wn = (wid & 1) * 32;
  const int fr = lane & 15, fq = lane >> 4;
  float4v zf = {0.f, 0.f, 0.f, 0.f};
  float4v accg[4][2], accu[4][2];
#pragma unroll
  for (int i = 0; i < 4; ++i) { accg[i][0] = zf; accg[i][1] = zf; accu[i][0] = zf; accu[i][1] = zf; }
  for (int k0 = 0; k0 < 256; k0 += 64) {
#pragma unroll
    for (int j = 0; j < 4; ++j) gld16(gA[j] + k0,       lAg + j * 8 * 64);
#pragma unroll
    for (int j = 0; j < 4; ++j) gld16(gA[j] + 256 + k0, lAu + j * 8 * 64);
#pragma unroll
    for (int j = 0; j < 2; ++j) {
      gld16(gBg + (long)j * 8 * 256 + k0, lBg + j * 8 * 64);
      gld16(gBu + (long)j * 8 * 256 + k0, lBu + j * 8 * 64);
    }
    __syncthreads();
#pragma unroll
    for (int ks = 0; ks < 2; ++ks) {
      short8 ag[4], au[4], bg[2], bu[2];
#pragma unroll
      for (int mi = 0; mi < 4; ++mi) {
        ag[mi] = *reinterpret_cast<const short8*>(
            &Ag[(wm + mi * 16 + fr) * 64 + ks * 32 + fq * 8]);
        au[mi] = *reinterpret_cast<const short8*>(
            &Au[(wm + mi * 16 + fr) * 64 + ks * 32 + fq * 8]);
      }
#pragma unroll
      for (int nj = 0; nj < 2; ++nj) {
        bg[nj] = *reinterpret_cast<const short8*>(
            &Bg[(wn + nj * 16 + fr) * 64 + ks * 32 + fq * 8]);
        bu[nj] = *reinterpret_cast<const short8*>(
            &Bu[(wn + nj * 16 + fr) * 64 + ks * 32 + fq * 8]);
      }
#pragma unroll
      for (int mi = 0; mi < 4; ++mi)
#pragma unroll
        for (int nj = 0; nj < 2; ++nj) {
          accg[mi][nj] = MFMA16(ag[mi], bg[nj], accg[mi][nj], 0, 0, 0);
          accu[mi][nj] = MFMA16(au[mi], bu[nj], accu[mi][nj], 0, 0, 0);
        }
    }
    __syncthreads();
  }
#pragma unroll
  for (int mi = 0; mi < 4; ++mi)
#pragma unroll
    for (int r = 0; r < 4; ++r) {
      int row = m0 + wm + mi * 16 + fq * 4 + r;
      if (row < c) {
#pragma unroll
        for (int nj = 0; nj < 2; ++nj) {
          float g = accg[mi][nj][r];
          float u = accu[mi][nj][r];
          float s = g / (1.f + expf(-g)) * u;
          a[(long)(o + row) * cF + n0 + wn + nj * 16 + fr] = f2bf(s);
        }
      }
    }
}

// ---------------------------------------------------------------------------
// t3p[ks] = a @ udT^T (split-K=2, fp32 partial stores).  [2][ROWS][256].
// async staging, unpadded LDS [64][64], BK=64, clamped rows, 22 iters.
// grid = (8, 32, E): x = n(0..3) | ksp(0..1)<<2  -> ~512 effective blocks.
// ---------------------------------------------------------------------------
__global__ __launch_bounds__(256, 2) void k_t3(
    const unsigned short* __restrict__ a, const unsigned short* __restrict__ udT,
    float* __restrict__ t3p, const int* __restrict__ cnt,
    const int* __restrict__ off)
{
  __shared__ __align__(16) unsigned short As[64 * 64], Bs[64 * 64];
  const int e = blockIdx.z, c = cnt[e], o = off[e];
  const int m0 = blockIdx.y * 64;
  if (m0 >= c) return;
  const int n0 = (blockIdx.x & 3) * 64;
  const int ksp = blockIdx.x >> 2;                 // 0..1
  const int kbase = ksp * 1408;
  const int tid = threadIdx.x;
  const int wid = tid >> 6, lane = tid & 63;
  const int sr8 = lane >> 3, sc = (lane & 7) * 8;
  const int ra0 = o + min(m0 + wid * 16 + sr8, c - 1);
  const int ra1 = o + min(m0 + wid * 16 + 8 + sr8, c - 1);
  const unsigned short* gA0 = a + (long)ra0 * cF + kbase + sc;
  const unsigned short* gA1 = a + (long)ra1 * cF + kbase + sc;
  const unsigned short* gB  = udT + (long)e * 256 * cF + (long)(n0 + wid * 16 + sr8) * cF + kbase + sc;
  unsigned short* lA = As + wid * 16 * 64;
  unsigned short* lB = Bs + wid * 16 * 64;
  const int wm = (wid >> 1) * 32, wn = (wid & 1) * 32;
  const int fr = lane & 15, fq = lane >> 4;
  float4v zf = {0.f, 0.f, 0.f, 0.f};
  float4v acc[2][2] = {{zf, zf}, {zf, zf}};
  for (int k0 = 0; k0 < 1408; k0 += 64) {
    gld16(gA0 + k0, lA);
    gld16(gA1 + k0, lA + 8 * 64);
    gld16(gB + k0, lB);
    gld16(gB + (long)8 * cF + k0, lB + 8 * 64);
    __syncthreads();
#pragma unroll
    for (int ks = 0; ks < 2; ++ks) {
      short8 af[2], bf[2];
#pragma unroll
      for (int mi = 0; mi < 2; ++mi)
        af[mi] = *reinterpret_cast<const short8*>(
            &As[(wm + mi * 16 + fr) * 64 + ks * 32 + fq * 8]);
#pragma unroll
      for (int nj = 0; nj < 2; ++nj)
        bf[nj] = *reinterpret_cast<const short8*>(
            &Bs[(wn + nj * 16 + fr) * 64 + ks * 32 + fq * 8]);
#pragma unroll
      for (int mi = 0; mi < 2; ++mi)
#pragma unroll
        for (int nj = 0; nj < 2; ++nj)
          acc[mi][nj] = MFMA16(af[mi], bf[nj], acc[mi][nj], 0, 0, 0);
    }
    __syncthreads();
  }
  float* dstbase = t3p + (long)ksp * ROWS * 256;
#pragma unroll
  for (int mi = 0; mi < 2; ++mi)
#pragma unroll
    for (int r = 0; r < 4; ++r) {
      int row = m0 + wm + mi * 16 + fq * 4 + r;
      if (row < c) {
        float* dst = dstbase + (long)(o + row) * 256 + n0 + wn;
#pragma unroll
        for (int nj = 0; nj < 2; ++nj)
          dst[nj * 16 + fr] = acc[mi][nj][r];
      }
    }
}

// ---------------------------------------------------------------------------
// t3b bf16 = sum of 2 fp32 t3p partials (pure streaming). grid = 512.
// ---------------------------------------------------------------------------
__global__ __launch_bounds__(256) void k_red2(
    const float* __restrict__ t3p, unsigned short* __restrict__ t3b)
{
  const long psz = (long)ROWS * 256;
  long i = ((long)blockIdx.x * 256 + threadIdx.x) * 8;
  float4 s0 = *reinterpret_cast<const float4*>(t3p + i);
  float4 s1 = *reinterpret_cast<const float4*>(t3p + i + 4);
  float4 a0 = *reinterpret_cast<const float4*>(t3p + psz + i);
  float4 a1 = *reinterpret_cast<const float4*>(t3p + psz + i + 4);
  s0.x += a0.x; s0.y += a0.y; s0.z += a0.z; s0.w += a0.w;
  s1.x += a1.x; s1.y += a1.y; s1.z += a1.z; s1.w += a1.w;
  store_bf8(t3b + i, s0, s1);
}

// ---------------------------------------------------------------------------
// y = t3b @ vd2t^T   [rows x 1024] bf16, plain stores. K = 256.
// async staging, unpadded LDS, BK=32. grid = (16, 16, E)
// ---------------------------------------------------------------------------
__global__ __launch_bounds__(256, 2) void k_y(
    const unsigned short* __restrict__ t3b, const unsigned short* __restrict__ vd2t,
    unsigned short* __restrict__ y, const int* __restrict__ cnt,
    const int* __restrict__ off)
{
  __shared__ __align__(16) unsigned short As[128 * 32], Bs[64 * 32];
  const int e = blockIdx.z, c = cnt[e], o = off[e];
  const int m0 = blockIdx.y * 128;
  if (m0 >= c) return;
  const int n0 = blockIdx.x * 64;
  const int tid = threadIdx.x;
  const int wid = tid >> 6, lane = tid & 63;
  const int sr16 = lane >> 2, sc = (lane & 3) * 8;
  const int ra0 = o + min(m0 + wid * 32 + sr16, c - 1);
  const int ra1 = o + min(m0 + wid * 32 + 16 + sr16, c - 1);
  const unsigned short* gA0 = t3b + (long)ra0 * 256 + sc;
  const unsigned short* gA1 = t3b + (long)ra1 * 256 + sc;
  const unsigned short* gB  = vd2t + (long)e * cH * 256 + (long)(n0 + wid * 16 + sr16) * 256 + sc;
  unsigned short* lA = As + wid * 32 * 32;
  unsigned short* lB = Bs + wid * 16 * 32;
  const int wm = (wid >> 1) * 64, wn = (wid & 1) * 32;
  const int fr = lane & 15, fq = lane >> 4;
  float4v zf = {0.f, 0.f, 0.f, 0.f};
  float4v acc[4][2];
#pragma unroll
  for (int i = 0; i < 4; ++i) { acc[i][0] = zf; acc[i][1] = zf; }
  for (int k0 = 0; k0 < 256; k0 += 32) {
    gld16(gA0 + k0, lA);
    gld16(gA1 + k0, lA + 16 * 32);
    gld16(gB + k0, lB);
    __syncthreads();
    short8 af[4], bf[2];
#pragma unroll
    for (int mi = 0; mi < 4; ++mi)
      af[mi] = *reinterpret_cast<const short8*>(&As[(wm + mi * 16 + fr) * 32 + fq * 8]);
#pragma unroll
    for (int nj = 0; nj < 2; ++nj)
      bf[nj] = *reinterpret_cast<const short8*>(&Bs[(wn + nj * 16 + fr) * 32 + fq * 8]);
#pragma unroll
    for (int mi = 0; mi < 4; ++mi)
#pragma unroll
      for (int nj = 0; nj < 2; ++nj)
        acc[mi][nj] = MFMA16(af[mi], bf[nj], acc[mi][nj], 0, 0, 0);
    __syncthreads();
  }
#pragma unroll
  for (int mi = 0; mi < 4; ++mi)
#pragma unroll
    for (int r = 0; r < 4; ++r) {
      int row = m0 + wm + mi * 16 + fq * 4 + r;
      if (row < c) {
#pragma unroll
        for (int nj = 0; nj < 2; ++nj)
          y[(long)(o + row) * cH + n0 + wn + nj * 16 + fr] = f2bf(acc[mi][nj][r]);
      }
    }
}

// ---------------------------------------------------------------------------
// out[t] = w0 * y[rowmap[2t]] + w1 * y[rowmap[2t+1]]   (pure write, no zero)
// ---------------------------------------------------------------------------
__global__ __launch_bounds__(256) void k_combine(
    const unsigned short* __restrict__ y, const float* __restrict__ wt,
    const int* __restrict__ rowmap, float* __restrict__ out)
{
  const int tid = threadIdx.x;
  const int t = blockIdx.x * 2 + (tid >> 7);
  const int h = (tid & 127) * 8;
  const int r0 = rowmap[2 * t], r1 = rowmap[2 * t + 1];
  const float w0 = wt[2 * t], w1 = wt[2 * t + 1];
  union { uint4 v; unsigned short s[8]; } ua, ub;
  ua.v = *reinterpret_cast<const uint4*>(y + (long)r0 * cH + h);
  ub.v = *reinterpret_cast<const uint4*>(y + (long)r1 * cH + h);
  float o[8];
#pragma unroll
  for (int i = 0; i < 8; ++i)
    o[i] = w0 * bf2f(ua.s[i]) + w1 * bf2f(ub.s[i]);
  float* dst = out + (long)t * cH + h;
  *reinterpret_cast<float4*>(dst)     = make_float4(o[0], o[1], o[2], o[3]);
  *reinterpret_cast<float4*>(dst + 4) = make_float4(o[4], o[5], o[6], o[7]);
}

// ---------------------------------------------------------------------------
extern "C" void kernel_launch(void* const* d_in, const int* in_sizes, int n_in,
                              void* d_out, int out_size, void* d_ws, size_t ws_size,
                              hipStream_t stream)
{
  const float* x  = (const float*)d_in[0];
  const float* gw = (const float*)d_in[1];
  const float* Ug = (const float*)d_in[2];
  const float* Cg = (const float*)d_in[3];
  const float* Vg = (const float*)d_in[4];
  const float* Uu = (const float*)d_in[5];
  const float* Cu = (const float*)d_in[6];
  const float* Vu = (const float*)d_in[7];
  const float* Ud = (const float*)d_in[8];
  const float* Cd = (const float*)d_in[9];
  const float* Vd = (const float*)d_in[10];
  float* out = (float*)d_out;

  // workspace layout (~83 MiB peak, with aliasing)
  char* w = (char*)d_ws;
  // region 0: vgT (11.53 MB, phase-1); phase-2: t3p (2 x 4.19 MB fp32
  // partials = 8.39) + t3b (2.1 MB bf16) alias it (10.5 <= 11.53)
  unsigned short* vgT = (unsigned short*)w;
  float*          t3p = (float*)w;
  unsigned short* t3b = (unsigned short*)(w + (long)2 * ROWS * 256 * 4);
  w += (long)cE * cF * 256 * 2;                                               // 11.53
  unsigned short* b1t = (unsigned short*)w;  w += (long)cE * 512 * 1024 * 2;  // 8.39
  unsigned short* vd2t = (unsigned short*)w; w += (long)cE * cH * 256 * 2;    // 4.19
  // vuT phase-1; yb (8.39) aliases it in phase 2
  unsigned short* vuT = (unsigned short*)w;
  unsigned short* yb  = (unsigned short*)w;  w += (long)cE * cF * 256 * 2;    // 11.53
  unsigned short* udT = (unsigned short*)w;  w += (long)cE * 256 * cF * 2;    // 11.53
  unsigned short* VdT = (unsigned short*)w;  w += (long)cE * cH * 256 * 2;    // 4.19
  unsigned short* xb  = (unsigned short*)w;  w += (long)cT * cH * 2;          // 4.19
  unsigned short* CgT = (unsigned short*)w;  w += (long)cR * cR * 2;          // 0.13
  unsigned short* CuT = (unsigned short*)w;  w += (long)cR * cR * 2;          // 0.13
  unsigned short* t1  = (unsigned short*)w;  w += (long)ROWS * 512 * 2;       // 4.19
  unsigned short* ab  = (unsigned short*)w;  w += (long)ROWS * cF * 2;        // 23.07
  float* wt   = (float*)w; w += ROWS * 4;
  int* et     = (int*)w; w += ROWS * 4;
  int* rowmap = (int*)w; w += ROWS * 4;
  int* tok    = (int*)w; w += ROWS * 4;
  int* cnt = (int*)w; w += cE * 4;
  int* off = (int*)w; w += cE * 4;

  // L1: all transposes (64x64 tiles) + gating + x->bf16
  k_prep1<<<dim3(PREP1_BLOCKS), dim3(256), 0, stream>>>(
      Cg, CgT, Cu, CuT, Vd, VdT, Vg, vgT, Vu, vuT, Ud, udT, x, gw, xb, et, wt);
  // L2: b1t fold + vd2t fold + routing lists
  k_prep2<<<dim3(PREP2_BLOCKS), dim3(256), 0, stream>>>(
      CgT, CuT, Ug, Uu, b1t, VdT, Cd, vd2t, et, rowmap, tok, cnt, off);
  // L3: compact t1 GEMM (gathered A rows, per-expert B)
  k_t1c<<<dim3(8, cT / 128, cE), dim3(256), 0, stream>>>(xb, b1t, t1, tok, cnt, off);
  // L4: a = silu(t1g @ Vg) * (t1u @ Vu)  (BK=64)
  k_act<<<dim3(cF / 64, cT / 128, cE), dim3(256), 0, stream>>>(t1, vgT, vuT, ab, cnt, off);
  // L5: t3p = a @ Ud (split-K=2, fp32 partials; aliases dead vgT)
  k_t3<<<dim3(8, cT / 64, cE), dim3(256), 0, stream>>>(ab, udT, t3p, cnt, off);
  // L6: t3b = bf16(p0 + p1)
  k_red2<<<dim3(ROWS * 256 / (256 * 8)), dim3(256), 0, stream>>>(t3p, t3b);
  // L7: y = t3b @ Vd2 (aliases dead vuT)
  k_y<<<dim3(cH / 64, cT / 128, cE), dim3(256), 0, stream>>>(t3b, vd2t, yb, cnt, off);
  // L8: out = w0*y[r0] + w1*y[r1]
  k_combine<<<dim3(cT / 2), dim3(256), 0, stream>>>(yb, wt, rowmap, out);
}

// Round 4
// 279.546 us; speedup vs baseline: 1.1021x; 1.0903x over previous
//
#include <hip/hip_runtime.h>
#include <math.h>

constexpr int cE = 8;
constexpr int cH = 1024;
constexpr int cF = 2816;
constexpr int cR = 256;
constexpr int cT = 2048;
constexpr int ROWS = cT * 2;   // total routed (token, expert) rows = T*K
constexpr int LDA = 40;        // padded LDS row stride (foldm reg-staged kernel)

using short8  = __attribute__((ext_vector_type(8))) short;
using float4v = __attribute__((ext_vector_type(4))) float;
#define MFMA16 __builtin_amdgcn_mfma_f32_16x16x32_bf16

__device__ __forceinline__ unsigned short f2bf(float f) {
  union { float f; unsigned u; } v; v.f = f;
  unsigned r = v.u + 0x7fffu + ((v.u >> 16) & 1u);   // RNE
  return (unsigned short)(r >> 16);
}
__device__ __forceinline__ float bf2f(unsigned short s) {
  union { unsigned u; float f; } v; v.u = (unsigned)s << 16; return v.f;
}

// pack 8 fp32 -> 8 bf16, single 16B store
__device__ __forceinline__ void store_bf8(unsigned short* dst, float4 a, float4 b) {
  union { unsigned short u[8]; uint4 v; } t;
  t.u[0] = f2bf(a.x); t.u[1] = f2bf(a.y); t.u[2] = f2bf(a.z); t.u[3] = f2bf(a.w);
  t.u[4] = f2bf(b.x); t.u[5] = f2bf(b.y); t.u[6] = f2bf(b.z); t.u[7] = f2bf(b.w);
  *reinterpret_cast<uint4*>(dst) = t.v;
}

// async global->LDS, 16 B per lane. LDS dest = wave-uniform base + lane*16,
// global source address is per-lane (gather/swizzle-capable).
__device__ __forceinline__ void gld16(const unsigned short* g, unsigned short* l) {
  __builtin_amdgcn_global_load_lds(
      (const __attribute__((address_space(1))) void*)g,
      (__attribute__((address_space(3))) void*)l, 16, 0, 0);
}

// ---------------------------------------------------------------------------
// 64x64 transpose tile (fp32 -> bf16): in [P][Q] per batch -> out [Q][P].
// ---------------------------------------------------------------------------
__device__ __forceinline__ void tconv_tile64(
    const float* __restrict__ in, unsigned short* __restrict__ out,
    int P, int Q, int e, int bx, int by, int tid, float (*tile)[65])
{
  const long es = (long)P * Q;
  in += e * es; out += e * es;
  const int c0 = bx * 64, r0 = by * 64;
  const int r = tid >> 4, c4 = (tid & 15) * 4;
#pragma unroll
  for (int p = 0; p < 4; ++p) {
    float4 v = *reinterpret_cast<const float4*>(
        in + (long)(r0 + p * 16 + r) * Q + c0 + c4);
    tile[p * 16 + r][c4 + 0] = v.x; tile[p * 16 + r][c4 + 1] = v.y;
    tile[p * 16 + r][c4 + 2] = v.z; tile[p * 16 + r][c4 + 3] = v.w;
  }
  __syncthreads();
  const int cc = tid >> 4, rr4 = (tid & 15) * 4;
#pragma unroll
  for (int p = 0; p < 4; ++p) {
    ushort4 o;
    o.x = f2bf(tile[rr4 + 0][p * 16 + cc]);
    o.y = f2bf(tile[rr4 + 1][p * 16 + cc]);
    o.z = f2bf(tile[rr4 + 2][p * 16 + cc]);
    o.w = f2bf(tile[rr4 + 3][p * 16 + cc]);
    *reinterpret_cast<ushort4*>(out + (long)(c0 + p * 16 + cc) * P + r0 + rr4) = o;
  }
}

// ---------------------------------------------------------------------------
// LAUNCH 1: all 6 transposes (64x64 tiles) + gating + x->bf16, one launch.
// ---------------------------------------------------------------------------
constexpr int TCONV_BLOCKS = 4768;
constexpr int PREP1_BLOCKS = TCONV_BLOCKS + cT / 4;

__global__ __launch_bounds__(256) void k_prep1(
    const float* __restrict__ Cg, unsigned short* __restrict__ CgT,
    const float* __restrict__ Cu, unsigned short* __restrict__ CuT,
    const float* __restrict__ Vd, unsigned short* __restrict__ VdT,
    const float* __restrict__ Vg, unsigned short* __restrict__ vgT,
    const float* __restrict__ Vu, unsigned short* __restrict__ vuT,
    const float* __restrict__ Ud, unsigned short* __restrict__ udT,
    const float* __restrict__ x, const float* __restrict__ gw,
    unsigned short* __restrict__ xb, int* __restrict__ et,
    float* __restrict__ wt)
{
  __shared__ float tile[64][65];
  int b = blockIdx.x;
  const int tid = threadIdx.x;
  if (b < TCONV_BLOCKS) {
    const float* in; unsigned short* out; int P, Q;
    if (b < 16)         { in = Cg; out = CgT; P = 256;  Q = 256;  }
    else if (b < 32)    { b -= 16;    in = Cu; out = CuT; P = 256;  Q = 256;  }
    else if (b < 544)   { b -= 32;    in = Vd; out = VdT; P = 256;  Q = 1024; }
    else if (b < 1952)  { b -= 544;   in = Vg; out = vgT; P = 256;  Q = 2816; }
    else if (b < 3360)  { b -= 1952;  in = Vu; out = vuT; P = 256;  Q = 2816; }
    else                { b -= 3360;  in = Ud; out = udT; P = 2816; Q = 256;  }
    const int tpe = (P / 64) * (Q / 64);
    const int e = b / tpe, rem = b % tpe;
    const int bx = rem % (Q / 64), by = rem / (Q / 64);
    tconv_tile64(in, out, P, Q, e, bx, by, tid, tile);
    return;
  }
  // ---- gating path ----
  const int wid = tid >> 6, lane = tid & 63;
  const int t = (b - TCONV_BLOCKS) * 4 + wid;
  const float* xr = x + (long)t * cH + lane * 16;
  float4 v0 = *reinterpret_cast<const float4*>(xr);
  float4 v1 = *reinterpret_cast<const float4*>(xr + 4);
  float4 v2 = *reinterpret_cast<const float4*>(xr + 8);
  float4 v3 = *reinterpret_cast<const float4*>(xr + 12);
  store_bf8(xb + (long)t * cH + lane * 16, v0, v1);
  store_bf8(xb + (long)t * cH + lane * 16 + 8, v2, v3);
  float xv[16];
  *reinterpret_cast<float4*>(&xv[0])  = v0;
  *reinterpret_cast<float4*>(&xv[4])  = v1;
  *reinterpret_cast<float4*>(&xv[8])  = v2;
  *reinterpret_cast<float4*>(&xv[12]) = v3;
  const float* g = gw + (long)lane * 16 * cE;
  float l[cE];
#pragma unroll
  for (int e = 0; e < cE; ++e) l[e] = 0.f;
#pragma unroll
  for (int i = 0; i < 16; ++i) {
    float4 ga = *reinterpret_cast<const float4*>(g + i * cE);
    float4 gb = *reinterpret_cast<const float4*>(g + i * cE + 4);
    float xi = xv[i];
    l[0] += xi * ga.x; l[1] += xi * ga.y; l[2] += xi * ga.z; l[3] += xi * ga.w;
    l[4] += xi * gb.x; l[5] += xi * gb.y; l[6] += xi * gb.z; l[7] += xi * gb.w;
  }
#pragma unroll
  for (int m = 1; m < 64; m <<= 1)
#pragma unroll
    for (int e = 0; e < cE; ++e)
      l[e] += __shfl_xor(l[e], m, 64);
  if (lane == 0) {
    int i0 = 0; float m0 = l[0];
#pragma unroll
    for (int e = 1; e < cE; ++e) if (l[e] > m0) { m0 = l[e]; i0 = e; }
    int i1 = -1; float m1 = -1e30f;
#pragma unroll
    for (int e = 0; e < cE; ++e) if (e != i0 && l[e] > m1) { m1 = l[e]; i1 = e; }
    float w0 = 1.f / (1.f + expf(m1 - m0));
    et[t * 2 + 0] = i0;  et[t * 2 + 1] = i1;
    wt[t * 2 + 0] = w0;  wt[t * 2 + 1] = 1.f - w0;
  }
}

// ---------------------------------------------------------------------------
// MFMA fold body: D[m][n] = sum_k A[m][k] * B[n][k],  K = 256 fixed.
// tile 128x64, BK=32, register prefetch.
// ---------------------------------------------------------------------------
__device__ __forceinline__ void foldm_body(
    const unsigned short* __restrict__ A, const float* __restrict__ B,
    unsigned short* __restrict__ D, int ldd, int m0, int n0, int tid,
    unsigned short* As, unsigned short* Bs)
{
  const int sr = tid >> 2, sk = (tid & 3) * 8;
  const unsigned short* a0 = A + (long)(m0 + sr) * 256 + sk;
  const unsigned short* a1 = a0 + (long)64 * 256;
  const float* br = B + (long)(n0 + sr) * 256 + sk;
  uint4 rA0, rA1; float4 rB0, rB1;
  auto load_slice = [&](int k0) {
    rA0 = *reinterpret_cast<const uint4*>(a0 + k0);
    rA1 = *reinterpret_cast<const uint4*>(a1 + k0);
    rB0 = *reinterpret_cast<const float4*>(br + k0);
    rB1 = *reinterpret_cast<const float4*>(br + k0 + 4);
  };
  load_slice(0);
  const int wid = tid >> 6, lane = tid & 63;
  const int wm = (wid >> 1) * 64, wn = (wid & 1) * 32;
  const int fr = lane & 15, fq = lane >> 4;
  float4v zf = {0.f, 0.f, 0.f, 0.f};
  float4v acc[4][2];
#pragma unroll
  for (int i = 0; i < 4; ++i) { acc[i][0] = zf; acc[i][1] = zf; }
  for (int k0 = 0; k0 < 256; k0 += 32) {
    *reinterpret_cast<uint4*>(&As[sr * LDA + sk]) = rA0;
    *reinterpret_cast<uint4*>(&As[(sr + 64) * LDA + sk]) = rA1;
    store_bf8(&Bs[sr * LDA + sk], rB0, rB1);
    if (k0 + 32 < 256) load_slice(k0 + 32);
    __syncthreads();
    short8 af[4], bf[2];
#pragma unroll
    for (int mi = 0; mi < 4; ++mi)
      af[mi] = *reinterpret_cast<const short8*>(&As[(wm + mi * 16 + fr) * LDA + fq * 8]);
#pragma unroll
    for (int nj = 0; nj < 2; ++nj)
      bf[nj] = *reinterpret_cast<const short8*>(&Bs[(wn + nj * 16 + fr) * LDA + fq * 8]);
#pragma unroll
    for (int mi = 0; mi < 4; ++mi)
#pragma unroll
      for (int nj = 0; nj < 2; ++nj)
        acc[mi][nj] = MFMA16(af[mi], bf[nj], acc[mi][nj], 0, 0, 0);
    __syncthreads();
  }
#pragma unroll
  for (int mi = 0; mi < 4; ++mi)
#pragma unroll
    for (int r = 0; r < 4; ++r) {
      int m = m0 + wm + mi * 16 + fq * 4 + r;
#pragma unroll
      for (int nj = 0; nj < 2; ++nj)
        D[(long)m * ldd + n0 + wn + nj * 16 + fr] = f2bf(acc[mi][nj][r]);
    }
}

// ---------------------------------------------------------------------------
// LAUNCH 2: foldm2 (b1t, 512 blocks) + foldm vd2t (256 blocks) + lists (1).
// ---------------------------------------------------------------------------
constexpr int PREP2_BLOCKS = 512 + 256 + 1;
__global__ __launch_bounds__(256, 2) void k_prep2(
    const unsigned short* __restrict__ CgT, const unsigned short* __restrict__ CuT,
    const float* __restrict__ Ug, const float* __restrict__ Uu,
    unsigned short* __restrict__ b1t,
    const unsigned short* __restrict__ VdT, const float* __restrict__ Cd,
    unsigned short* __restrict__ vd2t,
    const int* __restrict__ et, int* __restrict__ rowmap,
    int* __restrict__ tok, int* __restrict__ cnt, int* __restrict__ off)
{
  __shared__ __align__(16) unsigned short As[128 * LDA], Bs[64 * LDA];
  __shared__ int sc_[cE], sp_[cE], so_[cE];
  const int b = blockIdx.x;
  const int tid = threadIdx.x;
  if (b < 512) {
    const int bx = b & 15, by = (b >> 4) & 1, z = b >> 5;
    const int sel = z >> 3, e = z & 7;
    const unsigned short* A = sel ? CuT : CgT;
    const float* B = (sel ? Uu : Ug) + (long)e * cH * cR;
    unsigned short* Dp = b1t + (long)e * 512 * 1024 + (long)sel * 256 * 1024;
    foldm_body(A, B, Dp, cH, by * 128, bx * 64, tid, As, Bs);
  } else if (b < 768) {
    const int b2 = b - 512;
    const int bx = b2 & 3, by = (b2 >> 2) & 7, e = b2 >> 5;
    foldm_body(VdT + (long)e * cH * cR, Cd, vd2t + (long)e * cH * 256, cR,
               by * 128, bx * 64, tid, As, Bs);
  } else {
    // ---- lists path (single block) ----
    if (tid < cE) { sc_[tid] = 0; sp_[tid] = 0; }
    __syncthreads();
    for (int i = tid; i < ROWS; i += 256) atomicAdd(&sc_[et[i]], 1);
    __syncthreads();
    if (tid == 0) {
      int s = 0;
      for (int e = 0; e < cE; ++e) { so_[e] = s; s += sc_[e]; }
    }
    __syncthreads();
    for (int i = tid; i < ROWS; i += 256) {
      int e = et[i];
      int slot = atomicAdd(&sp_[e], 1);
      int cr = so_[e] + slot;
      rowmap[i] = cr;
      tok[cr] = i >> 1;
    }
    if (tid < cE) { cnt[tid] = sc_[tid]; off[tid] = so_[tid]; }
  }
}

// ---------------------------------------------------------------------------
// COMPACT t1 GEMM: t1[o+row] = xb[tok[o+row]] @ b1t[e]^T   (K=1024, N=512)
// tile 128x64, BK=64, gathered A rows, LDS DOUBLE-BUFFER:
//   STAGE(t+1) -> compute(t) -> one __syncthreads() per K-step.
// grid = (8, cT/128, E), early-return past cnt[e].
// ---------------------------------------------------------------------------
__global__ __launch_bounds__(256, 3) void k_t1c(
    const unsigned short* __restrict__ xb, const unsigned short* __restrict__ b1t,
    unsigned short* __restrict__ t1, const int* __restrict__ tok,
    const int* __restrict__ cnt, const int* __restrict__ off)
{
  __shared__ __align__(16) unsigned short As[2][128 * 64], Bs[2][64 * 64];
  const int e = blockIdx.z, c = cnt[e], o = off[e];
  const int m0 = blockIdx.y * 128;
  if (m0 >= c) return;
  const int n0 = blockIdx.x * 64;
  const int tid = threadIdx.x;
  const int wid = tid >> 6, lane = tid & 63;
  const int sr8 = lane >> 3, sc = (lane & 7) * 8;
  const unsigned short* gA[4];
#pragma unroll
  for (int j = 0; j < 4; ++j) {
    int row = min(m0 + wid * 32 + j * 8 + sr8, c - 1);
    gA[j] = xb + (long)tok[o + row] * cH + sc;
  }
  const unsigned short* gB = b1t + (long)e * 512 * 1024 +
      (long)(n0 + wid * 16 + sr8) * 1024 + sc;
  const int lA = wid * 32 * 64;   // wave-uniform dest offsets
  const int lB = wid * 16 * 64;
  auto STAGE = [&](int k0, int buf) {
#pragma unroll
    for (int j = 0; j < 4; ++j) gld16(gA[j] + k0, &As[buf][lA + j * 8 * 64]);
    gld16(gB + k0, &Bs[buf][lB]);
    gld16(gB + (long)8 * 1024 + k0, &Bs[buf][lB + 8 * 64]);
  };
  const int wm = (wid >> 1) * 64, wn = (wid & 1) * 32;
  const int fr = lane & 15, fq = lane >> 4;
  float4v zf = {0.f, 0.f, 0.f, 0.f};
  float4v acc[4][2];
#pragma unroll
  for (int i = 0; i < 4; ++i) { acc[i][0] = zf; acc[i][1] = zf; }
  STAGE(0, 0);
  __syncthreads();
  for (int t = 0; t < 16; ++t) {
    const int cur = t & 1;
    if (t < 15) STAGE((t + 1) * 64, cur ^ 1);
#pragma unroll
    for (int ks = 0; ks < 2; ++ks) {
      short8 af[4], bf[2];
#pragma unroll
      for (int mi = 0; mi < 4; ++mi)
        af[mi] = *reinterpret_cast<const short8*>(
            &As[cur][(wm + mi * 16 + fr) * 64 + ks * 32 + fq * 8]);
#pragma unroll
      for (int nj = 0; nj < 2; ++nj)
        bf[nj] = *reinterpret_cast<const short8*>(
            &Bs[cur][(wn + nj * 16 + fr) * 64 + ks * 32 + fq * 8]);
#pragma unroll
      for (int mi = 0; mi < 4; ++mi)
#pragma unroll
        for (int nj = 0; nj < 2; ++nj)
          acc[mi][nj] = MFMA16(af[mi], bf[nj], acc[mi][nj], 0, 0, 0);
    }
    __syncthreads();
  }
#pragma unroll
  for (int mi = 0; mi < 4; ++mi)
#pragma unroll
    for (int r = 0; r < 4; ++r) {
      int row = m0 + wm + mi * 16 + fq * 4 + r;
      if (row < c) {
#pragma unroll
        for (int nj = 0; nj < 2; ++nj)
          t1[(long)(o + row) * 512 + n0 + wn + nj * 16 + fr] = f2bf(acc[mi][nj][r]);
      }
    }
}

// ---------------------------------------------------------------------------
// dual GEMM: a = silu(t1g @ vgT^T) * (t1u @ vuT^T)  [rows x F], K=256
// BK=32, LDS double-buffer (48 KB), one barrier per K-step. grid=(44,16,E)
// ---------------------------------------------------------------------------
__global__ __launch_bounds__(256, 3) void k_act(
    const unsigned short* __restrict__ t1,
    const unsigned short* __restrict__ vgT, const unsigned short* __restrict__ vuT,
    unsigned short* __restrict__ a, const int* __restrict__ cnt,
    const int* __restrict__ off)
{
  __shared__ __align__(16) unsigned short Ag[2][128 * 32], Au[2][128 * 32];
  __shared__ __align__(16) unsigned short Bg[2][64 * 32],  Bu[2][64 * 32];
  const int e = blockIdx.z, c = cnt[e], o = off[e];
  const int m0 = blockIdx.y * 128;
  if (m0 >= c) return;
  const int n0 = blockIdx.x * 64;
  const int tid = threadIdx.x;
  const int wid = tid >> 6, lane = tid & 63;
  const int sr16 = lane >> 2, sc = (lane & 3) * 8;
  const int ra0 = o + min(m0 + wid * 32 + sr16, c - 1);
  const int ra1 = o + min(m0 + wid * 32 + 16 + sr16, c - 1);
  const unsigned short* gAg0 = t1 + (long)ra0 * 512 + sc;
  const unsigned short* gAg1 = t1 + (long)ra1 * 512 + sc;
  const unsigned short* gBg = vgT + (long)e * cF * 256 + (long)(n0 + wid * 16 + sr16) * 256 + sc;
  const unsigned short* gBu = vuT + (long)e * cF * 256 + (long)(n0 + wid * 16 + sr16) * 256 + sc;
  const int lA = wid * 32 * 32;
  const int lB = wid * 16 * 32;
  auto STAGE = [&](int k0, int buf) {
    gld16(gAg0 + k0, &Ag[buf][lA]);
    gld16(gAg1 + k0, &Ag[buf][lA + 16 * 32]);
    gld16(gAg0 + 256 + k0, &Au[buf][lA]);
    gld16(gAg1 + 256 + k0, &Au[buf][lA + 16 * 32]);
    gld16(gBg + k0, &Bg[buf][lB]);
    gld16(gBu + k0, &Bu[buf][lB]);
  };
  const int wm = (wid >> 1) * 64, wn = (wid & 1) * 32;
  const int fr = lane & 15, fq = lane >> 4;
  float4v zf = {0.f, 0.f, 0.f, 0.f};
  float4v accg[4][2], accu[4][2];
#pragma unroll
  for (int i = 0; i < 4; ++i) { accg[i][0] = zf; accg[i][1] = zf; accu[i][0] = zf; accu[i][1] = zf; }
  STAGE(0, 0);
  __syncthreads();
  for (int t = 0; t < 8; ++t) {
    const int cur = t & 1;
    if (t < 7) STAGE((t + 1) * 32, cur ^ 1);
    short8 ag[4], au[4], bg[2], bu[2];
#pragma unroll
    for (int mi = 0; mi < 4; ++mi) {
      ag[mi] = *reinterpret_cast<const short8*>(&Ag[cur][(wm + mi * 16 + fr) * 32 + fq * 8]);
      au[mi] = *reinterpret_cast<const short8*>(&Au[cur][(wm + mi * 16 + fr) * 32 + fq * 8]);
    }
#pragma unroll
    for (int nj = 0; nj < 2; ++nj) {
      bg[nj] = *reinterpret_cast<const short8*>(&Bg[cur][(wn + nj * 16 + fr) * 32 + fq * 8]);
      bu[nj] = *reinterpret_cast<const short8*>(&Bu[cur][(wn + nj * 16 + fr) * 32 + fq * 8]);
    }
#pragma unroll
    for (int mi = 0; mi < 4; ++mi)
#pragma unroll
      for (int nj = 0; nj < 2; ++nj) {
        accg[mi][nj] = MFMA16(ag[mi], bg[nj], accg[mi][nj], 0, 0, 0);
        accu[mi][nj] = MFMA16(au[mi], bu[nj], accu[mi][nj], 0, 0, 0);
      }
    __syncthreads();
  }
#pragma unroll
  for (int mi = 0; mi < 4; ++mi)
#pragma unroll
    for (int r = 0; r < 4; ++r) {
      int row = m0 + wm + mi * 16 + fq * 4 + r;
      if (row < c) {
#pragma unroll
        for (int nj = 0; nj < 2; ++nj) {
          float g = accg[mi][nj][r];
          float u = accu[mi][nj][r];
          float s = g / (1.f + expf(-g)) * u;
          a[(long)(o + row) * cF + n0 + wn + nj * 16 + fr] = f2bf(s);
        }
      }
    }
}

// ---------------------------------------------------------------------------
// t3p[ks] = a @ udT^T (split-K=4, fp32 partials).  [4][ROWS][256].
// LDS double-buffer + XOR-swizzled staging (pre-swizzled gld16 source,
// swizzled ds_read; rule #21 both-sides involution). 11 iters.
// grid = (16, 32, E): x = n(0..3) | ksp(0..3)<<2  -> ~1024 active blocks.
// ---------------------------------------------------------------------------
__global__ __launch_bounds__(256, 4) void k_t3(
    const unsigned short* __restrict__ a, const unsigned short* __restrict__ udT,
    float* __restrict__ t3p, const int* __restrict__ cnt,
    const int* __restrict__ off)
{
  __shared__ __align__(16) unsigned short As[2][64 * 64], Bs[2][64 * 64];
  const int e = blockIdx.z, c = cnt[e], o = off[e];
  const int m0 = blockIdx.y * 64;
  if (m0 >= c) return;
  const int n0 = (blockIdx.x & 3) * 64;
  const int ksp = blockIdx.x >> 2;                 // 0..3
  const int kbase = ksp * 704;                     // 704 shorts = 11*128 B (aligned)
  const int tid = threadIdx.x;
  const int wid = tid >> 6, lane = tid & 63;
  const int sr8 = lane >> 3;
  // swizzled source column: dest row r=lane>>3, dest colb=(lane&7)*16;
  // source colb = dest colb ^ (r*16)  -> read side XORs the same pattern.
  const int scs = ((lane & 7) ^ sr8) * 8;
  const int ra0 = o + min(m0 + wid * 16 + sr8, c - 1);
  const int ra1 = o + min(m0 + wid * 16 + 8 + sr8, c - 1);
  const unsigned short* gA0 = a + (long)ra0 * cF + kbase + scs;
  const unsigned short* gA1 = a + (long)ra1 * cF + kbase + scs;
  const unsigned short* gB  = udT + (long)e * 256 * cF +
      (long)(n0 + wid * 16 + sr8) * cF + kbase + scs;
  const int lofs = wid * 16 * 64;
  auto STAGE = [&](int k0, int buf) {
    gld16(gA0 + k0, &As[buf][lofs]);
    gld16(gA1 + k0, &As[buf][lofs + 8 * 64]);
    gld16(gB + k0, &Bs[buf][lofs]);
    gld16(gB + (long)8 * cF + k0, &Bs[buf][lofs + 8 * 64]);
  };
  const int wm = (wid >> 1) * 32, wn = (wid & 1) * 32;
  const int fr = lane & 15, fq = lane >> 4;
  const int swz = (fr & 7) * 8;                    // read-side XOR (shorts)
  float4v zf = {0.f, 0.f, 0.f, 0.f};
  float4v acc[2][2] = {{zf, zf}, {zf, zf}};
  STAGE(0, 0);
  __syncthreads();
  for (int t = 0; t < 11; ++t) {
    const int cur = t & 1;
    if (t < 10) STAGE((t + 1) * 64, cur ^ 1);
#pragma unroll
    for (int ks = 0; ks < 2; ++ks) {
      short8 af[2], bf[2];
#pragma unroll
      for (int mi = 0; mi < 2; ++mi)
        af[mi] = *reinterpret_cast<const short8*>(
            &As[cur][(wm + mi * 16 + fr) * 64 + ((ks * 32 + fq * 8) ^ swz)]);
#pragma unroll
      for (int nj = 0; nj < 2; ++nj)
        bf[nj] = *reinterpret_cast<const short8*>(
            &Bs[cur][(wn + nj * 16 + fr) * 64 + ((ks * 32 + fq * 8) ^ swz)]);
#pragma unroll
      for (int mi = 0; mi < 2; ++mi)
#pragma unroll
        for (int nj = 0; nj < 2; ++nj)
          acc[mi][nj] = MFMA16(af[mi], bf[nj], acc[mi][nj], 0, 0, 0);
    }
    __syncthreads();
  }
  float* dstbase = t3p + (long)ksp * ROWS * 256;
#pragma unroll
  for (int mi = 0; mi < 2; ++mi)
#pragma unroll
    for (int r = 0; r < 4; ++r) {
      int row = m0 + wm + mi * 16 + fq * 4 + r;
      if (row < c) {
        float* dst = dstbase + (long)(o + row) * 256 + n0 + wn;
#pragma unroll
        for (int nj = 0; nj < 2; ++nj)
          dst[nj * 16 + fr] = acc[mi][nj][r];
      }
    }
}

// ---------------------------------------------------------------------------
// t3b bf16 = sum of 4 fp32 t3p partials (pure streaming). grid = 512.
// ---------------------------------------------------------------------------
__global__ __launch_bounds__(256) void k_red(
    const float* __restrict__ t3p, unsigned short* __restrict__ t3b)
{
  const long psz = (long)ROWS * 256;
  long i = ((long)blockIdx.x * 256 + threadIdx.x) * 8;
  float4 s0 = *reinterpret_cast<const float4*>(t3p + i);
  float4 s1 = *reinterpret_cast<const float4*>(t3p + i + 4);
#pragma unroll
  for (int q = 1; q < 4; ++q) {
    float4 a0 = *reinterpret_cast<const float4*>(t3p + q * psz + i);
    float4 a1 = *reinterpret_cast<const float4*>(t3p + q * psz + i + 4);
    s0.x += a0.x; s0.y += a0.y; s0.z += a0.z; s0.w += a0.w;
    s1.x += a1.x; s1.y += a1.y; s1.z += a1.z; s1.w += a1.w;
  }
  store_bf8(t3b + i, s0, s1);
}

// ---------------------------------------------------------------------------
// y = t3b @ vd2t^T   [rows x 1024] bf16. K = 256.
// BK=32, LDS double-buffer (24 KB), one barrier per K-step. grid = (16,16,E)
// ---------------------------------------------------------------------------
__global__ __launch_bounds__(256, 4) void k_y(
    const unsigned short* __restrict__ t3b, const unsigned short* __restrict__ vd2t,
    unsigned short* __restrict__ y, const int* __restrict__ cnt,
    const int* __restrict__ off)
{
  __shared__ __align__(16) unsigned short As[2][128 * 32], Bs[2][64 * 32];
  const int e = blockIdx.z, c = cnt[e], o = off[e];
  const int m0 = blockIdx.y * 128;
  if (m0 >= c) return;
  const int n0 = blockIdx.x * 64;
  const int tid = threadIdx.x;
  const int wid = tid >> 6, lane = tid & 63;
  const int sr16 = lane >> 2, sc = (lane & 3) * 8;
  const int ra0 = o + min(m0 + wid * 32 + sr16, c - 1);
  const int ra1 = o + min(m0 + wid * 32 + 16 + sr16, c - 1);
  const unsigned short* gA0 = t3b + (long)ra0 * 256 + sc;
  const unsigned short* gA1 = t3b + (long)ra1 * 256 + sc;
  const unsigned short* gB  = vd2t + (long)e * cH * 256 + (long)(n0 + wid * 16 + sr16) * 256 + sc;
  const int lA = wid * 32 * 32;
  const int lB = wid * 16 * 32;
  auto STAGE = [&](int k0, int buf) {
    gld16(gA0 + k0, &As[buf][lA]);
    gld16(gA1 + k0, &As[buf][lA + 16 * 32]);
    gld16(gB + k0, &Bs[buf][lB]);
  };
  const int wm = (wid >> 1) * 64, wn = (wid & 1) * 32;
  const int fr = lane & 15, fq = lane >> 4;
  float4v zf = {0.f, 0.f, 0.f, 0.f};
  float4v acc[4][2];
#pragma unroll
  for (int i = 0; i < 4; ++i) { acc[i][0] = zf; acc[i][1] = zf; }
  STAGE(0, 0);
  __syncthreads();
  for (int t = 0; t < 8; ++t) {
    const int cur = t & 1;
    if (t < 7) STAGE((t + 1) * 32, cur ^ 1);
    short8 af[4], bf[2];
#pragma unroll
    for (int mi = 0; mi < 4; ++mi)
      af[mi] = *reinterpret_cast<const short8*>(&As[cur][(wm + mi * 16 + fr) * 32 + fq * 8]);
#pragma unroll
    for (int nj = 0; nj < 2; ++nj)
      bf[nj] = *reinterpret_cast<const short8*>(&Bs[cur][(wn + nj * 16 + fr) * 32 + fq * 8]);
#pragma unroll
    for (int mi = 0; mi < 4; ++mi)
#pragma unroll
      for (int nj = 0; nj < 2; ++nj)
        acc[mi][nj] = MFMA16(af[mi], bf[nj], acc[mi][nj], 0, 0, 0);
    __syncthreads();
  }
#pragma unroll
  for (int mi = 0; mi < 4; ++mi)
#pragma unroll
    for (int r = 0; r < 4; ++r) {
      int row = m0 + wm + mi * 16 + fq * 4 + r;
      if (row < c) {
#pragma unroll
        for (int nj = 0; nj < 2; ++nj)
          y[(long)(o + row) * cH + n0 + wn + nj * 16 + fr] = f2bf(acc[mi][nj][r]);
      }
    }
}

// ---------------------------------------------------------------------------
// out[t] = w0 * y[rowmap[2t]] + w1 * y[rowmap[2t+1]]   (pure write, no zero)
// ---------------------------------------------------------------------------
__global__ __launch_bounds__(256) void k_combine(
    const unsigned short* __restrict__ y, const float* __restrict__ wt,
    const int* __restrict__ rowmap, float* __restrict__ out)
{
  const int tid = threadIdx.x;
  const int t = blockIdx.x * 2 + (tid >> 7);
  const int h = (tid & 127) * 8;
  const int r0 = rowmap[2 * t], r1 = rowmap[2 * t + 1];
  const float w0 = wt[2 * t], w1 = wt[2 * t + 1];
  union { uint4 v; unsigned short s[8]; } ua, ub;
  ua.v = *reinterpret_cast<const uint4*>(y + (long)r0 * cH + h);
  ub.v = *reinterpret_cast<const uint4*>(y + (long)r1 * cH + h);
  float o[8];
#pragma unroll
  for (int i = 0; i < 8; ++i)
    o[i] = w0 * bf2f(ua.s[i]) + w1 * bf2f(ub.s[i]);
  float* dst = out + (long)t * cH + h;
  *reinterpret_cast<float4*>(dst)     = make_float4(o[0], o[1], o[2], o[3]);
  *reinterpret_cast<float4*>(dst + 4) = make_float4(o[4], o[5], o[6], o[7]);
}

// ---------------------------------------------------------------------------
extern "C" void kernel_launch(void* const* d_in, const int* in_sizes, int n_in,
                              void* d_out, int out_size, void* d_ws, size_t ws_size,
                              hipStream_t stream)
{
  const float* x  = (const float*)d_in[0];
  const float* gw = (const float*)d_in[1];
  const float* Ug = (const float*)d_in[2];
  const float* Cg = (const float*)d_in[3];
  const float* Vg = (const float*)d_in[4];
  const float* Uu = (const float*)d_in[5];
  const float* Cu = (const float*)d_in[6];
  const float* Vu = (const float*)d_in[7];
  const float* Ud = (const float*)d_in[8];
  const float* Cd = (const float*)d_in[9];
  const float* Vd = (const float*)d_in[10];
  float* out = (float*)d_out;

  // workspace layout (~83 MiB peak, with aliasing)
  char* w = (char*)d_ws;
  // region 0: [vgT 11.53 | b1t 8.39] phase-1; phase-2: t3p (16.78 MiB fp32 x4
  // partials) + t3b (2.1 MiB bf16) alias it (18.88 <= 19.92) — both vgT (act)
  // and b1t (t1c) are dead before k_t3 runs.
  unsigned short* vgT = (unsigned short*)w;
  float*          t3p = (float*)w;
  unsigned short* t3b = (unsigned short*)(w + (long)4 * ROWS * 256 * 4);
  w += (long)cE * cF * 256 * 2;                                               // 11.53
  unsigned short* b1t = (unsigned short*)w;  w += (long)cE * 512 * 1024 * 2;  // 8.39
  unsigned short* vd2t = (unsigned short*)w; w += (long)cE * cH * 256 * 2;    // 4.19
  // vuT phase-1; yb (8.39) aliases it in phase 2
  unsigned short* vuT = (unsigned short*)w;
  unsigned short* yb  = (unsigned short*)w;  w += (long)cE * cF * 256 * 2;    // 11.53
  unsigned short* udT = (unsigned short*)w;  w += (long)cE * 256 * cF * 2;    // 11.53
  unsigned short* VdT = (unsigned short*)w;  w += (long)cE * cH * 256 * 2;    // 4.19
  unsigned short* xb  = (unsigned short*)w;  w += (long)cT * cH * 2;          // 4.19
  unsigned short* CgT = (unsigned short*)w;  w += (long)cR * cR * 2;          // 0.13
  unsigned short* CuT = (unsigned short*)w;  w += (long)cR * cR * 2;          // 0.13
  unsigned short* t1  = (unsigned short*)w;  w += (long)ROWS * 512 * 2;       // 4.19
  unsigned short* ab  = (unsigned short*)w;  w += (long)ROWS * cF * 2;        // 23.07
  float* wt   = (float*)w; w += ROWS * 4;
  int* et     = (int*)w; w += ROWS * 4;
  int* rowmap = (int*)w; w += ROWS * 4;
  int* tok    = (int*)w; w += ROWS * 4;
  int* cnt = (int*)w; w += cE * 4;
  int* off = (int*)w; w += cE * 4;

  // L1: all transposes (64x64 tiles) + gating + x->bf16
  k_prep1<<<dim3(PREP1_BLOCKS), dim3(256), 0, stream>>>(
      Cg, CgT, Cu, CuT, Vd, VdT, Vg, vgT, Vu, vuT, Ud, udT, x, gw, xb, et, wt);
  // L2: b1t fold + vd2t fold + routing lists
  k_prep2<<<dim3(PREP2_BLOCKS), dim3(256), 0, stream>>>(
      CgT, CuT, Ug, Uu, b1t, VdT, Cd, vd2t, et, rowmap, tok, cnt, off);
  // L3: compact t1 GEMM (dbuf)
  k_t1c<<<dim3(8, cT / 128, cE), dim3(256), 0, stream>>>(xb, b1t, t1, tok, cnt, off);
  // L4: a = silu(t1g @ Vg) * (t1u @ Vu)  (dbuf)
  k_act<<<dim3(cF / 64, cT / 128, cE), dim3(256), 0, stream>>>(t1, vgT, vuT, ab, cnt, off);
  // L5: t3p = a @ Ud (split-K=4, dbuf + swizzle; aliases dead vgT+b1t)
  k_t3<<<dim3(16, cT / 64, cE), dim3(256), 0, stream>>>(ab, udT, t3p, cnt, off);
  // L6: t3b = bf16(sum of 4 partials)
  k_red<<<dim3(ROWS * 256 / (256 * 8)), dim3(256), 0, stream>>>(t3p, t3b);
  // L7: y = t3b @ Vd2 (dbuf; aliases dead vuT)
  k_y<<<dim3(cH / 64, cT / 128, cE), dim3(256), 0, stream>>>(t3b, vd2t, yb, cnt, off);
  // L8: out = w0*y[r0] + w1*y[r1]
  k_combine<<<dim3(cT / 2), dim3(256), 0, stream>>>(yb, wt, rowmap, out);
}

// Round 7
// 275.421 us; speedup vs baseline: 1.1186x; 1.0150x over previous
//
#include <hip/hip_runtime.h>
#include <math.h>

constexpr int cE = 8;
constexpr int cH = 1024;
constexpr int cF = 2816;
constexpr int cR = 256;
constexpr int cT = 2048;
constexpr int ROWS = cT * 2;   // total routed (token, expert) rows = T*K
constexpr int LDA = 40;        // padded LDS row stride (foldm reg-staged kernel)

using short8  = __attribute__((ext_vector_type(8))) short;
using float4v = __attribute__((ext_vector_type(4))) float;
#define MFMA16 __builtin_amdgcn_mfma_f32_16x16x32_bf16

__device__ __forceinline__ unsigned short f2bf(float f) {
  union { float f; unsigned u; } v; v.f = f;
  unsigned r = v.u + 0x7fffu + ((v.u >> 16) & 1u);   // RNE
  return (unsigned short)(r >> 16);
}
__device__ __forceinline__ float bf2f(unsigned short s) {
  union { unsigned u; float f; } v; v.u = (unsigned)s << 16; return v.f;
}

// pack 8 fp32 -> 8 bf16, single 16B store
__device__ __forceinline__ void store_bf8(unsigned short* dst, float4 a, float4 b) {
  union { unsigned short u[8]; uint4 v; } t;
  t.u[0] = f2bf(a.x); t.u[1] = f2bf(a.y); t.u[2] = f2bf(a.z); t.u[3] = f2bf(a.w);
  t.u[4] = f2bf(b.x); t.u[5] = f2bf(b.y); t.u[6] = f2bf(b.z); t.u[7] = f2bf(b.w);
  *reinterpret_cast<uint4*>(dst) = t.v;
}

// async global->LDS, 16 B per lane. LDS dest = wave-uniform base + lane*16,
// global source address is per-lane (gather/swizzle-capable).
__device__ __forceinline__ void gld16(const unsigned short* g, unsigned short* l) {
  __builtin_amdgcn_global_load_lds(
      (const __attribute__((address_space(1))) void*)g,
      (__attribute__((address_space(3))) void*)l, 16, 0, 0);
}

// ---------------------------------------------------------------------------
// 64x64 transpose tile (fp32 -> bf16): in [P][Q] per batch -> out [Q][P].
// (R4-proven version)
// ---------------------------------------------------------------------------
__device__ __forceinline__ void tconv_tile64(
    const float* __restrict__ in, unsigned short* __restrict__ out,
    int P, int Q, int e, int bx, int by, int tid, float (*tile)[65])
{
  const long es = (long)P * Q;
  in += e * es; out += e * es;
  const int c0 = bx * 64, r0 = by * 64;
  const int r = tid >> 4, c4 = (tid & 15) * 4;
#pragma unroll
  for (int p = 0; p < 4; ++p) {
    float4 v = *reinterpret_cast<const float4*>(
        in + (long)(r0 + p * 16 + r) * Q + c0 + c4);
    tile[p * 16 + r][c4 + 0] = v.x; tile[p * 16 + r][c4 + 1] = v.y;
    tile[p * 16 + r][c4 + 2] = v.z; tile[p * 16 + r][c4 + 3] = v.w;
  }
  __syncthreads();
  const int cc = tid >> 4, rr4 = (tid & 15) * 4;
#pragma unroll
  for (int p = 0; p < 4; ++p) {
    ushort4 o;
    o.x = f2bf(tile[rr4 + 0][p * 16 + cc]);
    o.y = f2bf(tile[rr4 + 1][p * 16 + cc]);
    o.z = f2bf(tile[rr4 + 2][p * 16 + cc]);
    o.w = f2bf(tile[rr4 + 3][p * 16 + cc]);
    *reinterpret_cast<ushort4*>(out + (long)(c0 + p * 16 + cc) * P + r0 + rr4) = o;
  }
}

// ---------------------------------------------------------------------------
// LAUNCH 1: all 6 transposes (64x64 tiles) + gating + x->bf16, one launch.
// ---------------------------------------------------------------------------
constexpr int TCONV_BLOCKS = 4768;
constexpr int PREP1_BLOCKS = TCONV_BLOCKS + cT / 4;

__global__ __launch_bounds__(256) void k_prep1(
    const float* __restrict__ Cg, unsigned short* __restrict__ CgT,
    const float* __restrict__ Cu, unsigned short* __restrict__ CuT,
    const float* __restrict__ Vd, unsigned short* __restrict__ VdT,
    const float* __restrict__ Vg, unsigned short* __restrict__ vgT,
    const float* __restrict__ Vu, unsigned short* __restrict__ vuT,
    const float* __restrict__ Ud, unsigned short* __restrict__ udT,
    const float* __restrict__ x, const float* __restrict__ gw,
    unsigned short* __restrict__ xb, int* __restrict__ et,
    float* __restrict__ wt)
{
  __shared__ float tile[64][65];
  int b = blockIdx.x;
  const int tid = threadIdx.x;
  if (b < TCONV_BLOCKS) {
    const float* in; unsigned short* out; int P, Q;
    if (b < 16)         { in = Cg; out = CgT; P = 256;  Q = 256;  }
    else if (b < 32)    { b -= 16;    in = Cu; out = CuT; P = 256;  Q = 256;  }
    else if (b < 544)   { b -= 32;    in = Vd; out = VdT; P = 256;  Q = 1024; }
    else if (b < 1952)  { b -= 544;   in = Vg; out = vgT; P = 256;  Q = 2816; }
    else if (b < 3360)  { b -= 1952;  in = Vu; out = vuT; P = 256;  Q = 2816; }
    else                { b -= 3360;  in = Ud; out = udT; P = 2816; Q = 256;  }
    const int tpe = (P / 64) * (Q / 64);
    const int e = b / tpe, rem = b % tpe;
    const int bx = rem % (Q / 64), by = rem / (Q / 64);
    tconv_tile64(in, out, P, Q, e, bx, by, tid, tile);
    return;
  }
  // ---- gating path ----
  const int wid = tid >> 6, lane = tid & 63;
  const int t = (b - TCONV_BLOCKS) * 4 + wid;
  const float* xr = x + (long)t * cH + lane * 16;
  float4 v0 = *reinterpret_cast<const float4*>(xr);
  float4 v1 = *reinterpret_cast<const float4*>(xr + 4);
  float4 v2 = *reinterpret_cast<const float4*>(xr + 8);
  float4 v3 = *reinterpret_cast<const float4*>(xr + 12);
  store_bf8(xb + (long)t * cH + lane * 16, v0, v1);
  store_bf8(xb + (long)t * cH + lane * 16 + 8, v2, v3);
  float xv[16];
  *reinterpret_cast<float4*>(&xv[0])  = v0;
  *reinterpret_cast<float4*>(&xv[4])  = v1;
  *reinterpret_cast<float4*>(&xv[8])  = v2;
  *reinterpret_cast<float4*>(&xv[12]) = v3;
  const float* g = gw + (long)lane * 16 * cE;
  float l[cE];
#pragma unroll
  for (int e = 0; e < cE; ++e) l[e] = 0.f;
#pragma unroll
  for (int i = 0; i < 16; ++i) {
    float4 ga = *reinterpret_cast<const float4*>(g + i * cE);
    float4 gb = *reinterpret_cast<const float4*>(g + i * cE + 4);
    float xi = xv[i];
    l[0] += xi * ga.x; l[1] += xi * ga.y; l[2] += xi * ga.z; l[3] += xi * ga.w;
    l[4] += xi * gb.x; l[5] += xi * gb.y; l[6] += xi * gb.z; l[7] += xi * gb.w;
  }
#pragma unroll
  for (int m = 1; m < 64; m <<= 1)
#pragma unroll
    for (int e = 0; e < cE; ++e)
      l[e] += __shfl_xor(l[e], m, 64);
  if (lane == 0) {
    int i0 = 0; float m0 = l[0];
#pragma unroll
    for (int e = 1; e < cE; ++e) if (l[e] > m0) { m0 = l[e]; i0 = e; }
    int i1 = -1; float m1 = -1e30f;
#pragma unroll
    for (int e = 0; e < cE; ++e) if (e != i0 && l[e] > m1) { m1 = l[e]; i1 = e; }
    float w0 = 1.f / (1.f + expf(m1 - m0));
    et[t * 2 + 0] = i0;  et[t * 2 + 1] = i1;
    wt[t * 2 + 0] = w0;  wt[t * 2 + 1] = 1.f - w0;
  }
}

// ---------------------------------------------------------------------------
// MFMA fold body: D[m][n] = sum_k A[m][k] * B[n][k],  K = 256 fixed.
// tile 128x64, BK=32, register prefetch.
// ---------------------------------------------------------------------------
__device__ __forceinline__ void foldm_body(
    const unsigned short* __restrict__ A, const float* __restrict__ B,
    unsigned short* __restrict__ D, int ldd, int m0, int n0, int tid,
    unsigned short* As, unsigned short* Bs)
{
  const int sr = tid >> 2, sk = (tid & 3) * 8;
  const unsigned short* a0 = A + (long)(m0 + sr) * 256 + sk;
  const unsigned short* a1 = a0 + (long)64 * 256;
  const float* br = B + (long)(n0 + sr) * 256 + sk;
  uint4 rA0, rA1; float4 rB0, rB1;
  auto load_slice = [&](int k0) {
    rA0 = *reinterpret_cast<const uint4*>(a0 + k0);
    rA1 = *reinterpret_cast<const uint4*>(a1 + k0);
    rB0 = *reinterpret_cast<const float4*>(br + k0);
    rB1 = *reinterpret_cast<const float4*>(br + k0 + 4);
  };
  load_slice(0);
  const int wid = tid >> 6, lane = tid & 63;
  const int wm = (wid >> 1) * 64, wn = (wid & 1) * 32;
  const int fr = lane & 15, fq = lane >> 4;
  float4v zf = {0.f, 0.f, 0.f, 0.f};
  float4v acc[4][2];
#pragma unroll
  for (int i = 0; i < 4; ++i) { acc[i][0] = zf; acc[i][1] = zf; }
  for (int k0 = 0; k0 < 256; k0 += 32) {
    *reinterpret_cast<uint4*>(&As[sr * LDA + sk]) = rA0;
    *reinterpret_cast<uint4*>(&As[(sr + 64) * LDA + sk]) = rA1;
    store_bf8(&Bs[sr * LDA + sk], rB0, rB1);
    if (k0 + 32 < 256) load_slice(k0 + 32);
    __syncthreads();
    short8 af[4], bf[2];
#pragma unroll
    for (int mi = 0; mi < 4; ++mi)
      af[mi] = *reinterpret_cast<const short8*>(&As[(wm + mi * 16 + fr) * LDA + fq * 8]);
#pragma unroll
    for (int nj = 0; nj < 2; ++nj)
      bf[nj] = *reinterpret_cast<const short8*>(&Bs[(wn + nj * 16 + fr) * LDA + fq * 8]);
#pragma unroll
    for (int mi = 0; mi < 4; ++mi)
#pragma unroll
      for (int nj = 0; nj < 2; ++nj)
        acc[mi][nj] = MFMA16(af[mi], bf[nj], acc[mi][nj], 0, 0, 0);
    __syncthreads();
  }
#pragma unroll
  for (int mi = 0; mi < 4; ++mi)
#pragma unroll
    for (int r = 0; r < 4; ++r) {
      int m = m0 + wm + mi * 16 + fq * 4 + r;
#pragma unroll
      for (int nj = 0; nj < 2; ++nj)
        D[(long)m * ldd + n0 + wn + nj * 16 + fr] = f2bf(acc[mi][nj][r]);
    }
}

// ---------------------------------------------------------------------------
// LAUNCH 2: foldm2 (b1t, 512 blocks) + foldm vd2t (256 blocks) + lists (1).
// ---------------------------------------------------------------------------
constexpr int PREP2_BLOCKS = 512 + 256 + 1;
__global__ __launch_bounds__(256, 2) void k_prep2(
    const unsigned short* __restrict__ CgT, const unsigned short* __restrict__ CuT,
    const float* __restrict__ Ug, const float* __restrict__ Uu,
    unsigned short* __restrict__ b1t,
    const unsigned short* __restrict__ VdT, const float* __restrict__ Cd,
    unsigned short* __restrict__ vd2t,
    const int* __restrict__ et, int* __restrict__ rowmap,
    int* __restrict__ tok, int* __restrict__ cnt, int* __restrict__ off)
{
  __shared__ __align__(16) unsigned short As[128 * LDA], Bs[64 * LDA];
  __shared__ int sc_[cE], sp_[cE], so_[cE];
  const int b = blockIdx.x;
  const int tid = threadIdx.x;
  if (b < 512) {
    const int bx = b & 15, by = (b >> 4) & 1, z = b >> 5;
    const int sel = z >> 3, e = z & 7;
    const unsigned short* A = sel ? CuT : CgT;
    const float* B = (sel ? Uu : Ug) + (long)e * cH * cR;
    unsigned short* Dp = b1t + (long)e * 512 * 1024 + (long)sel * 256 * 1024;
    foldm_body(A, B, Dp, cH, by * 128, bx * 64, tid, As, Bs);
  } else if (b < 768) {
    const int b2 = b - 512;
    const int bx = b2 & 3, by = (b2 >> 2) & 7, e = b2 >> 5;
    foldm_body(VdT + (long)e * cH * cR, Cd, vd2t + (long)e * cH * 256, cR,
               by * 128, bx * 64, tid, As, Bs);
  } else {
    // ---- lists path (single block) ----
    if (tid < cE) { sc_[tid] = 0; sp_[tid] = 0; }
    __syncthreads();
    for (int i = tid; i < ROWS; i += 256) atomicAdd(&sc_[et[i]], 1);
    __syncthreads();
    if (tid == 0) {
      int s = 0;
      for (int e = 0; e < cE; ++e) { so_[e] = s; s += sc_[e]; }
    }
    __syncthreads();
    for (int i = tid; i < ROWS; i += 256) {
      int e = et[i];
      int slot = atomicAdd(&sp_[e], 1);
      int cr = so_[e] + slot;
      rowmap[i] = cr;
      tok[cr] = i >> 1;
    }
    if (tid < cE) { cnt[tid] = sc_[tid]; off[tid] = so_[tid]; }
  }
}

// ---------------------------------------------------------------------------
// COMPACT t1 GEMM: t1[o+row] = xb[tok[o+row]] @ b1t[e]^T   (K=1024, N=512)
// tile 128x64, BK=64, gathered A rows, LDS dbuf + XOR swizzle (8-chunk rows:
// source col ^(row&7), read ^(fr&7) — same involution as k_t3's, rule #21).
// grid = (8, cT/128, E), early-return past cnt[e].
// ---------------------------------------------------------------------------
__global__ __launch_bounds__(256, 3) void k_t1c(
    const unsigned short* __restrict__ xb, const unsigned short* __restrict__ b1t,
    unsigned short* __restrict__ t1, const int* __restrict__ tok,
    const int* __restrict__ cnt, const int* __restrict__ off)
{
  __shared__ __align__(16) unsigned short As[2][128 * 64], Bs[2][64 * 64];
  const int e = blockIdx.z, c = cnt[e], o = off[e];
  const int m0 = blockIdx.y * 128;
  if (m0 >= c) return;
  const int n0 = blockIdx.x * 64;
  const int tid = threadIdx.x;
  const int wid = tid >> 6, lane = tid & 63;
  const int sr8 = lane >> 3;
  const int scs = ((lane & 7) ^ sr8) * 8;          // pre-swizzled source col
  const unsigned short* gA[4];
#pragma unroll
  for (int j = 0; j < 4; ++j) {
    int row = min(m0 + wid * 32 + j * 8 + sr8, c - 1);
    gA[j] = xb + (long)tok[o + row] * cH + scs;
  }
  const unsigned short* gB = b1t + (long)e * 512 * 1024 +
      (long)(n0 + wid * 16 + sr8) * 1024 + scs;
  const int lA = wid * 32 * 64;   // wave-uniform dest offsets
  const int lB = wid * 16 * 64;
  auto STAGE = [&](int k0, int buf) {
#pragma unroll
    for (int j = 0; j < 4; ++j) gld16(gA[j] + k0, &As[buf][lA + j * 8 * 64]);
    gld16(gB + k0, &Bs[buf][lB]);
    gld16(gB + (long)8 * 1024 + k0, &Bs[buf][lB + 8 * 64]);
  };
  const int wm = (wid >> 1) * 64, wn = (wid & 1) * 32;
  const int fr = lane & 15, fq = lane >> 4;
  const int swz = (fr & 7) * 8;                    // read-side XOR (shorts)
  float4v zf = {0.f, 0.f, 0.f, 0.f};
  float4v acc[4][2];
#pragma unroll
  for (int i = 0; i < 4; ++i) { acc[i][0] = zf; acc[i][1] = zf; }
  STAGE(0, 0);
  __syncthreads();
  for (int t = 0; t < 16; ++t) {
    const int cur = t & 1;
    if (t < 15) STAGE((t + 1) * 64, cur ^ 1);
#pragma unroll
    for (int ks = 0; ks < 2; ++ks) {
      short8 af[4], bf[2];
#pragma unroll
      for (int mi = 0; mi < 4; ++mi)
        af[mi] = *reinterpret_cast<const short8*>(
            &As[cur][(wm + mi * 16 + fr) * 64 + ((ks * 32 + fq * 8) ^ swz)]);
#pragma unroll
      for (int nj = 0; nj < 2; ++nj)
        bf[nj] = *reinterpret_cast<const short8*>(
            &Bs[cur][(wn + nj * 16 + fr) * 64 + ((ks * 32 + fq * 8) ^ swz)]);
#pragma unroll
      for (int mi = 0; mi < 4; ++mi)
#pragma unroll
        for (int nj = 0; nj < 2; ++nj)
          acc[mi][nj] = MFMA16(af[mi], bf[nj], acc[mi][nj], 0, 0, 0);
    }
    __syncthreads();
  }
#pragma unroll
  for (int mi = 0; mi < 4; ++mi)
#pragma unroll
    for (int r = 0; r < 4; ++r) {
      int row = m0 + wm + mi * 16 + fq * 4 + r;
      if (row < c) {
#pragma unroll
        for (int nj = 0; nj < 2; ++nj)
          t1[(long)(o + row) * 512 + n0 + wn + nj * 16 + fr] = f2bf(acc[mi][nj][r]);
      }
    }
}

// ---------------------------------------------------------------------------
// dual GEMM: a = silu(t1g @ vgT^T) * (t1u @ vuT^T)  [rows x F], K=256
// BK=32, LDS dbuf + XOR swizzle (4-chunk rows: source col ^(row&3),
// read ^(fr&3)). One barrier per K-step. grid=(44,16,E)
// ---------------------------------------------------------------------------
__global__ __launch_bounds__(256, 3) void k_act(
    const unsigned short* __restrict__ t1,
    const unsigned short* __restrict__ vgT, const unsigned short* __restrict__ vuT,
    unsigned short* __restrict__ a, const int* __restrict__ cnt,
    const int* __restrict__ off)
{
  __shared__ __align__(16) unsigned short Ag[2][128 * 32], Au[2][128 * 32];
  __shared__ __align__(16) unsigned short Bg[2][64 * 32],  Bu[2][64 * 32];
  const int e = blockIdx.z, c = cnt[e], o = off[e];
  const int m0 = blockIdx.y * 128;
  if (m0 >= c) return;
  const int n0 = blockIdx.x * 64;
  const int tid = threadIdx.x;
  const int wid = tid >> 6, lane = tid & 63;
  const int sr16 = lane >> 2;
  const int scs = (((lane & 3) ^ (sr16 & 3)) * 8); // pre-swizzled source col
  const int ra0 = o + min(m0 + wid * 32 + sr16, c - 1);
  const int ra1 = o + min(m0 + wid * 32 + 16 + sr16, c - 1);
  const unsigned short* gAg0 = t1 + (long)ra0 * 512 + scs;
  const unsigned short* gAg1 = t1 + (long)ra1 * 512 + scs;
  const unsigned short* gBg = vgT + (long)e * cF * 256 + (long)(n0 + wid * 16 + sr16) * 256 + scs;
  const unsigned short* gBu = vuT + (long)e * cF * 256 + (long)(n0 + wid * 16 + sr16) * 256 + scs;
  const int lA = wid * 32 * 32;
  const int lB = wid * 16 * 32;
  auto STAGE = [&](int k0, int buf) {
    gld16(gAg0 + k0, &Ag[buf][lA]);
    gld16(gAg1 + k0, &Ag[buf][lA + 16 * 32]);
    gld16(gAg0 + 256 + k0, &Au[buf][lA]);
    gld16(gAg1 + 256 + k0, &Au[buf][lA + 16 * 32]);
    gld16(gBg + k0, &Bg[buf][lB]);
    gld16(gBu + k0, &Bu[buf][lB]);
  };
  const int wm = (wid >> 1) * 64, wn = (wid & 1) * 32;
  const int fr = lane & 15, fq = lane >> 4;
  const int swz = (fr & 3) * 8;                    // read-side XOR (shorts)
  float4v zf = {0.f, 0.f, 0.f, 0.f};
  float4v accg[4][2], accu[4][2];
#pragma unroll
  for (int i = 0; i < 4; ++i) { accg[i][0] = zf; accg[i][1] = zf; accu[i][0] = zf; accu[i][1] = zf; }
  STAGE(0, 0);
  __syncthreads();
  for (int t = 0; t < 8; ++t) {
    const int cur = t & 1;
    if (t < 7) STAGE((t + 1) * 32, cur ^ 1);
    short8 ag[4], au[4], bg[2], bu[2];
#pragma unroll
    for (int mi = 0; mi < 4; ++mi) {
      ag[mi] = *reinterpret_cast<const short8*>(
          &Ag[cur][(wm + mi * 16 + fr) * 32 + ((fq * 8) ^ swz)]);
      au[mi] = *reinterpret_cast<const short8*>(
          &Au[cur][(wm + mi * 16 + fr) * 32 + ((fq * 8) ^ swz)]);
    }
#pragma unroll
    for (int nj = 0; nj < 2; ++nj) {
      bg[nj] = *reinterpret_cast<const short8*>(
          &Bg[cur][(wn + nj * 16 + fr) * 32 + ((fq * 8) ^ swz)]);
      bu[nj] = *reinterpret_cast<const short8*>(
          &Bu[cur][(wn + nj * 16 + fr) * 32 + ((fq * 8) ^ swz)]);
    }
#pragma unroll
    for (int mi = 0; mi < 4; ++mi)
#pragma unroll
      for (int nj = 0; nj < 2; ++nj) {
        accg[mi][nj] = MFMA16(ag[mi], bg[nj], accg[mi][nj], 0, 0, 0);
        accu[mi][nj] = MFMA16(au[mi], bu[nj], accu[mi][nj], 0, 0, 0);
      }
    __syncthreads();
  }
#pragma unroll
  for (int mi = 0; mi < 4; ++mi)
#pragma unroll
    for (int r = 0; r < 4; ++r) {
      int row = m0 + wm + mi * 16 + fq * 4 + r;
      if (row < c) {
#pragma unroll
        for (int nj = 0; nj < 2; ++nj) {
          float g = accg[mi][nj][r];
          float u = accu[mi][nj][r];
          float s = g / (1.f + expf(-g)) * u;
          a[(long)(o + row) * cF + n0 + wn + nj * 16 + fr] = f2bf(s);
        }
      }
    }
}

// ---------------------------------------------------------------------------
// t3p[ks] = a @ udT^T (split-K=4, fp32 partials).  [4][ROWS][256].
// LDS double-buffer + XOR-swizzled staging. 11 iters.
// grid = (16, 32, E): x = n(0..3) | ksp(0..3)<<2  -> ~1024 active blocks.
// ---------------------------------------------------------------------------
__global__ __launch_bounds__(256, 4) void k_t3(
    const unsigned short* __restrict__ a, const unsigned short* __restrict__ udT,
    float* __restrict__ t3p, const int* __restrict__ cnt,
    const int* __restrict__ off)
{
  __shared__ __align__(16) unsigned short As[2][64 * 64], Bs[2][64 * 64];
  const int e = blockIdx.z, c = cnt[e], o = off[e];
  const int m0 = blockIdx.y * 64;
  if (m0 >= c) return;
  const int n0 = (blockIdx.x & 3) * 64;
  const int ksp = blockIdx.x >> 2;                 // 0..3
  const int kbase = ksp * 704;
  const int tid = threadIdx.x;
  const int wid = tid >> 6, lane = tid & 63;
  const int sr8 = lane >> 3;
  const int scs = ((lane & 7) ^ sr8) * 8;          // pre-swizzled source col
  const int ra0 = o + min(m0 + wid * 16 + sr8, c - 1);
  const int ra1 = o + min(m0 + wid * 16 + 8 + sr8, c - 1);
  const unsigned short* gA0 = a + (long)ra0 * cF + kbase + scs;
  const unsigned short* gA1 = a + (long)ra1 * cF + kbase + scs;
  const unsigned short* gB  = udT + (long)e * 256 * cF +
      (long)(n0 + wid * 16 + sr8) * cF + kbase + scs;
  const int lofs = wid * 16 * 64;
  auto STAGE = [&](int k0, int buf) {
    gld16(gA0 + k0, &As[buf][lofs]);
    gld16(gA1 + k0, &As[buf][lofs + 8 * 64]);
    gld16(gB + k0, &Bs[buf][lofs]);
    gld16(gB + (long)8 * cF + k0, &Bs[buf][lofs + 8 * 64]);
  };
  const int wm = (wid >> 1) * 32, wn = (wid & 1) * 32;
  const int fr = lane & 15, fq = lane >> 4;
  const int swz = (fr & 7) * 8;                    // read-side XOR (shorts)
  float4v zf = {0.f, 0.f, 0.f, 0.f};
  float4v acc[2][2] = {{zf, zf}, {zf, zf}};
  STAGE(0, 0);
  __syncthreads();
  for (int t = 0; t < 11; ++t) {
    const int cur = t & 1;
    if (t < 10) STAGE((t + 1) * 64, cur ^ 1);
#pragma unroll
    for (int ks = 0; ks < 2; ++ks) {
      short8 af[2], bf[2];
#pragma unroll
      for (int mi = 0; mi < 2; ++mi)
        af[mi] = *reinterpret_cast<const short8*>(
            &As[cur][(wm + mi * 16 + fr) * 64 + ((ks * 32 + fq * 8) ^ swz)]);
#pragma unroll
      for (int nj = 0; nj < 2; ++nj)
        bf[nj] = *reinterpret_cast<const short8*>(
            &Bs[cur][(wn + nj * 16 + fr) * 64 + ((ks * 32 + fq * 8) ^ swz)]);
#pragma unroll
      for (int mi = 0; mi < 2; ++mi)
#pragma unroll
        for (int nj = 0; nj < 2; ++nj)
          acc[mi][nj] = MFMA16(af[mi], bf[nj], acc[mi][nj], 0, 0, 0);
    }
    __syncthreads();
  }
  float* dstbase = t3p + (long)ksp * ROWS * 256;
#pragma unroll
  for (int mi = 0; mi < 2; ++mi)
#pragma unroll
    for (int r = 0; r < 4; ++r) {
      int row = m0 + wm + mi * 16 + fq * 4 + r;
      if (row < c) {
        float* dst = dstbase + (long)(o + row) * 256 + n0 + wn;
#pragma unroll
        for (int nj = 0; nj < 2; ++nj)
          dst[nj * 16 + fr] = acc[mi][nj][r];
      }
    }
}

// ---------------------------------------------------------------------------
// t3b bf16 = sum of 4 fp32 t3p partials (pure streaming). grid = 512.
// ---------------------------------------------------------------------------
__global__ __launch_bounds__(256) void k_red(
    const float* __restrict__ t3p, unsigned short* __restrict__ t3b)
{
  const long psz = (long)ROWS * 256;
  long i = ((long)blockIdx.x * 256 + threadIdx.x) * 8;
  float4 s0 = *reinterpret_cast<const float4*>(t3p + i);
  float4 s1 = *reinterpret_cast<const float4*>(t3p + i + 4);
#pragma unroll
  for (int q = 1; q < 4; ++q) {
    float4 a0 = *reinterpret_cast<const float4*>(t3p + q * psz + i);
    float4 a1 = *reinterpret_cast<const float4*>(t3p + q * psz + i + 4);
    s0.x += a0.x; s0.y += a0.y; s0.z += a0.z; s0.w += a0.w;
    s1.x += a1.x; s1.y += a1.y; s1.z += a1.z; s1.w += a1.w;
  }
  store_bf8(t3b + i, s0, s1);
}

// ---------------------------------------------------------------------------
// y = t3b @ vd2t^T   [rows x 1024] bf16. K = 256.
// BK=32, LDS dbuf + XOR swizzle (4-chunk rows). grid = (16,16,E)
// ---------------------------------------------------------------------------
__global__ __launch_bounds__(256, 4) void k_y(
    const unsigned short* __restrict__ t3b, const unsigned short* __restrict__ vd2t,
    unsigned short* __restrict__ y, const int* __restrict__ cnt,
    const int* __restrict__ off)
{
  __shared__ __align__(16) unsigned short As[2][128 * 32], Bs[2][64 * 32];
  const int e = blockIdx.z, c = cnt[e], o = off[e];
  const int m0 = blockIdx.y * 128;
  if (m0 >= c) return;
  const int n0 = blockIdx.x * 64;
  const int tid = threadIdx.x;
  const int wid = tid >> 6, lane = tid & 63;
  const int sr16 = lane >> 2;
  const int scs = (((lane & 3) ^ (sr16 & 3)) * 8); // pre-swizzled source col
  const int ra0 = o + min(m0 + wid * 32 + sr16, c - 1);
  const int ra1 = o + min(m0 + wid * 32 + 16 + sr16, c - 1);
  const unsigned short* gA0 = t3b + (long)ra0 * 256 + scs;
  const unsigned short* gA1 = t3b + (long)ra1 * 256 + scs;
  const unsigned short* gB  = vd2t + (long)e * cH * 256 + (long)(n0 + wid * 16 + sr16) * 256 + scs;
  const int lA = wid * 32 * 32;
  const int lB = wid * 16 * 32;
  auto STAGE = [&](int k0, int buf) {
    gld16(gA0 + k0, &As[buf][lA]);
    gld16(gA1 + k0, &As[buf][lA + 16 * 32]);
    gld16(gB + k0, &Bs[buf][lB]);
  };
  const int wm = (wid >> 1) * 64, wn = (wid & 1) * 32;
  const int fr = lane & 15, fq = lane >> 4;
  const int swz = (fr & 3) * 8;                    // read-side XOR (shorts)
  float4v zf = {0.f, 0.f, 0.f, 0.f};
  float4v acc[4][2];
#pragma unroll
  for (int i = 0; i < 4; ++i) { acc[i][0] = zf; acc[i][1] = zf; }
  STAGE(0, 0);
  __syncthreads();
  for (int t = 0; t < 8; ++t) {
    const int cur = t & 1;
    if (t < 7) STAGE((t + 1) * 32, cur ^ 1);
    short8 af[4], bf[2];
#pragma unroll
    for (int mi = 0; mi < 4; ++mi)
      af[mi] = *reinterpret_cast<const short8*>(
          &As[cur][(wm + mi * 16 + fr) * 32 + ((fq * 8) ^ swz)]);
#pragma unroll
    for (int nj = 0; nj < 2; ++nj)
      bf[nj] = *reinterpret_cast<const short8*>(
          &Bs[cur][(wn + nj * 16 + fr) * 32 + ((fq * 8) ^ swz)]);
#pragma unroll
    for (int mi = 0; mi < 4; ++mi)
#pragma unroll
      for (int nj = 0; nj < 2; ++nj)
        acc[mi][nj] = MFMA16(af[mi], bf[nj], acc[mi][nj], 0, 0, 0);
    __syncthreads();
  }
#pragma unroll
  for (int mi = 0; mi < 4; ++mi)
#pragma unroll
    for (int r = 0; r < 4; ++r) {
      int row = m0 + wm + mi * 16 + fq * 4 + r;
      if (row < c) {
#pragma unroll
        for (int nj = 0; nj < 2; ++nj)
          y[(long)(o + row) * cH + n0 + wn + nj * 16 + fr] = f2bf(acc[mi][nj][r]);
      }
    }
}

// ---------------------------------------------------------------------------
// out[t] = w0 * y[rowmap[2t]] + w1 * y[rowmap[2t+1]]   (pure write, no zero)
// ---------------------------------------------------------------------------
__global__ __launch_bounds__(256) void k_combine(
    const unsigned short* __restrict__ y, const float* __restrict__ wt,
    const int* __restrict__ rowmap, float* __restrict__ out)
{
  const int tid = threadIdx.x;
  const int t = blockIdx.x * 2 + (tid >> 7);
  const int h = (tid & 127) * 8;
  const int r0 = rowmap[2 * t], r1 = rowmap[2 * t + 1];
  const float w0 = wt[2 * t], w1 = wt[2 * t + 1];
  union { uint4 v; unsigned short s[8]; } ua, ub;
  ua.v = *reinterpret_cast<const uint4*>(y + (long)r0 * cH + h);
  ub.v = *reinterpret_cast<const uint4*>(y + (long)r1 * cH + h);
  float o[8];
#pragma unroll
  for (int i = 0; i < 8; ++i)
    o[i] = w0 * bf2f(ua.s[i]) + w1 * bf2f(ub.s[i]);
  float* dst = out + (long)t * cH + h;
  *reinterpret_cast<float4*>(dst)     = make_float4(o[0], o[1], o[2], o[3]);
  *reinterpret_cast<float4*>(dst + 4) = make_float4(o[4], o[5], o[6], o[7]);
}

// ---------------------------------------------------------------------------
extern "C" void kernel_launch(void* const* d_in, const int* in_sizes, int n_in,
                              void* d_out, int out_size, void* d_ws, size_t ws_size,
                              hipStream_t stream)
{
  const float* x  = (const float*)d_in[0];
  const float* gw = (const float*)d_in[1];
  const float* Ug = (const float*)d_in[2];
  const float* Cg = (const float*)d_in[3];
  const float* Vg = (const float*)d_in[4];
  const float* Uu = (const float*)d_in[5];
  const float* Cu = (const float*)d_in[6];
  const float* Vu = (const float*)d_in[7];
  const float* Ud = (const float*)d_in[8];
  const float* Cd = (const float*)d_in[9];
  const float* Vd = (const float*)d_in[10];
  float* out = (float*)d_out;

  // workspace layout (~83 MiB peak, with aliasing)
  char* w = (char*)d_ws;
  unsigned short* vgT = (unsigned short*)w;
  float*          t3p = (float*)w;
  unsigned short* t3b = (unsigned short*)(w + (long)4 * ROWS * 256 * 4);
  w += (long)cE * cF * 256 * 2;                                               // 11.53
  unsigned short* b1t = (unsigned short*)w;  w += (long)cE * 512 * 1024 * 2;  // 8.39
  unsigned short* vd2t = (unsigned short*)w; w += (long)cE * cH * 256 * 2;    // 4.19
  unsigned short* vuT = (unsigned short*)w;
  unsigned short* yb  = (unsigned short*)w;  w += (long)cE * cF * 256 * 2;    // 11.53
  unsigned short* udT = (unsigned short*)w;  w += (long)cE * 256 * cF * 2;    // 11.53
  unsigned short* VdT = (unsigned short*)w;  w += (long)cE * cH * 256 * 2;    // 4.19
  unsigned short* xb  = (unsigned short*)w;  w += (long)cT * cH * 2;          // 4.19
  unsigned short* CgT = (unsigned short*)w;  w += (long)cR * cR * 2;          // 0.13
  unsigned short* CuT = (unsigned short*)w;  w += (long)cR * cR * 2;          // 0.13
  unsigned short* t1  = (unsigned short*)w;  w += (long)ROWS * 512 * 2;       // 4.19
  unsigned short* ab  = (unsigned short*)w;  w += (long)ROWS * cF * 2;        // 23.07
  float* wt   = (float*)w; w += ROWS * 4;
  int* et     = (int*)w; w += ROWS * 4;
  int* rowmap = (int*)w; w += ROWS * 4;
  int* tok    = (int*)w; w += ROWS * 4;
  int* cnt = (int*)w; w += cE * 4;
  int* off = (int*)w; w += cE * 4;

  // L1: all transposes (64x64 tiles, R4-proven) + gating + x->bf16
  k_prep1<<<dim3(PREP1_BLOCKS), dim3(256), 0, stream>>>(
      Cg, CgT, Cu, CuT, Vd, VdT, Vg, vgT, Vu, vuT, Ud, udT, x, gw, xb, et, wt);
  // L2: b1t fold + vd2t fold + routing lists
  k_prep2<<<dim3(PREP2_BLOCKS), dim3(256), 0, stream>>>(
      CgT, CuT, Ug, Uu, b1t, VdT, Cd, vd2t, et, rowmap, tok, cnt, off);
  // L3: compact t1 GEMM (dbuf + swizzle)
  k_t1c<<<dim3(8, cT / 128, cE), dim3(256), 0, stream>>>(xb, b1t, t1, tok, cnt, off);
  // L4: a = silu(t1g @ Vg) * (t1u @ Vu)  (dbuf + swizzle)
  k_act<<<dim3(cF / 64, cT / 128, cE), dim3(256), 0, stream>>>(t1, vgT, vuT, ab, cnt, off);
  // L5: t3p = a @ Ud (split-K=4, dbuf + swizzle; aliases dead vgT+b1t)
  k_t3<<<dim3(16, cT / 64, cE), dim3(256), 0, stream>>>(ab, udT, t3p, cnt, off);
  // L6: t3b = bf16(sum of 4 partials)
  k_red<<<dim3(ROWS * 256 / (256 * 8)), dim3(256), 0, stream>>>(t3p, t3b);
  // L7: y = t3b @ Vd2 (dbuf + swizzle; aliases dead vuT)
  k_y<<<dim3(cH / 64, cT / 128, cE), dim3(256), 0, stream>>>(t3b, vd2t, yb, cnt, off);
  // L8: out = w0*y[r0] + w1*y[r1]
  k_combine<<<dim3(cT / 2), dim3(256), 0, stream>>>(yb, wt, rowmap, out);
}

// Round 8
// 264.752 us; speedup vs baseline: 1.1637x; 1.0403x over previous
//
#include <hip/hip_runtime.h>
#include <math.h>

constexpr int cE = 8;
constexpr int cH = 1024;
constexpr int cF = 2816;
constexpr int cR = 256;
constexpr int cT = 2048;
constexpr int ROWS = cT * 2;   // total routed (token, expert) rows = T*K
constexpr int LDA = 40;        // padded LDS row stride (foldm reg-staged kernel)

using short8  = __attribute__((ext_vector_type(8))) short;
using float4v = __attribute__((ext_vector_type(4))) float;
#define MFMA16 __builtin_amdgcn_mfma_f32_16x16x32_bf16

__device__ __forceinline__ unsigned short f2bf(float f) {
  union { float f; unsigned u; } v; v.f = f;
  unsigned r = v.u + 0x7fffu + ((v.u >> 16) & 1u);   // RNE
  return (unsigned short)(r >> 16);
}
__device__ __forceinline__ float bf2f(unsigned short s) {
  union { unsigned u; float f; } v; v.u = (unsigned)s << 16; return v.f;
}

// pack 8 fp32 -> 8 bf16, single 16B store
__device__ __forceinline__ void store_bf8(unsigned short* dst, float4 a, float4 b) {
  union { unsigned short u[8]; uint4 v; } t;
  t.u[0] = f2bf(a.x); t.u[1] = f2bf(a.y); t.u[2] = f2bf(a.z); t.u[3] = f2bf(a.w);
  t.u[4] = f2bf(b.x); t.u[5] = f2bf(b.y); t.u[6] = f2bf(b.z); t.u[7] = f2bf(b.w);
  *reinterpret_cast<uint4*>(dst) = t.v;
}

// async global->LDS, 16 B per lane. LDS dest = wave-uniform base + lane*16,
// global source address is per-lane (gather/swizzle-capable).
__device__ __forceinline__ void gld16(const unsigned short* g, unsigned short* l) {
  __builtin_amdgcn_global_load_lds(
      (const __attribute__((address_space(1))) void*)g,
      (__attribute__((address_space(3))) void*)l, 16, 0, 0);
}

// ---------------------------------------------------------------------------
// 64x64 transpose tile (fp32 -> bf16): in [P][Q] per batch -> out [Q][P].
// (R4-proven version)
// ---------------------------------------------------------------------------
__device__ __forceinline__ void tconv_tile64(
    const float* __restrict__ in, unsigned short* __restrict__ out,
    int P, int Q, int e, int bx, int by, int tid, float (*tile)[65])
{
  const long es = (long)P * Q;
  in += e * es; out += e * es;
  const int c0 = bx * 64, r0 = by * 64;
  const int r = tid >> 4, c4 = (tid & 15) * 4;
#pragma unroll
  for (int p = 0; p < 4; ++p) {
    float4 v = *reinterpret_cast<const float4*>(
        in + (long)(r0 + p * 16 + r) * Q + c0 + c4);
    tile[p * 16 + r][c4 + 0] = v.x; tile[p * 16 + r][c4 + 1] = v.y;
    tile[p * 16 + r][c4 + 2] = v.z; tile[p * 16 + r][c4 + 3] = v.w;
  }
  __syncthreads();
  const int cc = tid >> 4, rr4 = (tid & 15) * 4;
#pragma unroll
  for (int p = 0; p < 4; ++p) {
    ushort4 o;
    o.x = f2bf(tile[rr4 + 0][p * 16 + cc]);
    o.y = f2bf(tile[rr4 + 1][p * 16 + cc]);
    o.z = f2bf(tile[rr4 + 2][p * 16 + cc]);
    o.w = f2bf(tile[rr4 + 3][p * 16 + cc]);
    *reinterpret_cast<ushort4*>(out + (long)(c0 + p * 16 + cc) * P + r0 + rr4) = o;
  }
}

// ---------------------------------------------------------------------------
// LAUNCH 1: SMALL transposes (Cg/Cu/Vd, 544 tiles) + gating + x->bf16.
// Big transposes (Vg/Vu/Ud) moved into launch 2 to overlap with MFMA folds.
//  [0,16) Cg | [16,32) Cu | [32,544) Vd | [544,1056) gating
// ---------------------------------------------------------------------------
constexpr int P1_TCONV = 544;
constexpr int PREP1_BLOCKS = P1_TCONV + cT / 4;

__global__ __launch_bounds__(256) void k_prep1s(
    const float* __restrict__ Cg, unsigned short* __restrict__ CgT,
    const float* __restrict__ Cu, unsigned short* __restrict__ CuT,
    const float* __restrict__ Vd, unsigned short* __restrict__ VdT,
    const float* __restrict__ x, const float* __restrict__ gw,
    unsigned short* __restrict__ xb, int* __restrict__ et,
    float* __restrict__ wt)
{
  __shared__ float tile[64][65];
  int b = blockIdx.x;
  const int tid = threadIdx.x;
  if (b < P1_TCONV) {
    const float* in; unsigned short* out; int P, Q;
    if (b < 16)       { in = Cg; out = CgT; P = 256; Q = 256;  }
    else if (b < 32)  { b -= 16; in = Cu; out = CuT; P = 256; Q = 256;  }
    else              { b -= 32; in = Vd; out = VdT; P = 256; Q = 1024; }
    const int tpe = (P / 64) * (Q / 64);
    const int e = b / tpe, rem = b % tpe;
    const int bx = rem % (Q / 64), by = rem / (Q / 64);
    tconv_tile64(in, out, P, Q, e, bx, by, tid, tile);
    return;
  }
  // ---- gating path ----
  const int wid = tid >> 6, lane = tid & 63;
  const int t = (b - P1_TCONV) * 4 + wid;
  const float* xr = x + (long)t * cH + lane * 16;
  float4 v0 = *reinterpret_cast<const float4*>(xr);
  float4 v1 = *reinterpret_cast<const float4*>(xr + 4);
  float4 v2 = *reinterpret_cast<const float4*>(xr + 8);
  float4 v3 = *reinterpret_cast<const float4*>(xr + 12);
  store_bf8(xb + (long)t * cH + lane * 16, v0, v1);
  store_bf8(xb + (long)t * cH + lane * 16 + 8, v2, v3);
  float xv[16];
  *reinterpret_cast<float4*>(&xv[0])  = v0;
  *reinterpret_cast<float4*>(&xv[4])  = v1;
  *reinterpret_cast<float4*>(&xv[8])  = v2;
  *reinterpret_cast<float4*>(&xv[12]) = v3;
  const float* g = gw + (long)lane * 16 * cE;
  float l[cE];
#pragma unroll
  for (int e = 0; e < cE; ++e) l[e] = 0.f;
#pragma unroll
  for (int i = 0; i < 16; ++i) {
    float4 ga = *reinterpret_cast<const float4*>(g + i * cE);
    float4 gb = *reinterpret_cast<const float4*>(g + i * cE + 4);
    float xi = xv[i];
    l[0] += xi * ga.x; l[1] += xi * ga.y; l[2] += xi * ga.z; l[3] += xi * ga.w;
    l[4] += xi * gb.x; l[5] += xi * gb.y; l[6] += xi * gb.z; l[7] += xi * gb.w;
  }
#pragma unroll
  for (int m = 1; m < 64; m <<= 1)
#pragma unroll
    for (int e = 0; e < cE; ++e)
      l[e] += __shfl_xor(l[e], m, 64);
  if (lane == 0) {
    int i0 = 0; float m0 = l[0];
#pragma unroll
    for (int e = 1; e < cE; ++e) if (l[e] > m0) { m0 = l[e]; i0 = e; }
    int i1 = -1; float m1 = -1e30f;
#pragma unroll
    for (int e = 0; e < cE; ++e) if (e != i0 && l[e] > m1) { m1 = l[e]; i1 = e; }
    float w0 = 1.f / (1.f + expf(m1 - m0));
    et[t * 2 + 0] = i0;  et[t * 2 + 1] = i1;
    wt[t * 2 + 0] = w0;  wt[t * 2 + 1] = 1.f - w0;
  }
}

// ---------------------------------------------------------------------------
// MFMA fold body: D[m][n] = sum_k A[m][k] * B[n][k],  K = 256 fixed.
// tile 128x64, BK=32, register prefetch.
// ---------------------------------------------------------------------------
__device__ __forceinline__ void foldm_body(
    const unsigned short* __restrict__ A, const float* __restrict__ B,
    unsigned short* __restrict__ D, int ldd, int m0, int n0, int tid,
    unsigned short* As, unsigned short* Bs)
{
  const int sr = tid >> 2, sk = (tid & 3) * 8;
  const unsigned short* a0 = A + (long)(m0 + sr) * 256 + sk;
  const unsigned short* a1 = a0 + (long)64 * 256;
  const float* br = B + (long)(n0 + sr) * 256 + sk;
  uint4 rA0, rA1; float4 rB0, rB1;
  auto load_slice = [&](int k0) {
    rA0 = *reinterpret_cast<const uint4*>(a0 + k0);
    rA1 = *reinterpret_cast<const uint4*>(a1 + k0);
    rB0 = *reinterpret_cast<const float4*>(br + k0);
    rB1 = *reinterpret_cast<const float4*>(br + k0 + 4);
  };
  load_slice(0);
  const int wid = tid >> 6, lane = tid & 63;
  const int wm = (wid >> 1) * 64, wn = (wid & 1) * 32;
  const int fr = lane & 15, fq = lane >> 4;
  float4v zf = {0.f, 0.f, 0.f, 0.f};
  float4v acc[4][2];
#pragma unroll
  for (int i = 0; i < 4; ++i) { acc[i][0] = zf; acc[i][1] = zf; }
  for (int k0 = 0; k0 < 256; k0 += 32) {
    *reinterpret_cast<uint4*>(&As[sr * LDA + sk]) = rA0;
    *reinterpret_cast<uint4*>(&As[(sr + 64) * LDA + sk]) = rA1;
    store_bf8(&Bs[sr * LDA + sk], rB0, rB1);
    if (k0 + 32 < 256) load_slice(k0 + 32);
    __syncthreads();
    short8 af[4], bf[2];
#pragma unroll
    for (int mi = 0; mi < 4; ++mi)
      af[mi] = *reinterpret_cast<const short8*>(&As[(wm + mi * 16 + fr) * LDA + fq * 8]);
#pragma unroll
    for (int nj = 0; nj < 2; ++nj)
      bf[nj] = *reinterpret_cast<const short8*>(&Bs[(wn + nj * 16 + fr) * LDA + fq * 8]);
#pragma unroll
    for (int mi = 0; mi < 4; ++mi)
#pragma unroll
      for (int nj = 0; nj < 2; ++nj)
        acc[mi][nj] = MFMA16(af[mi], bf[nj], acc[mi][nj], 0, 0, 0);
    __syncthreads();
  }
#pragma unroll
  for (int mi = 0; mi < 4; ++mi)
#pragma unroll
    for (int r = 0; r < 4; ++r) {
      int m = m0 + wm + mi * 16 + fq * 4 + r;
#pragma unroll
      for (int nj = 0; nj < 2; ++nj)
        D[(long)m * ldd + n0 + wn + nj * 16 + fr] = f2bf(acc[mi][nj][r]);
    }
}

// ---------------------------------------------------------------------------
// LAUNCH 2: folds (768) + lists (1) + BIG transposes Vg/Vu/Ud (4224 tiles).
// Heterogeneous co-scheduling: memory-bound transpose blocks overlap the
// MFMA-bound fold blocks on the same CUs. LDS unioned (fold 15.4KB /
// tile 16.6KB / lists 96B).
//  [0,512) b1t folds | [512,768) vd2t folds | 768 lists |
//  [769,2177) Vg | [2177,3585) Vu | [3585,4993) Ud
// ---------------------------------------------------------------------------
constexpr int PREP2_BLOCKS = 769 + 3 * 1408;
__global__ __launch_bounds__(256, 3) void k_prep2(
    const unsigned short* __restrict__ CgT, const unsigned short* __restrict__ CuT,
    const float* __restrict__ Ug, const float* __restrict__ Uu,
    unsigned short* __restrict__ b1t,
    const unsigned short* __restrict__ VdT, const float* __restrict__ Cd,
    unsigned short* __restrict__ vd2t,
    const float* __restrict__ Vg, unsigned short* __restrict__ vgT,
    const float* __restrict__ Vu, unsigned short* __restrict__ vuT,
    const float* __restrict__ Ud, unsigned short* __restrict__ udT,
    const int* __restrict__ et, int* __restrict__ rowmap,
    int* __restrict__ tok, int* __restrict__ cnt, int* __restrict__ off)
{
  __shared__ __align__(16) char smem[64 * 65 * 4];   // 16640 B union
  const int b = blockIdx.x;
  const int tid = threadIdx.x;
  if (b < 512) {
    unsigned short* As = (unsigned short*)smem;
    unsigned short* Bs = As + 128 * LDA;
    const int bx = b & 15, by = (b >> 4) & 1, z = b >> 5;
    const int sel = z >> 3, e = z & 7;
    const unsigned short* A = sel ? CuT : CgT;
    const float* B = (sel ? Uu : Ug) + (long)e * cH * cR;
    unsigned short* Dp = b1t + (long)e * 512 * 1024 + (long)sel * 256 * 1024;
    foldm_body(A, B, Dp, cH, by * 128, bx * 64, tid, As, Bs);
  } else if (b < 768) {
    unsigned short* As = (unsigned short*)smem;
    unsigned short* Bs = As + 128 * LDA;
    const int b2 = b - 512;
    const int bx = b2 & 3, by = (b2 >> 2) & 7, e = b2 >> 5;
    foldm_body(VdT + (long)e * cH * cR, Cd, vd2t + (long)e * cH * 256, cR,
               by * 128, bx * 64, tid, As, Bs);
  } else if (b == 768) {
    // ---- lists path (single block) ----
    int* sc_ = (int*)smem;
    int* sp_ = sc_ + cE;
    int* so_ = sc_ + 2 * cE;
    if (tid < cE) { sc_[tid] = 0; sp_[tid] = 0; }
    __syncthreads();
    for (int i = tid; i < ROWS; i += 256) atomicAdd(&sc_[et[i]], 1);
    __syncthreads();
    if (tid == 0) {
      int s = 0;
      for (int e = 0; e < cE; ++e) { so_[e] = s; s += sc_[e]; }
    }
    __syncthreads();
    for (int i = tid; i < ROWS; i += 256) {
      int e = et[i];
      int slot = atomicAdd(&sp_[e], 1);
      int cr = so_[e] + slot;
      rowmap[i] = cr;
      tok[cr] = i >> 1;
    }
    if (tid < cE) { cnt[tid] = sc_[tid]; off[tid] = so_[tid]; }
  } else {
    // ---- big transpose path ----
    float (*tile)[65] = reinterpret_cast<float(*)[65]>(smem);
    int t = b - 769;
    const float* in; unsigned short* out; int P, Q;
    if (t < 1408)       { in = Vg; out = vgT; P = 256;  Q = 2816; }
    else if (t < 2816)  { t -= 1408; in = Vu; out = vuT; P = 256;  Q = 2816; }
    else                { t -= 2816; in = Ud; out = udT; P = 2816; Q = 256;  }
    const int tpe = (P / 64) * (Q / 64);
    const int e = t / tpe, rem = t % tpe;
    const int bx = rem % (Q / 64), by = rem / (Q / 64);
    tconv_tile64(in, out, P, Q, e, bx, by, tid, tile);
  }
}

// ---------------------------------------------------------------------------
// COMPACT t1 GEMM: t1[o+row] = xb[tok[o+row]] @ b1t[e]^T   (K=1024, N=512)
// tile 128x64, BK=64, gathered A rows, LDS dbuf + XOR swizzle.
// grid = (8, cT/128, E), early-return past cnt[e].
// ---------------------------------------------------------------------------
__global__ __launch_bounds__(256, 3) void k_t1c(
    const unsigned short* __restrict__ xb, const unsigned short* __restrict__ b1t,
    unsigned short* __restrict__ t1, const int* __restrict__ tok,
    const int* __restrict__ cnt, const int* __restrict__ off)
{
  __shared__ __align__(16) unsigned short As[2][128 * 64], Bs[2][64 * 64];
  const int e = blockIdx.z, c = cnt[e], o = off[e];
  const int m0 = blockIdx.y * 128;
  if (m0 >= c) return;
  const int n0 = blockIdx.x * 64;
  const int tid = threadIdx.x;
  const int wid = tid >> 6, lane = tid & 63;
  const int sr8 = lane >> 3;
  const int scs = ((lane & 7) ^ sr8) * 8;          // pre-swizzled source col
  const unsigned short* gA[4];
#pragma unroll
  for (int j = 0; j < 4; ++j) {
    int row = min(m0 + wid * 32 + j * 8 + sr8, c - 1);
    gA[j] = xb + (long)tok[o + row] * cH + scs;
  }
  const unsigned short* gB = b1t + (long)e * 512 * 1024 +
      (long)(n0 + wid * 16 + sr8) * 1024 + scs;
  const int lA = wid * 32 * 64;   // wave-uniform dest offsets
  const int lB = wid * 16 * 64;
  auto STAGE = [&](int k0, int buf) {
#pragma unroll
    for (int j = 0; j < 4; ++j) gld16(gA[j] + k0, &As[buf][lA + j * 8 * 64]);
    gld16(gB + k0, &Bs[buf][lB]);
    gld16(gB + (long)8 * 1024 + k0, &Bs[buf][lB + 8 * 64]);
  };
  const int wm = (wid >> 1) * 64, wn = (wid & 1) * 32;
  const int fr = lane & 15, fq = lane >> 4;
  const int swz = (fr & 7) * 8;                    // read-side XOR (shorts)
  float4v zf = {0.f, 0.f, 0.f, 0.f};
  float4v acc[4][2];
#pragma unroll
  for (int i = 0; i < 4; ++i) { acc[i][0] = zf; acc[i][1] = zf; }
  STAGE(0, 0);
  __syncthreads();
  for (int t = 0; t < 16; ++t) {
    const int cur = t & 1;
    if (t < 15) STAGE((t + 1) * 64, cur ^ 1);
#pragma unroll
    for (int ks = 0; ks < 2; ++ks) {
      short8 af[4], bf[2];
#pragma unroll
      for (int mi = 0; mi < 4; ++mi)
        af[mi] = *reinterpret_cast<const short8*>(
            &As[cur][(wm + mi * 16 + fr) * 64 + ((ks * 32 + fq * 8) ^ swz)]);
#pragma unroll
      for (int nj = 0; nj < 2; ++nj)
        bf[nj] = *reinterpret_cast<const short8*>(
            &Bs[cur][(wn + nj * 16 + fr) * 64 + ((ks * 32 + fq * 8) ^ swz)]);
#pragma unroll
      for (int mi = 0; mi < 4; ++mi)
#pragma unroll
        for (int nj = 0; nj < 2; ++nj)
          acc[mi][nj] = MFMA16(af[mi], bf[nj], acc[mi][nj], 0, 0, 0);
    }
    __syncthreads();
  }
#pragma unroll
  for (int mi = 0; mi < 4; ++mi)
#pragma unroll
    for (int r = 0; r < 4; ++r) {
      int row = m0 + wm + mi * 16 + fq * 4 + r;
      if (row < c) {
#pragma unroll
        for (int nj = 0; nj < 2; ++nj)
          t1[(long)(o + row) * 512 + n0 + wn + nj * 16 + fr] = f2bf(acc[mi][nj][r]);
      }
    }
}

// ---------------------------------------------------------------------------
// dual GEMM: a = silu(t1g @ vgT^T) * (t1u @ vuT^T)  [rows x F], K=256
// BK=32, LDS dbuf + XOR swizzle (4-chunk rows). grid=(44,16,E)
// ---------------------------------------------------------------------------
__global__ __launch_bounds__(256, 3) void k_act(
    const unsigned short* __restrict__ t1,
    const unsigned short* __restrict__ vgT, const unsigned short* __restrict__ vuT,
    unsigned short* __restrict__ a, const int* __restrict__ cnt,
    const int* __restrict__ off)
{
  __shared__ __align__(16) unsigned short Ag[2][128 * 32], Au[2][128 * 32];
  __shared__ __align__(16) unsigned short Bg[2][64 * 32],  Bu[2][64 * 32];
  const int e = blockIdx.z, c = cnt[e], o = off[e];
  const int m0 = blockIdx.y * 128;
  if (m0 >= c) return;
  const int n0 = blockIdx.x * 64;
  const int tid = threadIdx.x;
  const int wid = tid >> 6, lane = tid & 63;
  const int sr16 = lane >> 2;
  const int scs = (((lane & 3) ^ (sr16 & 3)) * 8); // pre-swizzled source col
  const int ra0 = o + min(m0 + wid * 32 + sr16, c - 1);
  const int ra1 = o + min(m0 + wid * 32 + 16 + sr16, c - 1);
  const unsigned short* gAg0 = t1 + (long)ra0 * 512 + scs;
  const unsigned short* gAg1 = t1 + (long)ra1 * 512 + scs;
  const unsigned short* gBg = vgT + (long)e * cF * 256 + (long)(n0 + wid * 16 + sr16) * 256 + scs;
  const unsigned short* gBu = vuT + (long)e * cF * 256 + (long)(n0 + wid * 16 + sr16) * 256 + scs;
  const int lA = wid * 32 * 32;
  const int lB = wid * 16 * 32;
  auto STAGE = [&](int k0, int buf) {
    gld16(gAg0 + k0, &Ag[buf][lA]);
    gld16(gAg1 + k0, &Ag[buf][lA + 16 * 32]);
    gld16(gAg0 + 256 + k0, &Au[buf][lA]);
    gld16(gAg1 + 256 + k0, &Au[buf][lA + 16 * 32]);
    gld16(gBg + k0, &Bg[buf][lB]);
    gld16(gBu + k0, &Bu[buf][lB]);
  };
  const int wm = (wid >> 1) * 64, wn = (wid & 1) * 32;
  const int fr = lane & 15, fq = lane >> 4;
  const int swz = (fr & 3) * 8;                    // read-side XOR (shorts)
  float4v zf = {0.f, 0.f, 0.f, 0.f};
  float4v accg[4][2], accu[4][2];
#pragma unroll
  for (int i = 0; i < 4; ++i) { accg[i][0] = zf; accg[i][1] = zf; accu[i][0] = zf; accu[i][1] = zf; }
  STAGE(0, 0);
  __syncthreads();
  for (int t = 0; t < 8; ++t) {
    const int cur = t & 1;
    if (t < 7) STAGE((t + 1) * 32, cur ^ 1);
    short8 ag[4], au[4], bg[2], bu[2];
#pragma unroll
    for (int mi = 0; mi < 4; ++mi) {
      ag[mi] = *reinterpret_cast<const short8*>(
          &Ag[cur][(wm + mi * 16 + fr) * 32 + ((fq * 8) ^ swz)]);
      au[mi] = *reinterpret_cast<const short8*>(
          &Au[cur][(wm + mi * 16 + fr) * 32 + ((fq * 8) ^ swz)]);
    }
#pragma unroll
    for (int nj = 0; nj < 2; ++nj) {
      bg[nj] = *reinterpret_cast<const short8*>(
          &Bg[cur][(wn + nj * 16 + fr) * 32 + ((fq * 8) ^ swz)]);
      bu[nj] = *reinterpret_cast<const short8*>(
          &Bu[cur][(wn + nj * 16 + fr) * 32 + ((fq * 8) ^ swz)]);
    }
#pragma unroll
    for (int mi = 0; mi < 4; ++mi)
#pragma unroll
      for (int nj = 0; nj < 2; ++nj) {
        accg[mi][nj] = MFMA16(ag[mi], bg[nj], accg[mi][nj], 0, 0, 0);
        accu[mi][nj] = MFMA16(au[mi], bu[nj], accu[mi][nj], 0, 0, 0);
      }
    __syncthreads();
  }
#pragma unroll
  for (int mi = 0; mi < 4; ++mi)
#pragma unroll
    for (int r = 0; r < 4; ++r) {
      int row = m0 + wm + mi * 16 + fq * 4 + r;
      if (row < c) {
#pragma unroll
        for (int nj = 0; nj < 2; ++nj) {
          float g = accg[mi][nj][r];
          float u = accu[mi][nj][r];
          float s = g / (1.f + expf(-g)) * u;
          a[(long)(o + row) * cF + n0 + wn + nj * 16 + fr] = f2bf(s);
        }
      }
    }
}

// ---------------------------------------------------------------------------
// t3p[ks] = a @ udT^T (split-K=4, fp32 partials).  [4][ROWS][256].
// LDS double-buffer + XOR-swizzled staging. 11 iters.
// grid = (16, 32, E): x = n(0..3) | ksp(0..3)<<2  -> ~1024 active blocks.
// ---------------------------------------------------------------------------
__global__ __launch_bounds__(256, 4) void k_t3(
    const unsigned short* __restrict__ a, const unsigned short* __restrict__ udT,
    float* __restrict__ t3p, const int* __restrict__ cnt,
    const int* __restrict__ off)
{
  __shared__ __align__(16) unsigned short As[2][64 * 64], Bs[2][64 * 64];
  const int e = blockIdx.z, c = cnt[e], o = off[e];
  const int m0 = blockIdx.y * 64;
  if (m0 >= c) return;
  const int n0 = (blockIdx.x & 3) * 64;
  const int ksp = blockIdx.x >> 2;                 // 0..3
  const int kbase = ksp * 704;
  const int tid = threadIdx.x;
  const int wid = tid >> 6, lane = tid & 63;
  const int sr8 = lane >> 3;
  const int scs = ((lane & 7) ^ sr8) * 8;          // pre-swizzled source col
  const int ra0 = o + min(m0 + wid * 16 + sr8, c - 1);
  const int ra1 = o + min(m0 + wid * 16 + 8 + sr8, c - 1);
  const unsigned short* gA0 = a + (long)ra0 * cF + kbase + scs;
  const unsigned short* gA1 = a + (long)ra1 * cF + kbase + scs;
  const unsigned short* gB  = udT + (long)e * 256 * cF +
      (long)(n0 + wid * 16 + sr8) * cF + kbase + scs;
  const int lofs = wid * 16 * 64;
  auto STAGE = [&](int k0, int buf) {
    gld16(gA0 + k0, &As[buf][lofs]);
    gld16(gA1 + k0, &As[buf][lofs + 8 * 64]);
    gld16(gB + k0, &Bs[buf][lofs]);
    gld16(gB + (long)8 * cF + k0, &Bs[buf][lofs + 8 * 64]);
  };
  const int wm = (wid >> 1) * 32, wn = (wid & 1) * 32;
  const int fr = lane & 15, fq = lane >> 4;
  const int swz = (fr & 7) * 8;                    // read-side XOR (shorts)
  float4v zf = {0.f, 0.f, 0.f, 0.f};
  float4v acc[2][2] = {{zf, zf}, {zf, zf}};
  STAGE(0, 0);
  __syncthreads();
  for (int t = 0; t < 11; ++t) {
    const int cur = t & 1;
    if (t < 10) STAGE((t + 1) * 64, cur ^ 1);
#pragma unroll
    for (int ks = 0; ks < 2; ++ks) {
      short8 af[2], bf[2];
#pragma unroll
      for (int mi = 0; mi < 2; ++mi)
        af[mi] = *reinterpret_cast<const short8*>(
            &As[cur][(wm + mi * 16 + fr) * 64 + ((ks * 32 + fq * 8) ^ swz)]);
#pragma unroll
      for (int nj = 0; nj < 2; ++nj)
        bf[nj] = *reinterpret_cast<const short8*>(
            &Bs[cur][(wn + nj * 16 + fr) * 64 + ((ks * 32 + fq * 8) ^ swz)]);
#pragma unroll
      for (int mi = 0; mi < 2; ++mi)
#pragma unroll
        for (int nj = 0; nj < 2; ++nj)
          acc[mi][nj] = MFMA16(af[mi], bf[nj], acc[mi][nj], 0, 0, 0);
    }
    __syncthreads();
  }
  float* dstbase = t3p + (long)ksp * ROWS * 256;
#pragma unroll
  for (int mi = 0; mi < 2; ++mi)
#pragma unroll
    for (int r = 0; r < 4; ++r) {
      int row = m0 + wm + mi * 16 + fq * 4 + r;
      if (row < c) {
        float* dst = dstbase + (long)(o + row) * 256 + n0 + wn;
#pragma unroll
        for (int nj = 0; nj < 2; ++nj)
          dst[nj * 16 + fr] = acc[mi][nj][r];
      }
    }
}

// ---------------------------------------------------------------------------
// t3b bf16 = sum of 4 fp32 t3p partials (pure streaming). grid = 512.
// ---------------------------------------------------------------------------
__global__ __launch_bounds__(256) void k_red(
    const float* __restrict__ t3p, unsigned short* __restrict__ t3b)
{
  const long psz = (long)ROWS * 256;
  long i = ((long)blockIdx.x * 256 + threadIdx.x) * 8;
  float4 s0 = *reinterpret_cast<const float4*>(t3p + i);
  float4 s1 = *reinterpret_cast<const float4*>(t3p + i + 4);
#pragma unroll
  for (int q = 1; q < 4; ++q) {
    float4 a0 = *reinterpret_cast<const float4*>(t3p + q * psz + i);
    float4 a1 = *reinterpret_cast<const float4*>(t3p + q * psz + i + 4);
    s0.x += a0.x; s0.y += a0.y; s0.z += a0.z; s0.w += a0.w;
    s1.x += a1.x; s1.y += a1.y; s1.z += a1.z; s1.w += a1.w;
  }
  store_bf8(t3b + i, s0, s1);
}

// ---------------------------------------------------------------------------
// y = t3b @ vd2t^T   [rows x 1024] bf16. K = 256.
// BK=32, LDS dbuf + XOR swizzle (4-chunk rows). grid = (16,16,E)
// ---------------------------------------------------------------------------
__global__ __launch_bounds__(256, 4) void k_y(
    const unsigned short* __restrict__ t3b, const unsigned short* __restrict__ vd2t,
    unsigned short* __restrict__ y, const int* __restrict__ cnt,
    const int* __restrict__ off)
{
  __shared__ __align__(16) unsigned short As[2][128 * 32], Bs[2][64 * 32];
  const int e = blockIdx.z, c = cnt[e], o = off[e];
  const int m0 = blockIdx.y * 128;
  if (m0 >= c) return;
  const int n0 = blockIdx.x * 64;
  const int tid = threadIdx.x;
  const int wid = tid >> 6, lane = tid & 63;
  const int sr16 = lane >> 2;
  const int scs = (((lane & 3) ^ (sr16 & 3)) * 8); // pre-swizzled source col
  const int ra0 = o + min(m0 + wid * 32 + sr16, c - 1);
  const int ra1 = o + min(m0 + wid * 32 + 16 + sr16, c - 1);
  const unsigned short* gA0 = t3b + (long)ra0 * 256 + scs;
  const unsigned short* gA1 = t3b + (long)ra1 * 256 + scs;
  const unsigned short* gB  = vd2t + (long)e * cH * 256 + (long)(n0 + wid * 16 + sr16) * 256 + scs;
  const int lA = wid * 32 * 32;
  const int lB = wid * 16 * 32;
  auto STAGE = [&](int k0, int buf) {
    gld16(gA0 + k0, &As[buf][lA]);
    gld16(gA1 + k0, &As[buf][lA + 16 * 32]);
    gld16(gB + k0, &Bs[buf][lB]);
  };
  const int wm = (wid >> 1) * 64, wn = (wid & 1) * 32;
  const int fr = lane & 15, fq = lane >> 4;
  const int swz = (fr & 3) * 8;                    // read-side XOR (shorts)
  float4v zf = {0.f, 0.f, 0.f, 0.f};
  float4v acc[4][2];
#pragma unroll
  for (int i = 0; i < 4; ++i) { acc[i][0] = zf; acc[i][1] = zf; }
  STAGE(0, 0);
  __syncthreads();
  for (int t = 0; t < 8; ++t) {
    const int cur = t & 1;
    if (t < 7) STAGE((t + 1) * 32, cur ^ 1);
    short8 af[4], bf[2];
#pragma unroll
    for (int mi = 0; mi < 4; ++mi)
      af[mi] = *reinterpret_cast<const short8*>(
          &As[cur][(wm + mi * 16 + fr) * 32 + ((fq * 8) ^ swz)]);
#pragma unroll
    for (int nj = 0; nj < 2; ++nj)
      bf[nj] = *reinterpret_cast<const short8*>(
          &Bs[cur][(wn + nj * 16 + fr) * 32 + ((fq * 8) ^ swz)]);
#pragma unroll
    for (int mi = 0; mi < 4; ++mi)
#pragma unroll
      for (int nj = 0; nj < 2; ++nj)
        acc[mi][nj] = MFMA16(af[mi], bf[nj], acc[mi][nj], 0, 0, 0);
    __syncthreads();
  }
#pragma unroll
  for (int mi = 0; mi < 4; ++mi)
#pragma unroll
    for (int r = 0; r < 4; ++r) {
      int row = m0 + wm + mi * 16 + fq * 4 + r;
      if (row < c) {
#pragma unroll
        for (int nj = 0; nj < 2; ++nj)
          y[(long)(o + row) * cH + n0 + wn + nj * 16 + fr] = f2bf(acc[mi][nj][r]);
      }
    }
}

// ---------------------------------------------------------------------------
// out[t] = w0 * y[rowmap[2t]] + w1 * y[rowmap[2t+1]]   (pure write, no zero)
// ---------------------------------------------------------------------------
__global__ __launch_bounds__(256) void k_combine(
    const unsigned short* __restrict__ y, const float* __restrict__ wt,
    const int* __restrict__ rowmap, float* __restrict__ out)
{
  const int tid = threadIdx.x;
  const int t = blockIdx.x * 2 + (tid >> 7);
  const int h = (tid & 127) * 8;
  const int r0 = rowmap[2 * t], r1 = rowmap[2 * t + 1];
  const float w0 = wt[2 * t], w1 = wt[2 * t + 1];
  union { uint4 v; unsigned short s[8]; } ua, ub;
  ua.v = *reinterpret_cast<const uint4*>(y + (long)r0 * cH + h);
  ub.v = *reinterpret_cast<const uint4*>(y + (long)r1 * cH + h);
  float o[8];
#pragma unroll
  for (int i = 0; i < 8; ++i)
    o[i] = w0 * bf2f(ua.s[i]) + w1 * bf2f(ub.s[i]);
  float* dst = out + (long)t * cH + h;
  *reinterpret_cast<float4*>(dst)     = make_float4(o[0], o[1], o[2], o[3]);
  *reinterpret_cast<float4*>(dst + 4) = make_float4(o[4], o[5], o[6], o[7]);
}

// ---------------------------------------------------------------------------
extern "C" void kernel_launch(void* const* d_in, const int* in_sizes, int n_in,
                              void* d_out, int out_size, void* d_ws, size_t ws_size,
                              hipStream_t stream)
{
  const float* x  = (const float*)d_in[0];
  const float* gw = (const float*)d_in[1];
  const float* Ug = (const float*)d_in[2];
  const float* Cg = (const float*)d_in[3];
  const float* Vg = (const float*)d_in[4];
  const float* Uu = (const float*)d_in[5];
  const float* Cu = (const float*)d_in[6];
  const float* Vu = (const float*)d_in[7];
  const float* Ud = (const float*)d_in[8];
  const float* Cd = (const float*)d_in[9];
  const float* Vd = (const float*)d_in[10];
  float* out = (float*)d_out;

  // workspace layout (~83 MiB peak, with aliasing)
  char* w = (char*)d_ws;
  unsigned short* vgT = (unsigned short*)w;
  float*          t3p = (float*)w;
  unsigned short* t3b = (unsigned short*)(w + (long)4 * ROWS * 256 * 4);
  w += (long)cE * cF * 256 * 2;                                               // 11.53
  unsigned short* b1t = (unsigned short*)w;  w += (long)cE * 512 * 1024 * 2;  // 8.39
  unsigned short* vd2t = (unsigned short*)w; w += (long)cE * cH * 256 * 2;    // 4.19
  unsigned short* vuT = (unsigned short*)w;
  unsigned short* yb  = (unsigned short*)w;  w += (long)cE * cF * 256 * 2;    // 11.53
  unsigned short* udT = (unsigned short*)w;  w += (long)cE * 256 * cF * 2;    // 11.53
  unsigned short* VdT = (unsigned short*)w;  w += (long)cE * cH * 256 * 2;    // 4.19
  unsigned short* xb  = (unsigned short*)w;  w += (long)cT * cH * 2;          // 4.19
  unsigned short* CgT = (unsigned short*)w;  w += (long)cR * cR * 2;          // 0.13
  unsigned short* CuT = (unsigned short*)w;  w += (long)cR * cR * 2;          // 0.13
  unsigned short* t1  = (unsigned short*)w;  w += (long)ROWS * 512 * 2;       // 4.19
  unsigned short* ab  = (unsigned short*)w;  w += (long)ROWS * cF * 2;        // 23.07
  float* wt   = (float*)w; w += ROWS * 4;
  int* et     = (int*)w; w += ROWS * 4;
  int* rowmap = (int*)w; w += ROWS * 4;
  int* tok    = (int*)w; w += ROWS * 4;
  int* cnt = (int*)w; w += cE * 4;
  int* off = (int*)w; w += cE * 4;

  // L1: SMALL transposes (Cg/Cu/Vd) + gating + x->bf16
  k_prep1s<<<dim3(PREP1_BLOCKS), dim3(256), 0, stream>>>(
      Cg, CgT, Cu, CuT, Vd, VdT, x, gw, xb, et, wt);
  // L2: folds + lists + BIG transposes (Vg/Vu/Ud), co-scheduled
  k_prep2<<<dim3(PREP2_BLOCKS), dim3(256), 0, stream>>>(
      CgT, CuT, Ug, Uu, b1t, VdT, Cd, vd2t,
      Vg, vgT, Vu, vuT, Ud, udT, et, rowmap, tok, cnt, off);
  // L3: compact t1 GEMM (dbuf + swizzle)
  k_t1c<<<dim3(8, cT / 128, cE), dim3(256), 0, stream>>>(xb, b1t, t1, tok, cnt, off);
  // L4: a = silu(t1g @ Vg) * (t1u @ Vu)  (dbuf + swizzle)
  k_act<<<dim3(cF / 64, cT / 128, cE), dim3(256), 0, stream>>>(t1, vgT, vuT, ab, cnt, off);
  // L5: t3p = a @ Ud (split-K=4, dbuf + swizzle; aliases dead vgT+b1t)
  k_t3<<<dim3(16, cT / 64, cE), dim3(256), 0, stream>>>(ab, udT, t3p, cnt, off);
  // L6: t3b = bf16(sum of 4 partials)
  k_red<<<dim3(ROWS * 256 / (256 * 8)), dim3(256), 0, stream>>>(t3p, t3b);
  // L7: y = t3b @ Vd2 (dbuf + swizzle; aliases dead vuT)
  k_y<<<dim3(cH / 64, cT / 128, cE), dim3(256), 0, stream>>>(t3b, vd2t, yb, cnt, off);
  // L8: out = w0*y[r0] + w1*y[r1]
  k_combine<<<dim3(cT / 2), dim3(256), 0, stream>>>(yb, wt, rowmap, out);
}

// Round 9
// 259.521 us; speedup vs baseline: 1.1872x; 1.0202x over previous
//
#include <hip/hip_runtime.h>
#include <math.h>

constexpr int cE = 8;
constexpr int cH = 1024;
constexpr int cF = 2816;
constexpr int cR = 256;
constexpr int cT = 2048;
constexpr int ROWS = cT * 2;   // total routed (token, expert) rows = T*K
constexpr int LDA = 40;        // padded LDS row stride (foldm reg-staged kernel)

using short8  = __attribute__((ext_vector_type(8))) short;
using float4v = __attribute__((ext_vector_type(4))) float;
#define MFMA16 __builtin_amdgcn_mfma_f32_16x16x32_bf16

__device__ __forceinline__ unsigned short f2bf(float f) {
  union { float f; unsigned u; } v; v.f = f;
  unsigned r = v.u + 0x7fffu + ((v.u >> 16) & 1u);   // RNE
  return (unsigned short)(r >> 16);
}
__device__ __forceinline__ float bf2f(unsigned short s) {
  union { unsigned u; float f; } v; v.u = (unsigned)s << 16; return v.f;
}

// pack 8 fp32 -> 8 bf16, single 16B store
__device__ __forceinline__ void store_bf8(unsigned short* dst, float4 a, float4 b) {
  union { unsigned short u[8]; uint4 v; } t;
  t.u[0] = f2bf(a.x); t.u[1] = f2bf(a.y); t.u[2] = f2bf(a.z); t.u[3] = f2bf(a.w);
  t.u[4] = f2bf(b.x); t.u[5] = f2bf(b.y); t.u[6] = f2bf(b.z); t.u[7] = f2bf(b.w);
  *reinterpret_cast<uint4*>(dst) = t.v;
}

// async global->LDS, 16 B per lane. LDS dest = wave-uniform base + lane*16,
// global source address is per-lane (gather/swizzle-capable).
__device__ __forceinline__ void gld16(const unsigned short* g, unsigned short* l) {
  __builtin_amdgcn_global_load_lds(
      (const __attribute__((address_space(1))) void*)g,
      (__attribute__((address_space(3))) void*)l, 16, 0, 0);
}

// ---------------------------------------------------------------------------
// 64x64 transpose tile (fp32 -> bf16): in [P][Q] per batch -> out [Q][P].
// ---------------------------------------------------------------------------
__device__ __forceinline__ void tconv_tile64(
    const float* __restrict__ in, unsigned short* __restrict__ out,
    int P, int Q, int e, int bx, int by, int tid, float (*tile)[65])
{
  const long es = (long)P * Q;
  in += e * es; out += e * es;
  const int c0 = bx * 64, r0 = by * 64;
  const int r = tid >> 4, c4 = (tid & 15) * 4;
#pragma unroll
  for (int p = 0; p < 4; ++p) {
    float4 v = *reinterpret_cast<const float4*>(
        in + (long)(r0 + p * 16 + r) * Q + c0 + c4);
    tile[p * 16 + r][c4 + 0] = v.x; tile[p * 16 + r][c4 + 1] = v.y;
    tile[p * 16 + r][c4 + 2] = v.z; tile[p * 16 + r][c4 + 3] = v.w;
  }
  __syncthreads();
  const int cc = tid >> 4, rr4 = (tid & 15) * 4;
#pragma unroll
  for (int p = 0; p < 4; ++p) {
    ushort4 o;
    o.x = f2bf(tile[rr4 + 0][p * 16 + cc]);
    o.y = f2bf(tile[rr4 + 1][p * 16 + cc]);
    o.z = f2bf(tile[rr4 + 2][p * 16 + cc]);
    o.w = f2bf(tile[rr4 + 3][p * 16 + cc]);
    *reinterpret_cast<ushort4*>(out + (long)(c0 + p * 16 + cc) * P + r0 + rr4) = o;
  }
}

// ---------------------------------------------------------------------------
// LAUNCH 1: SMALL transposes (Cg/Cu/Vd, 544 tiles) + gating + x->bf16.
//  [0,16) Cg | [16,32) Cu | [32,544) Vd | [544,1056) gating
// ---------------------------------------------------------------------------
constexpr int P1_TCONV = 544;
constexpr int PREP1_BLOCKS = P1_TCONV + cT / 4;

__global__ __launch_bounds__(256) void k_prep1s(
    const float* __restrict__ Cg, unsigned short* __restrict__ CgT,
    const float* __restrict__ Cu, unsigned short* __restrict__ CuT,
    const float* __restrict__ Vd, unsigned short* __restrict__ VdT,
    const float* __restrict__ x, const float* __restrict__ gw,
    unsigned short* __restrict__ xb, int* __restrict__ et,
    float* __restrict__ wt)
{
  __shared__ float tile[64][65];
  int b = blockIdx.x;
  const int tid = threadIdx.x;
  if (b < P1_TCONV) {
    const float* in; unsigned short* out; int P, Q;
    if (b < 16)       { in = Cg; out = CgT; P = 256; Q = 256;  }
    else if (b < 32)  { b -= 16; in = Cu; out = CuT; P = 256; Q = 256;  }
    else              { b -= 32; in = Vd; out = VdT; P = 256; Q = 1024; }
    const int tpe = (P / 64) * (Q / 64);
    const int e = b / tpe, rem = b % tpe;
    const int bx = rem % (Q / 64), by = rem / (Q / 64);
    tconv_tile64(in, out, P, Q, e, bx, by, tid, tile);
    return;
  }
  // ---- gating path ----
  const int wid = tid >> 6, lane = tid & 63;
  const int t = (b - P1_TCONV) * 4 + wid;
  const float* xr = x + (long)t * cH + lane * 16;
  float4 v0 = *reinterpret_cast<const float4*>(xr);
  float4 v1 = *reinterpret_cast<const float4*>(xr + 4);
  float4 v2 = *reinterpret_cast<const float4*>(xr + 8);
  float4 v3 = *reinterpret_cast<const float4*>(xr + 12);
  store_bf8(xb + (long)t * cH + lane * 16, v0, v1);
  store_bf8(xb + (long)t * cH + lane * 16 + 8, v2, v3);
  float xv[16];
  *reinterpret_cast<float4*>(&xv[0])  = v0;
  *reinterpret_cast<float4*>(&xv[4])  = v1;
  *reinterpret_cast<float4*>(&xv[8])  = v2;
  *reinterpret_cast<float4*>(&xv[12]) = v3;
  const float* g = gw + (long)lane * 16 * cE;
  float l[cE];
#pragma unroll
  for (int e = 0; e < cE; ++e) l[e] = 0.f;
#pragma unroll
  for (int i = 0; i < 16; ++i) {
    float4 ga = *reinterpret_cast<const float4*>(g + i * cE);
    float4 gb = *reinterpret_cast<const float4*>(g + i * cE + 4);
    float xi = xv[i];
    l[0] += xi * ga.x; l[1] += xi * ga.y; l[2] += xi * ga.z; l[3] += xi * ga.w;
    l[4] += xi * gb.x; l[5] += xi * gb.y; l[6] += xi * gb.z; l[7] += xi * gb.w;
  }
#pragma unroll
  for (int m = 1; m < 64; m <<= 1)
#pragma unroll
    for (int e = 0; e < cE; ++e)
      l[e] += __shfl_xor(l[e], m, 64);
  if (lane == 0) {
    int i0 = 0; float m0 = l[0];
#pragma unroll
    for (int e = 1; e < cE; ++e) if (l[e] > m0) { m0 = l[e]; i0 = e; }
    int i1 = -1; float m1 = -1e30f;
#pragma unroll
    for (int e = 0; e < cE; ++e) if (e != i0 && l[e] > m1) { m1 = l[e]; i1 = e; }
    float w0 = 1.f / (1.f + expf(m1 - m0));
    et[t * 2 + 0] = i0;  et[t * 2 + 1] = i1;
    wt[t * 2 + 0] = w0;  wt[t * 2 + 1] = 1.f - w0;
  }
}

// ---------------------------------------------------------------------------
// MFMA fold body: D[m][n] = sum_k A[m][k] * B[n][k],  K = 256 fixed.
// tile 128x64, BK=32, register prefetch.
// ---------------------------------------------------------------------------
__device__ __forceinline__ void foldm_body(
    const unsigned short* __restrict__ A, const float* __restrict__ B,
    unsigned short* __restrict__ D, int ldd, int m0, int n0, int tid,
    unsigned short* As, unsigned short* Bs)
{
  const int sr = tid >> 2, sk = (tid & 3) * 8;
  const unsigned short* a0 = A + (long)(m0 + sr) * 256 + sk;
  const unsigned short* a1 = a0 + (long)64 * 256;
  const float* br = B + (long)(n0 + sr) * 256 + sk;
  uint4 rA0, rA1; float4 rB0, rB1;
  auto load_slice = [&](int k0) {
    rA0 = *reinterpret_cast<const uint4*>(a0 + k0);
    rA1 = *reinterpret_cast<const uint4*>(a1 + k0);
    rB0 = *reinterpret_cast<const float4*>(br + k0);
    rB1 = *reinterpret_cast<const float4*>(br + k0 + 4);
  };
  load_slice(0);
  const int wid = tid >> 6, lane = tid & 63;
  const int wm = (wid >> 1) * 64, wn = (wid & 1) * 32;
  const int fr = lane & 15, fq = lane >> 4;
  float4v zf = {0.f, 0.f, 0.f, 0.f};
  float4v acc[4][2];
#pragma unroll
  for (int i = 0; i < 4; ++i) { acc[i][0] = zf; acc[i][1] = zf; }
  for (int k0 = 0; k0 < 256; k0 += 32) {
    *reinterpret_cast<uint4*>(&As[sr * LDA + sk]) = rA0;
    *reinterpret_cast<uint4*>(&As[(sr + 64) * LDA + sk]) = rA1;
    store_bf8(&Bs[sr * LDA + sk], rB0, rB1);
    if (k0 + 32 < 256) load_slice(k0 + 32);
    __syncthreads();
    short8 af[4], bf[2];
#pragma unroll
    for (int mi = 0; mi < 4; ++mi)
      af[mi] = *reinterpret_cast<const short8*>(&As[(wm + mi * 16 + fr) * LDA + fq * 8]);
#pragma unroll
    for (int nj = 0; nj < 2; ++nj)
      bf[nj] = *reinterpret_cast<const short8*>(&Bs[(wn + nj * 16 + fr) * LDA + fq * 8]);
#pragma unroll
    for (int mi = 0; mi < 4; ++mi)
#pragma unroll
      for (int nj = 0; nj < 2; ++nj)
        acc[mi][nj] = MFMA16(af[mi], bf[nj], acc[mi][nj], 0, 0, 0);
    __syncthreads();
  }
#pragma unroll
  for (int mi = 0; mi < 4; ++mi)
#pragma unroll
    for (int r = 0; r < 4; ++r) {
      int m = m0 + wm + mi * 16 + fq * 4 + r;
#pragma unroll
      for (int nj = 0; nj < 2; ++nj)
        D[(long)m * ldd + n0 + wn + nj * 16 + fr] = f2bf(acc[mi][nj][r]);
    }
}

// ---------------------------------------------------------------------------
// LAUNCH 2: folds (768) + lists (1) + BIG transposes Vg/Vu/Ud (4224 tiles).
//  [0,512) b1t folds | [512,768) vd2t folds | 768 lists |
//  [769,2177) Vg | [2177,3585) Vu | [3585,4993) Ud
// ---------------------------------------------------------------------------
constexpr int PREP2_BLOCKS = 769 + 3 * 1408;
__global__ __launch_bounds__(256, 3) void k_prep2(
    const unsigned short* __restrict__ CgT, const unsigned short* __restrict__ CuT,
    const float* __restrict__ Ug, const float* __restrict__ Uu,
    unsigned short* __restrict__ b1t,
    const unsigned short* __restrict__ VdT, const float* __restrict__ Cd,
    unsigned short* __restrict__ vd2t,
    const float* __restrict__ Vg, unsigned short* __restrict__ vgT,
    const float* __restrict__ Vu, unsigned short* __restrict__ vuT,
    const float* __restrict__ Ud, unsigned short* __restrict__ udT,
    const int* __restrict__ et, int* __restrict__ rowmap,
    int* __restrict__ tok, int* __restrict__ cnt, int* __restrict__ off)
{
  __shared__ __align__(16) char smem[64 * 65 * 4];   // 16640 B union
  const int b = blockIdx.x;
  const int tid = threadIdx.x;
  if (b < 512) {
    unsigned short* As = (unsigned short*)smem;
    unsigned short* Bs = As + 128 * LDA;
    const int bx = b & 15, by = (b >> 4) & 1, z = b >> 5;
    const int sel = z >> 3, e = z & 7;
    const unsigned short* A = sel ? CuT : CgT;
    const float* B = (sel ? Uu : Ug) + (long)e * cH * cR;
    unsigned short* Dp = b1t + (long)e * 512 * 1024 + (long)sel * 256 * 1024;
    foldm_body(A, B, Dp, cH, by * 128, bx * 64, tid, As, Bs);
  } else if (b < 768) {
    unsigned short* As = (unsigned short*)smem;
    unsigned short* Bs = As + 128 * LDA;
    const int b2 = b - 512;
    const int bx = b2 & 3, by = (b2 >> 2) & 7, e = b2 >> 5;
    foldm_body(VdT + (long)e * cH * cR, Cd, vd2t + (long)e * cH * 256, cR,
               by * 128, bx * 64, tid, As, Bs);
  } else if (b == 768) {
    // ---- lists path (single block) ----
    int* sc_ = (int*)smem;
    int* sp_ = sc_ + cE;
    int* so_ = sc_ + 2 * cE;
    if (tid < cE) { sc_[tid] = 0; sp_[tid] = 0; }
    __syncthreads();
    for (int i = tid; i < ROWS; i += 256) atomicAdd(&sc_[et[i]], 1);
    __syncthreads();
    if (tid == 0) {
      int s = 0;
      for (int e = 0; e < cE; ++e) { so_[e] = s; s += sc_[e]; }
    }
    __syncthreads();
    for (int i = tid; i < ROWS; i += 256) {
      int e = et[i];
      int slot = atomicAdd(&sp_[e], 1);
      int cr = so_[e] + slot;
      rowmap[i] = cr;
      tok[cr] = i >> 1;
    }
    if (tid < cE) { cnt[tid] = sc_[tid]; off[tid] = so_[tid]; }
  } else {
    // ---- big transpose path ----
    float (*tile)[65] = reinterpret_cast<float(*)[65]>(smem);
    int t = b - 769;
    const float* in; unsigned short* out; int P, Q;
    if (t < 1408)       { in = Vg; out = vgT; P = 256;  Q = 2816; }
    else if (t < 2816)  { t -= 1408; in = Vu; out = vuT; P = 256;  Q = 2816; }
    else                { t -= 2816; in = Ud; out = udT; P = 2816; Q = 256;  }
    const int tpe = (P / 64) * (Q / 64);
    const int e = t / tpe, rem = t % tpe;
    const int bx = rem % (Q / 64), by = rem / (Q / 64);
    tconv_tile64(in, out, P, Q, e, bx, by, tid, tile);
  }
}

// ---------------------------------------------------------------------------
// COMPACT t1 GEMM: t1[o+row] = xb[tok[o+row]] @ b1t[e]^T   (K=1024, N=512)
// M-TILE 64 (TLP retile): tile 64x64, BK=64, acc[2][2], LDS 32 KB ->
// 5 blocks/CU, active blocks 2x. dbuf + XOR swizzle (8-chunk).
// grid = (8, cT/64, E), early-return past cnt[e].
// ---------------------------------------------------------------------------
__global__ __launch_bounds__(256, 4) void k_t1c(
    const unsigned short* __restrict__ xb, const unsigned short* __restrict__ b1t,
    unsigned short* __restrict__ t1, const int* __restrict__ tok,
    const int* __restrict__ cnt, const int* __restrict__ off)
{
  __shared__ __align__(16) unsigned short As[2][64 * 64], Bs[2][64 * 64];
  const int e = blockIdx.z, c = cnt[e], o = off[e];
  const int m0 = blockIdx.y * 64;
  if (m0 >= c) return;
  const int n0 = blockIdx.x * 64;
  const int tid = threadIdx.x;
  const int wid = tid >> 6, lane = tid & 63;
  const int sr8 = lane >> 3;
  const int scs = ((lane & 7) ^ sr8) * 8;          // pre-swizzled source col
  const unsigned short* gA[2];
#pragma unroll
  for (int j = 0; j < 2; ++j) {
    int row = min(m0 + wid * 16 + j * 8 + sr8, c - 1);
    gA[j] = xb + (long)tok[o + row] * cH + scs;
  }
  const unsigned short* gB = b1t + (long)e * 512 * 1024 +
      (long)(n0 + wid * 16 + sr8) * 1024 + scs;
  const int lofs = wid * 16 * 64;
  auto STAGE = [&](int k0, int buf) {
    gld16(gA[0] + k0, &As[buf][lofs]);
    gld16(gA[1] + k0, &As[buf][lofs + 8 * 64]);
    gld16(gB + k0, &Bs[buf][lofs]);
    gld16(gB + (long)8 * 1024 + k0, &Bs[buf][lofs + 8 * 64]);
  };
  const int wm = (wid >> 1) * 32, wn = (wid & 1) * 32;
  const int fr = lane & 15, fq = lane >> 4;
  const int swz = (fr & 7) * 8;                    // read-side XOR (shorts)
  float4v zf = {0.f, 0.f, 0.f, 0.f};
  float4v acc[2][2] = {{zf, zf}, {zf, zf}};
  STAGE(0, 0);
  __syncthreads();
  for (int t = 0; t < 16; ++t) {
    const int cur = t & 1;
    if (t < 15) STAGE((t + 1) * 64, cur ^ 1);
#pragma unroll
    for (int ks = 0; ks < 2; ++ks) {
      short8 af[2], bf[2];
#pragma unroll
      for (int mi = 0; mi < 2; ++mi)
        af[mi] = *reinterpret_cast<const short8*>(
            &As[cur][(wm + mi * 16 + fr) * 64 + ((ks * 32 + fq * 8) ^ swz)]);
#pragma unroll
      for (int nj = 0; nj < 2; ++nj)
        bf[nj] = *reinterpret_cast<const short8*>(
            &Bs[cur][(wn + nj * 16 + fr) * 64 + ((ks * 32 + fq * 8) ^ swz)]);
#pragma unroll
      for (int mi = 0; mi < 2; ++mi)
#pragma unroll
        for (int nj = 0; nj < 2; ++nj)
          acc[mi][nj] = MFMA16(af[mi], bf[nj], acc[mi][nj], 0, 0, 0);
    }
    __syncthreads();
  }
#pragma unroll
  for (int mi = 0; mi < 2; ++mi)
#pragma unroll
    for (int r = 0; r < 4; ++r) {
      int row = m0 + wm + mi * 16 + fq * 4 + r;
      if (row < c) {
#pragma unroll
        for (int nj = 0; nj < 2; ++nj)
          t1[(long)(o + row) * 512 + n0 + wn + nj * 16 + fr] = f2bf(acc[mi][nj][r]);
      }
    }
}

// ---------------------------------------------------------------------------
// dual GEMM: a = silu(t1g @ vgT^T) * (t1u @ vuT^T)  [rows x F], K=256
// M-TILE 64 (TLP retile): tile 64x64, acc[2][2] x2 dtypes, LDS 32 KB ->
// 5 blocks/CU, active blocks 2x (11/CU). BK=32, dbuf + XOR swizzle (4-chunk).
// grid = (44, cT/64, E)
// ---------------------------------------------------------------------------
__global__ __launch_bounds__(256, 4) void k_act(
    const unsigned short* __restrict__ t1,
    const unsigned short* __restrict__ vgT, const unsigned short* __restrict__ vuT,
    unsigned short* __restrict__ a, const int* __restrict__ cnt,
    const int* __restrict__ off)
{
  __shared__ __align__(16) unsigned short Ag[2][64 * 32], Au[2][64 * 32];
  __shared__ __align__(16) unsigned short Bg[2][64 * 32], Bu[2][64 * 32];
  const int e = blockIdx.z, c = cnt[e], o = off[e];
  const int m0 = blockIdx.y * 64;
  if (m0 >= c) return;
  const int n0 = blockIdx.x * 64;
  const int tid = threadIdx.x;
  const int wid = tid >> 6, lane = tid & 63;
  const int sr16 = lane >> 2;
  const int scs = (((lane & 3) ^ (sr16 & 3)) * 8); // pre-swizzled source col
  const int ra = o + min(m0 + wid * 16 + sr16, c - 1);
  const unsigned short* gAg = t1 + (long)ra * 512 + scs;
  const unsigned short* gBg = vgT + (long)e * cF * 256 + (long)(n0 + wid * 16 + sr16) * 256 + scs;
  const unsigned short* gBu = vuT + (long)e * cF * 256 + (long)(n0 + wid * 16 + sr16) * 256 + scs;
  const int lofs = wid * 16 * 32;
  auto STAGE = [&](int k0, int buf) {
    gld16(gAg + k0, &Ag[buf][lofs]);
    gld16(gAg + 256 + k0, &Au[buf][lofs]);
    gld16(gBg + k0, &Bg[buf][lofs]);
    gld16(gBu + k0, &Bu[buf][lofs]);
  };
  const int wm = (wid >> 1) * 32, wn = (wid & 1) * 32;
  const int fr = lane & 15, fq = lane >> 4;
  const int swz = (fr & 3) * 8;                    // read-side XOR (shorts)
  float4v zf = {0.f, 0.f, 0.f, 0.f};
  float4v accg[2][2] = {{zf, zf}, {zf, zf}};
  float4v accu[2][2] = {{zf, zf}, {zf, zf}};
  STAGE(0, 0);
  __syncthreads();
  for (int t = 0; t < 8; ++t) {
    const int cur = t & 1;
    if (t < 7) STAGE((t + 1) * 32, cur ^ 1);
    short8 ag[2], au[2], bg[2], bu[2];
#pragma unroll
    for (int mi = 0; mi < 2; ++mi) {
      ag[mi] = *reinterpret_cast<const short8*>(
          &Ag[cur][(wm + mi * 16 + fr) * 32 + ((fq * 8) ^ swz)]);
      au[mi] = *reinterpret_cast<const short8*>(
          &Au[cur][(wm + mi * 16 + fr) * 32 + ((fq * 8) ^ swz)]);
    }
#pragma unroll
    for (int nj = 0; nj < 2; ++nj) {
      bg[nj] = *reinterpret_cast<const short8*>(
          &Bg[cur][(wn + nj * 16 + fr) * 32 + ((fq * 8) ^ swz)]);
      bu[nj] = *reinterpret_cast<const short8*>(
          &Bu[cur][(wn + nj * 16 + fr) * 32 + ((fq * 8) ^ swz)]);
    }
#pragma unroll
    for (int mi = 0; mi < 2; ++mi)
#pragma unroll
      for (int nj = 0; nj < 2; ++nj) {
        accg[mi][nj] = MFMA16(ag[mi], bg[nj], accg[mi][nj], 0, 0, 0);
        accu[mi][nj] = MFMA16(au[mi], bu[nj], accu[mi][nj], 0, 0, 0);
      }
    __syncthreads();
  }
#pragma unroll
  for (int mi = 0; mi < 2; ++mi)
#pragma unroll
    for (int r = 0; r < 4; ++r) {
      int row = m0 + wm + mi * 16 + fq * 4 + r;
      if (row < c) {
#pragma unroll
        for (int nj = 0; nj < 2; ++nj) {
          float g = accg[mi][nj][r];
          float u = accu[mi][nj][r];
          float s = g / (1.f + expf(-g)) * u;
          a[(long)(o + row) * cF + n0 + wn + nj * 16 + fr] = f2bf(s);
        }
      }
    }
}

// ---------------------------------------------------------------------------
// t3p[ks] = a @ udT^T (split-K=4, fp32 partials).  [4][ROWS][256].
// LDS double-buffer + XOR-swizzled staging. 11 iters.
// grid = (16, 32, E): x = n(0..3) | ksp(0..3)<<2  -> ~1024 active blocks.
// ---------------------------------------------------------------------------
__global__ __launch_bounds__(256, 4) void k_t3(
    const unsigned short* __restrict__ a, const unsigned short* __restrict__ udT,
    float* __restrict__ t3p, const int* __restrict__ cnt,
    const int* __restrict__ off)
{
  __shared__ __align__(16) unsigned short As[2][64 * 64], Bs[2][64 * 64];
  const int e = blockIdx.z, c = cnt[e], o = off[e];
  const int m0 = blockIdx.y * 64;
  if (m0 >= c) return;
  const int n0 = (blockIdx.x & 3) * 64;
  const int ksp = blockIdx.x >> 2;                 // 0..3
  const int kbase = ksp * 704;
  const int tid = threadIdx.x;
  const int wid = tid >> 6, lane = tid & 63;
  const int sr8 = lane >> 3;
  const int scs = ((lane & 7) ^ sr8) * 8;          // pre-swizzled source col
  const int ra0 = o + min(m0 + wid * 16 + sr8, c - 1);
  const int ra1 = o + min(m0 + wid * 16 + 8 + sr8, c - 1);
  const unsigned short* gA0 = a + (long)ra0 * cF + kbase + scs;
  const unsigned short* gA1 = a + (long)ra1 * cF + kbase + scs;
  const unsigned short* gB  = udT + (long)e * 256 * cF +
      (long)(n0 + wid * 16 + sr8) * cF + kbase + scs;
  const int lofs = wid * 16 * 64;
  auto STAGE = [&](int k0, int buf) {
    gld16(gA0 + k0, &As[buf][lofs]);
    gld16(gA1 + k0, &As[buf][lofs + 8 * 64]);
    gld16(gB + k0, &Bs[buf][lofs]);
    gld16(gB + (long)8 * cF + k0, &Bs[buf][lofs + 8 * 64]);
  };
  const int wm = (wid >> 1) * 32, wn = (wid & 1) * 32;
  const int fr = lane & 15, fq = lane >> 4;
  const int swz = (fr & 7) * 8;                    // read-side XOR (shorts)
  float4v zf = {0.f, 0.f, 0.f, 0.f};
  float4v acc[2][2] = {{zf, zf}, {zf, zf}};
  STAGE(0, 0);
  __syncthreads();
  for (int t = 0; t < 11; ++t) {
    const int cur = t & 1;
    if (t < 10) STAGE((t + 1) * 64, cur ^ 1);
#pragma unroll
    for (int ks = 0; ks < 2; ++ks) {
      short8 af[2], bf[2];
#pragma unroll
      for (int mi = 0; mi < 2; ++mi)
        af[mi] = *reinterpret_cast<const short8*>(
            &As[cur][(wm + mi * 16 + fr) * 64 + ((ks * 32 + fq * 8) ^ swz)]);
#pragma unroll
      for (int nj = 0; nj < 2; ++nj)
        bf[nj] = *reinterpret_cast<const short8*>(
            &Bs[cur][(wn + nj * 16 + fr) * 64 + ((ks * 32 + fq * 8) ^ swz)]);
#pragma unroll
      for (int mi = 0; mi < 2; ++mi)
#pragma unroll
        for (int nj = 0; nj < 2; ++nj)
          acc[mi][nj] = MFMA16(af[mi], bf[nj], acc[mi][nj], 0, 0, 0);
    }
    __syncthreads();
  }
  float* dstbase = t3p + (long)ksp * ROWS * 256;
#pragma unroll
  for (int mi = 0; mi < 2; ++mi)
#pragma unroll
    for (int r = 0; r < 4; ++r) {
      int row = m0 + wm + mi * 16 + fq * 4 + r;
      if (row < c) {
        float* dst = dstbase + (long)(o + row) * 256 + n0 + wn;
#pragma unroll
        for (int nj = 0; nj < 2; ++nj)
          dst[nj * 16 + fr] = acc[mi][nj][r];
      }
    }
}

// ---------------------------------------------------------------------------
// t3b bf16 = sum of 4 fp32 t3p partials (pure streaming). grid = 512.
// ---------------------------------------------------------------------------
__global__ __launch_bounds__(256) void k_red(
    const float* __restrict__ t3p, unsigned short* __restrict__ t3b)
{
  const long psz = (long)ROWS * 256;
  long i = ((long)blockIdx.x * 256 + threadIdx.x) * 8;
  float4 s0 = *reinterpret_cast<const float4*>(t3p + i);
  float4 s1 = *reinterpret_cast<const float4*>(t3p + i + 4);
#pragma unroll
  for (int q = 1; q < 4; ++q) {
    float4 a0 = *reinterpret_cast<const float4*>(t3p + q * psz + i);
    float4 a1 = *reinterpret_cast<const float4*>(t3p + q * psz + i + 4);
    s0.x += a0.x; s0.y += a0.y; s0.z += a0.z; s0.w += a0.w;
    s1.x += a1.x; s1.y += a1.y; s1.z += a1.z; s1.w += a1.w;
  }
  store_bf8(t3b + i, s0, s1);
}

// ---------------------------------------------------------------------------
// y = t3b @ vd2t^T   [rows x 1024] bf16. K = 256.
// M-TILE 64 (TLP retile): tile 64x64, acc[2][2], LDS 16 KB, active 2x.
// BK=32, dbuf + XOR swizzle (4-chunk). grid = (16, cT/64, E)
// ---------------------------------------------------------------------------
__global__ __launch_bounds__(256, 4) void k_y(
    const unsigned short* __restrict__ t3b, const unsigned short* __restrict__ vd2t,
    unsigned short* __restrict__ y, const int* __restrict__ cnt,
    const int* __restrict__ off)
{
  __shared__ __align__(16) unsigned short As[2][64 * 32], Bs[2][64 * 32];
  const int e = blockIdx.z, c = cnt[e], o = off[e];
  const int m0 = blockIdx.y * 64;
  if (m0 >= c) return;
  const int n0 = blockIdx.x * 64;
  const int tid = threadIdx.x;
  const int wid = tid >> 6, lane = tid & 63;
  const int sr16 = lane >> 2;
  const int scs = (((lane & 3) ^ (sr16 & 3)) * 8); // pre-swizzled source col
  const int ra = o + min(m0 + wid * 16 + sr16, c - 1);
  const unsigned short* gA = t3b + (long)ra * 256 + scs;
  const unsigned short* gB = vd2t + (long)e * cH * 256 + (long)(n0 + wid * 16 + sr16) * 256 + scs;
  const int lofs = wid * 16 * 32;
  auto STAGE = [&](int k0, int buf) {
    gld16(gA + k0, &As[buf][lofs]);
    gld16(gB + k0, &Bs[buf][lofs]);
  };
  const int wm = (wid >> 1) * 32, wn = (wid & 1) * 32;
  const int fr = lane & 15, fq = lane >> 4;
  const int swz = (fr & 3) * 8;                    // read-side XOR (shorts)
  float4v zf = {0.f, 0.f, 0.f, 0.f};
  float4v acc[2][2] = {{zf, zf}, {zf, zf}};
  STAGE(0, 0);
  __syncthreads();
  for (int t = 0; t < 8; ++t) {
    const int cur = t & 1;
    if (t < 7) STAGE((t + 1) * 32, cur ^ 1);
    short8 af[2], bf[2];
#pragma unroll
    for (int mi = 0; mi < 2; ++mi)
      af[mi] = *reinterpret_cast<const short8*>(
          &As[cur][(wm + mi * 16 + fr) * 32 + ((fq * 8) ^ swz)]);
#pragma unroll
    for (int nj = 0; nj < 2; ++nj)
      bf[nj] = *reinterpret_cast<const short8*>(
          &Bs[cur][(wn + nj * 16 + fr) * 32 + ((fq * 8) ^ swz)]);
#pragma unroll
    for (int mi = 0; mi < 2; ++mi)
#pragma unroll
      for (int nj = 0; nj < 2; ++nj)
        acc[mi][nj] = MFMA16(af[mi], bf[nj], acc[mi][nj], 0, 0, 0);
    __syncthreads();
  }
#pragma unroll
  for (int mi = 0; mi < 2; ++mi)
#pragma unroll
    for (int r = 0; r < 4; ++r) {
      int row = m0 + wm + mi * 16 + fq * 4 + r;
      if (row < c) {
#pragma unroll
        for (int nj = 0; nj < 2; ++nj)
          y[(long)(o + row) * cH + n0 + wn + nj * 16 + fr] = f2bf(acc[mi][nj][r]);
      }
    }
}

// ---------------------------------------------------------------------------
// out[t] = w0 * y[rowmap[2t]] + w1 * y[rowmap[2t+1]]   (pure write, no zero)
// ---------------------------------------------------------------------------
__global__ __launch_bounds__(256) void k_combine(
    const unsigned short* __restrict__ y, const float* __restrict__ wt,
    const int* __restrict__ rowmap, float* __restrict__ out)
{
  const int tid = threadIdx.x;
  const int t = blockIdx.x * 2 + (tid >> 7);
  const int h = (tid & 127) * 8;
  const int r0 = rowmap[2 * t], r1 = rowmap[2 * t + 1];
  const float w0 = wt[2 * t], w1 = wt[2 * t + 1];
  union { uint4 v; unsigned short s[8]; } ua, ub;
  ua.v = *reinterpret_cast<const uint4*>(y + (long)r0 * cH + h);
  ub.v = *reinterpret_cast<const uint4*>(y + (long)r1 * cH + h);
  float o[8];
#pragma unroll
  for (int i = 0; i < 8; ++i)
    o[i] = w0 * bf2f(ua.s[i]) + w1 * bf2f(ub.s[i]);
  float* dst = out + (long)t * cH + h;
  *reinterpret_cast<float4*>(dst)     = make_float4(o[0], o[1], o[2], o[3]);
  *reinterpret_cast<float4*>(dst + 4) = make_float4(o[4], o[5], o[6], o[7]);
}

// ---------------------------------------------------------------------------
extern "C" void kernel_launch(void* const* d_in, const int* in_sizes, int n_in,
                              void* d_out, int out_size, void* d_ws, size_t ws_size,
                              hipStream_t stream)
{
  const float* x  = (const float*)d_in[0];
  const float* gw = (const float*)d_in[1];
  const float* Ug = (const float*)d_in[2];
  const float* Cg = (const float*)d_in[3];
  const float* Vg = (const float*)d_in[4];
  const float* Uu = (const float*)d_in[5];
  const float* Cu = (const float*)d_in[6];
  const float* Vu = (const float*)d_in[7];
  const float* Ud = (const float*)d_in[8];
  const float* Cd = (const float*)d_in[9];
  const float* Vd = (const float*)d_in[10];
  float* out = (float*)d_out;

  // workspace layout (~83 MiB peak, with aliasing)
  char* w = (char*)d_ws;
  unsigned short* vgT = (unsigned short*)w;
  float*          t3p = (float*)w;
  unsigned short* t3b = (unsigned short*)(w + (long)4 * ROWS * 256 * 4);
  w += (long)cE * cF * 256 * 2;                                               // 11.53
  unsigned short* b1t = (unsigned short*)w;  w += (long)cE * 512 * 1024 * 2;  // 8.39
  unsigned short* vd2t = (unsigned short*)w; w += (long)cE * cH * 256 * 2;    // 4.19
  unsigned short* vuT = (unsigned short*)w;
  unsigned short* yb  = (unsigned short*)w;  w += (long)cE * cF * 256 * 2;    // 11.53
  unsigned short* udT = (unsigned short*)w;  w += (long)cE * 256 * cF * 2;    // 11.53
  unsigned short* VdT = (unsigned short*)w;  w += (long)cE * cH * 256 * 2;    // 4.19
  unsigned short* xb  = (unsigned short*)w;  w += (long)cT * cH * 2;          // 4.19
  unsigned short* CgT = (unsigned short*)w;  w += (long)cR * cR * 2;          // 0.13
  unsigned short* CuT = (unsigned short*)w;  w += (long)cR * cR * 2;          // 0.13
  unsigned short* t1  = (unsigned short*)w;  w += (long)ROWS * 512 * 2;       // 4.19
  unsigned short* ab  = (unsigned short*)w;  w += (long)ROWS * cF * 2;        // 23.07
  float* wt   = (float*)w; w += ROWS * 4;
  int* et     = (int*)w; w += ROWS * 4;
  int* rowmap = (int*)w; w += ROWS * 4;
  int* tok    = (int*)w; w += ROWS * 4;
  int* cnt = (int*)w; w += cE * 4;
  int* off = (int*)w; w += cE * 4;

  // L1: SMALL transposes (Cg/Cu/Vd) + gating + x->bf16
  k_prep1s<<<dim3(PREP1_BLOCKS), dim3(256), 0, stream>>>(
      Cg, CgT, Cu, CuT, Vd, VdT, x, gw, xb, et, wt);
  // L2: folds + lists + BIG transposes (Vg/Vu/Ud), co-scheduled
  k_prep2<<<dim3(PREP2_BLOCKS), dim3(256), 0, stream>>>(
      CgT, CuT, Ug, Uu, b1t, VdT, Cd, vd2t,
      Vg, vgT, Vu, vuT, Ud, udT, et, rowmap, tok, cnt, off);
  // L3: compact t1 GEMM (M=64 retile, dbuf + swizzle)
  k_t1c<<<dim3(8, cT / 64, cE), dim3(256), 0, stream>>>(xb, b1t, t1, tok, cnt, off);
  // L4: a = silu(t1g @ Vg) * (t1u @ Vu)  (M=64 retile, dbuf + swizzle)
  k_act<<<dim3(cF / 64, cT / 64, cE), dim3(256), 0, stream>>>(t1, vgT, vuT, ab, cnt, off);
  // L5: t3p = a @ Ud (split-K=4, dbuf + swizzle; aliases dead vgT+b1t)
  k_t3<<<dim3(16, cT / 64, cE), dim3(256), 0, stream>>>(ab, udT, t3p, cnt, off);
  // L6: t3b = bf16(sum of 4 partials)
  k_red<<<dim3(ROWS * 256 / (256 * 8)), dim3(256), 0, stream>>>(t3p, t3b);
  // L7: y = t3b @ Vd2 (M=64 retile, dbuf + swizzle; aliases dead vuT)
  k_y<<<dim3(cH / 64, cT / 64, cE), dim3(256), 0, stream>>>(t3b, vd2t, yb, cnt, off);
  // L8: out = w0*y[r0] + w1*y[r1]
  k_combine<<<dim3(cT / 2), dim3(256), 0, stream>>>(yb, wt, rowmap, out);
}